// Round 6
// baseline (465.871 us; speedup 1.0000x reference)
//
#include <hip/hip_runtime.h>

// ---------------------------------------------------------------------------
// GraphUNet on MI355X.  Round-20 = round-19 resubmit (container infra failure,
// kernel audited: no deadlock, LDS 18.4KB x 8 blocks/CU = 147KB <= 160KB,
// alias bounds 17.2KB <= 18.4KB, barriers separate alias lifetimes).
//
// R16 structure (440.5 us measured) with ONE change: popc_aug_p + aug_merge
// fused into popc_aug_full.
//  * full-K word-chunk loop inside the popc kernel (LDS 18 KB, acc in regs),
//    epilogue = aug_merge's (diag zero, bf16 pack, LDS-transposed mirror,
//    rowsum atomics) with the mask LDS aliased as the float tile.
//    Removes ~33 MB int16 staging traffic + 1 launch.  maskb (1 MB) re-reads
//    are L2-resident.
//  * GEMM grid rule (R17/R18 lessons): every gemm_bt keeps >=256 scheduled
//    blocks; Saz=8, Sxw=4 everywhere.  No GEMM-side fusion.
// ---------------------------------------------------------------------------

typedef __attribute__((ext_vector_type(8))) short bf16x8;
typedef __attribute__((ext_vector_type(4))) short s16x4;
typedef __attribute__((ext_vector_type(4))) float f32x4;

__device__ __forceinline__ short f2bf(float f) {
    unsigned u = __builtin_bit_cast(unsigned, f);
    u += 0x7FFFu + ((u >> 16) & 1u);          // RNE
    return (short)(u >> 16);
}
__device__ __forceinline__ float bf2f(short s) {
    unsigned u = ((unsigned)(unsigned short)s) << 16;
    return __builtin_bit_cast(float, u);
}

#define GLL16(gsrc, ldst)                                                        \
    __builtin_amdgcn_global_load_lds(                                            \
        (__attribute__((address_space(1))) void*)(gsrc),                         \
        (__attribute__((address_space(3))) void*)(ldst), 16, 0, 0)

// ---------------------------------------------------------------------------
// bf16 BT GEMM: C(MxN) = A(MxK) @ B^T, B stored N x K row-major.
// MODE 0: Ah@Bh ; 1: +Ah@Bl ; 2: +Al@Bh   (lo*lo dropped, ~2^-18 rel)
// EPI 0: fp32 partial slice [z][M][N]
// EPI 1: fp32 mirrored square slices (TRI: blocks by>bx exit)
// EPI 3: fp32 TRANSPOSED partial slice [z][N][M] (f32x4 stores)
// ---------------------------------------------------------------------------
template<int MODE, int EPI>
__global__ __launch_bounds__(256, 2)
void gemm_bt(const short* __restrict__ Ah, const short* __restrict__ Al,
             const short* __restrict__ Bh, const short* __restrict__ Bl,
             float* __restrict__ Cf, int M, int N, int K, int kChunk)
{
    if (EPI == 1 && (int)blockIdx.y > (int)blockIdx.x) return;

    __shared__ short sAh[128 * 32];
    __shared__ short sBh[128 * 32];
    __shared__ short sAl[(MODE == 2) ? 128 * 32 : 8];
    __shared__ short sBl[(MODE >= 1) ? 128 * 32 : 8];

    const int t    = threadIdx.x;
    const int lane = t & 63;
    const int wave = t >> 6;
    const int tM   = blockIdx.y * 128;
    const int tN   = blockIdx.x * 128;
    const int k0   = blockIdx.z * kChunk;

    const int wm  = (wave >> 1) * 64;
    const int wn  = (wave & 1) * 64;
    const int l15 = lane & 15;
    const int g8  = (lane >> 4) * 8;

    f32x4 acc[4][4];
    const f32x4 zero = {0.f, 0.f, 0.f, 0.f};
#pragma unroll
    for (int i = 0; i < 4; i++)
#pragma unroll
        for (int j = 0; j < 4; j++) acc[i][j] = zero;

    const int i0 = t, i1 = t + 256;
    const short* a0 = Ah + (size_t)(tM + (i0 >> 2)) * K + (i0 & 3) * 8;
    const short* a1 = Ah + (size_t)(tM + (i1 >> 2)) * K + (i1 & 3) * 8;
    const short* b0 = Bh + (size_t)(tN + (i0 >> 2)) * K + (i0 & 3) * 8;
    const short* b1 = Bh + (size_t)(tN + (i1 >> 2)) * K + (i1 & 3) * 8;
    const short *bl0 = nullptr, *bl1 = nullptr, *al0 = nullptr, *al1 = nullptr;
    if (MODE >= 1) {
        bl0 = Bl + (size_t)(tN + (i0 >> 2)) * K + (i0 & 3) * 8;
        bl1 = Bl + (size_t)(tN + (i1 >> 2)) * K + (i1 & 3) * 8;
    }
    if (MODE == 2) {
        al0 = Al + (size_t)(tM + (i0 >> 2)) * K + (i0 & 3) * 8;
        al1 = Al + (size_t)(tM + (i1 >> 2)) * K + (i1 & 3) * 8;
    }

    for (int kb = k0; kb < k0 + kChunk; kb += 32) {
        GLL16(a0 + kb, &sAh[i0 * 8]);
        GLL16(a1 + kb, &sAh[i1 * 8]);
        GLL16(b0 + kb, &sBh[i0 * 8]);
        GLL16(b1 + kb, &sBh[i1 * 8]);
        if (MODE >= 1) { GLL16(bl0 + kb, &sBl[i0 * 8]); GLL16(bl1 + kb, &sBl[i1 * 8]); }
        if (MODE == 2) { GLL16(al0 + kb, &sAl[i0 * 8]); GLL16(al1 + kb, &sAl[i1 * 8]); }
        __syncthreads();

        bf16x8 aF[4], bF[4], aL[4], bL[4];
#pragma unroll
        for (int i = 0; i < 4; i++)
            aF[i] = *(const bf16x8*)&sAh[(wm + i * 16 + l15) * 32 + g8];
#pragma unroll
        for (int j = 0; j < 4; j++)
            bF[j] = *(const bf16x8*)&sBh[(wn + j * 16 + l15) * 32 + g8];
        if (MODE >= 1)
#pragma unroll
            for (int j = 0; j < 4; j++)
                bL[j] = *(const bf16x8*)&sBl[(wn + j * 16 + l15) * 32 + g8];
        if (MODE == 2)
#pragma unroll
            for (int i = 0; i < 4; i++)
                aL[i] = *(const bf16x8*)&sAl[(wm + i * 16 + l15) * 32 + g8];

#pragma unroll
        for (int i = 0; i < 4; i++)
#pragma unroll
            for (int j = 0; j < 4; j++) {
                acc[i][j] = __builtin_amdgcn_mfma_f32_16x16x32_bf16(aF[i], bF[j], acc[i][j], 0, 0, 0);
                if (MODE >= 1)
                    acc[i][j] = __builtin_amdgcn_mfma_f32_16x16x32_bf16(aF[i], bL[j], acc[i][j], 0, 0, 0);
                if (MODE == 2)
                    acc[i][j] = __builtin_amdgcn_mfma_f32_16x16x32_bf16(aL[i], bF[j], acc[i][j], 0, 0, 0);
            }
        __syncthreads();
    }

    // C/D layout: col=lane&15, row=(lane>>4)*4+reg  [m89-verified]
    const int r4 = (lane >> 4) * 4;
    if (EPI == 3) {
        float* CT = Cf + (size_t)blockIdx.z * M * N;   // [N][M]
#pragma unroll
        for (int i = 0; i < 4; i++)
#pragma unroll
            for (int j = 0; j < 4; j++) {
                const int col   = tN + wn + j * 16 + l15;
                const int rbase = tM + wm + i * 16 + r4;
                *(f32x4*)&CT[(size_t)col * M + rbase] = acc[i][j];
            }
    } else {
        float* Cg = Cf + (size_t)blockIdx.z * M * N;
#pragma unroll
        for (int i = 0; i < 4; i++)
#pragma unroll
            for (int j = 0; j < 4; j++) {
                const int col = tN + wn + j * 16 + l15;
                float* cp = Cg + (size_t)(tM + wm + i * 16 + r4) * N + col;
#pragma unroll
                for (int r = 0; r < 4; r++) cp[(size_t)r * N] = acc[i][j][r];
            }
        if (EPI == 1 && tM != tN) {
#pragma unroll
            for (int i = 0; i < 4; i++)
#pragma unroll
                for (int j = 0; j < 4; j++) {
                    const int col   = tN + wn + j * 16 + l15;
                    const int rbase = tM + wm + i * 16 + r4;
                    *(f32x4*)&Cg[(size_t)col * N + rbase] = acc[i][j];
                }
        }
    }
}

// ---------------------------------------------------------------------------
// Utility kernels
// ---------------------------------------------------------------------------

// one-shot prep: W^T hi/lo for all 7 layers + x0 hi/lo split + zero M0 bitmask
__global__ void prep(const float* __restrict__ Wd0, const float* __restrict__ Wd1,
                     const float* __restrict__ Wd2, const float* __restrict__ Wd3,
                     const float* __restrict__ Wu0, const float* __restrict__ Wu1,
                     const float* __restrict__ Wu2, const float* __restrict__ x0,
                     short* __restrict__ Wth, short* __restrict__ Wtl,
                     short* __restrict__ Xh, short* __restrict__ Xl,
                     unsigned long long* __restrict__ M0)
{
    int t = blockIdx.x * 256 + threadIdx.x;
    float v; int dst;
    if (t < 32768)       { int e = t;          v = Wd0[e]; dst = 0      + (e & 255) * 128 + (e >> 8); }
    else if (t < 98304)  { int e = t - 32768;  v = Wd1[e]; dst = 32768  + (e & 255) * 256 + (e >> 8); }
    else if (t < 163840) { int e = t - 98304;  v = Wd2[e]; dst = 98304  + (e & 255) * 256 + (e >> 8); }
    else if (t < 229376) { int e = t - 163840; v = Wd3[e]; dst = 163840 + (e & 255) * 256 + (e >> 8); }
    else if (t < 294912) { int e = t - 229376; v = Wu0[e]; dst = 229376 + (e & 255) * 256 + (e >> 8); }
    else if (t < 360448) { int e = t - 294912; v = Wu1[e]; dst = 294912 + (e & 255) * 256 + (e >> 8); }
    else if (t < 393216) { int e = t - 360448; v = Wu2[e]; dst = 360448 + (e & 127) * 256 + (e >> 7); }
    else if (t < 917504) {
        int e = t - 393216;                      // x0: 4096*128
        v = x0[e];
        short h = f2bf(v);
        Xh[e] = h; Xl[e] = f2bf(v - bf2f(h));
        return;
    } else {
        M0[t - 917504] = 0ull;                   // 4096*64 words
        return;
    }
    short h = f2bf(v);
    Wth[dst] = h; Wtl[dst] = f2bf(v - bf2f(h));
}

// edge list -> symmetric self-loop-free row bitmask (dedup for free)
__global__ void build_bits(const int* __restrict__ ei, int E,
                           unsigned long long* __restrict__ M0)
{
    int e = blockIdx.x * 256 + threadIdx.x;
    if (e >= E) return;
    int i = ei[e], j = ei[E + e];
    if (i != j) {
        atomicOr(&M0[(size_t)i * 64 + (j >> 6)], 1ull << (j & 63));
        atomicOr(&M0[(size_t)j * 64 + (i >> 6)], 1ull << (i & 63));
    }
}

// bitmask -> CSR (<=128 nnz/row, ascending) + degree, via wave prefix scan
__global__ void row_compact_bits(const unsigned long long* __restrict__ M0,
                                 int* __restrict__ csr, float* __restrict__ rs)
{
    int row = blockIdx.x * 4 + (threadIdx.x >> 6);
    int lane = threadIdx.x & 63;
    unsigned long long w = M0[(size_t)row * 64 + lane];
    int c = __popcll(w);
    int incl = c;
    for (int off = 1; off < 64; off <<= 1) {
        int v = __shfl_up(incl, off);
        if (lane >= off) incl += v;
    }
    int base = incl - c;
    int* out = csr + (size_t)row * 128;
    while (w) {
        int b = __ffsll((unsigned long long)w) - 1;
        if (base < 128) out[base] = lane * 64 + b;
        base++;
        w &= w - 1;
    }
    if (lane == 63) rs[row] = (float)incl;
}

// L0 popcount masks: gather selected M0 rows + self bit; zero rs1
__global__ void mask_gather(const unsigned long long* __restrict__ M0,
                            const int* __restrict__ perm,
                            unsigned long long* __restrict__ mask,
                            float* __restrict__ rs, int kk)
{
    int t = blockIdx.x * 256 + threadIdx.x;
    if (t < kk) rs[t] = 0.f;
    int r = t >> 6, l = t & 63;
    int u = perm[r];
    unsigned long long w = M0[(size_t)u * 64 + l];
    if ((u >> 6) == l) w |= 1ull << (u & 63);
    mask[t] = w;
}

// fused popcount augment: full-K word-chunk loop + aug_merge epilogue.
// Block (by,bx) TRI: 64x64 tile of A1 = (M+I)(M+I)^T popcounts, diag zeroed,
// bf16 pack to Ahs[gi][gj] + LDS-transposed mirror to Ahs[gj][gi] + rowsums.
// LDS: masks (18432 B) aliased after last use as float tile[64][65]+sums.
#define PSTR2 18
__global__ __launch_bounds__(256, 8)
void popc_aug_full(const unsigned long long* __restrict__ mask, int kk,
                   short* __restrict__ Ahs, float* __restrict__ rs)
{
    const int bx = blockIdx.x, by = blockIdx.y;
    if (by > bx) return;
    __shared__ unsigned long long smraw[2 * 64 * PSTR2];   // 18432 B
    unsigned long long* a = smraw;
    unsigned long long* b = smraw + 64 * PSTR2;
    float (*tile)[65] = (float (*)[65])smraw;              // 16640 B alias
    float* rsum = (float*)smraw + 64 * 65;                 // +256 B
    float* csum = rsum + 64;                               // +256 B (17152 B)

    const int t = threadIdx.x;
    const int i0 = (t >> 4) * 4;         // 4 consecutive rows
    const int j0 = t & 15;               // cols j0 + 16*qj
    int acc[4][4];
#pragma unroll
    for (int qi = 0; qi < 4; qi++)
#pragma unroll
        for (int qj = 0; qj < 4; qj++) acc[qi][qj] = 0;

    for (int z = 0; z < 4; z++) {
        __syncthreads();
#pragma unroll
        for (int p = 0; p < 4; p++) {
            int idx = p * 256 + t;       // 0..1023 = rr*16 + w
            int rr = idx >> 4, w = idx & 15;
            a[rr * PSTR2 + w] = mask[((size_t)(by * 64 + rr)) * 64 + z * 16 + w];
            b[rr * PSTR2 + w] = mask[((size_t)(bx * 64 + rr)) * 64 + z * 16 + w];
        }
        __syncthreads();
#pragma unroll
        for (int w = 0; w < 16; w += 2) {
            ulong2 av[4], bv[4];
#pragma unroll
            for (int q = 0; q < 4; q++) av[q] = *(const ulong2*)&a[(i0 + q) * PSTR2 + w];
#pragma unroll
            for (int q = 0; q < 4; q++) bv[q] = *(const ulong2*)&b[(j0 + 16 * q) * PSTR2 + w];
#pragma unroll
            for (int qi = 0; qi < 4; qi++)
#pragma unroll
                for (int qj = 0; qj < 4; qj++) {
                    acc[qi][qj] += __builtin_popcountll(av[qi].x & bv[qj].x);
                    acc[qi][qj] += __builtin_popcountll(av[qi].y & bv[qj].y);
                }
        }
    }

    // ---- epilogue (aug_merge logic), masks dead -> alias LDS as float tile
    __syncthreads();
    if (t < 64) { rsum[t] = 0.f; csum[t] = 0.f; }
#pragma unroll
    for (int qi = 0; qi < 4; qi++)
#pragma unroll
        for (int qj = 0; qj < 4; qj++) {
            const int gi = by * 64 + i0 + qi;
            const int gj = bx * 64 + j0 + 16 * qj;
            tile[i0 + qi][j0 + 16 * qj] = (gi == gj) ? 0.f : (float)acc[qi][qj];
        }
    __syncthreads();

    const int i  = t >> 2;               // row 0..63
    const int c0 = (t & 3) * 16;         // 16 consecutive cols
    const int gi = by * 64 + i;
    float rp = 0.f;
    s16x4 pk[4];
#pragma unroll
    for (int q = 0; q < 16; q++) {
        float val = tile[i][c0 + q];
        rp += val;
        pk[q >> 2][q & 3] = f2bf(val);
    }
#pragma unroll
    for (int q = 0; q < 4; q++)
        *(s16x4*)&Ahs[(size_t)gi * kk + bx * 64 + c0 + q * 4] = pk[q];
    atomicAdd(&rsum[i], rp);
    if (bx != by) {
        float cpv = 0.f;
#pragma unroll
        for (int q = 0; q < 16; q++) {
            float val = tile[c0 + q][i];
            cpv += val;
            pk[q >> 2][q & 3] = f2bf(val);
        }
#pragma unroll
        for (int q = 0; q < 4; q++)
            *(s16x4*)&Ahs[(size_t)(bx * 64 + i) * kk + by * 64 + c0 + q * 4] = pk[q];
        atomicAdd(&csum[i], cpv);
    }
    __syncthreads();
    if (t < 64) {
        atomicAdd(&rs[by * 64 + t], rsum[t]);
        if (bx != by) atomicAdd(&rs[bx * 64 + t], csum[t]);
    }
}

// reduce transposed xw partial slices -> Z^T hi/lo  (x4 vectorized)
__global__ void z_reduce(const float* __restrict__ Cp, int S,
                         const float* __restrict__ rs,
                         short* __restrict__ Zh, short* __restrict__ Zl,
                         int n, int C)
{
    int t4 = (blockIdx.x * 256 + threadIdx.x) * 4;   // t = c*n + r layout
    int r = t4 % n;
    size_t stride = (size_t)n * C;
    f32x4 v = {0.f, 0.f, 0.f, 0.f};
    for (int s = 0; s < S; s++) v += *(const f32x4*)&Cp[t4 + s * stride];
    f32x4 rsv = *(const f32x4*)&rs[r];
    s16x4 zh, zl;
#pragma unroll
    for (int q = 0; q < 4; q++) {
        float z = v[q] / sqrtf(rsv[q] + 2.f);
        short h = f2bf(z);
        zh[q] = h; zl[q] = f2bf(z - bf2f(h));
    }
    *(s16x4*)&Zh[t4] = zh;
    *(s16x4*)&Zl[t4] = zl;
}

// reduce row-major xw partial slices -> Zf fp32 [r][C]  (x4 vectorized)
__global__ void zf_reduce(const float* __restrict__ Cp, int S,
                          const float* __restrict__ rs,
                          float* __restrict__ Zf, int n, int C)
{
    int t4 = (blockIdx.x * 256 + threadIdx.x) * 4;   // t = r*C + c
    int r = t4 / C;
    size_t stride = (size_t)n * C;
    f32x4 v = {0.f, 0.f, 0.f, 0.f};
    for (int s = 0; s < S; s++) v += *(const f32x4*)&Cp[t4 + s * stride];
    float d = 1.f / sqrtf(rs[r] + 2.f);
    v *= d;
    *(f32x4*)&Zf[t4] = v;
}

// CSR SpMM + fused GCN epilogue (+ optional fused pool score: SC=1)
template<int CN, int RELU, int SC>
__global__ __launch_bounds__(256)
void spmm_gcn(const int* __restrict__ csr, const float* __restrict__ rs,
              const float* __restrict__ Zf, const float* __restrict__ b,
              float* __restrict__ out,
              const float* __restrict__ pvec, float* __restrict__ score)
{
    const int lane = threadIdx.x & 63;
    const int row  = blockIdx.x * 4 + (threadIdx.x >> 6);
    const int dg   = (int)rs[row];
    const int* nb  = csr + (size_t)row * 128;
    if (CN == 256) {
        const int c = lane * 4;
        float4 acc = {0.f, 0.f, 0.f, 0.f};
        int q = 0;
        for (; q + 4 <= dg; q += 4) {
            int j0 = nb[q], j1 = nb[q+1], j2 = nb[q+2], j3 = nb[q+3];
            float4 z0 = *(const float4*)&Zf[(size_t)j0 * CN + c];
            float4 z1 = *(const float4*)&Zf[(size_t)j1 * CN + c];
            float4 z2 = *(const float4*)&Zf[(size_t)j2 * CN + c];
            float4 z3 = *(const float4*)&Zf[(size_t)j3 * CN + c];
            acc.x += z0.x; acc.y += z0.y; acc.z += z0.z; acc.w += z0.w;
            acc.x += z1.x; acc.y += z1.y; acc.z += z1.z; acc.w += z1.w;
            acc.x += z2.x; acc.y += z2.y; acc.z += z2.z; acc.w += z2.w;
            acc.x += z3.x; acc.y += z3.y; acc.z += z3.z; acc.w += z3.w;
        }
        for (; q < dg; q++) {
            float4 z = *(const float4*)&Zf[(size_t)nb[q] * CN + c];
            acc.x += z.x; acc.y += z.y; acc.z += z.z; acc.w += z.w;
        }
        float d = 1.f / sqrtf(rs[row] + 2.f);
        float4 zi = *(const float4*)&Zf[(size_t)row * CN + c];
        float4 bb = *(const float4*)&b[c];
        float4 g;
        g.x = d * acc.x + 2.f * d * zi.x + bb.x;
        g.y = d * acc.y + 2.f * d * zi.y + bb.y;
        g.z = d * acc.z + 2.f * d * zi.z + bb.z;
        g.w = d * acc.w + 2.f * d * zi.w + bb.w;
        if (RELU) {
            g.x = fmaxf(g.x, 0.f); g.y = fmaxf(g.y, 0.f);
            g.z = fmaxf(g.z, 0.f); g.w = fmaxf(g.w, 0.f);
        }
        *(float4*)&out[(size_t)row * CN + c] = g;
        if (SC) {
            float4 pv = ((const float4*)pvec)[lane];
            double nn  = (double)pv.x * pv.x + (double)pv.y * pv.y +
                         (double)pv.z * pv.z + (double)pv.w * pv.w;
            double acd = (double)g.x * pv.x + (double)g.y * pv.y +
                         (double)g.z * pv.z + (double)g.w * pv.w;
            for (int off = 32; off; off >>= 1) {
                acd += __shfl_down(acd, off);
                nn  += __shfl_down(nn, off);
            }
            if (lane == 0) score[row] = tanhf((float)(acd / sqrt(nn)));
        }
    } else {
        const int c = lane * 2;
        float2 acc = {0.f, 0.f};
        int q = 0;
        for (; q + 4 <= dg; q += 4) {
            int j0 = nb[q], j1 = nb[q+1], j2 = nb[q+2], j3 = nb[q+3];
            float2 z0 = *(const float2*)&Zf[(size_t)j0 * CN + c];
            float2 z1 = *(const float2*)&Zf[(size_t)j1 * CN + c];
            float2 z2 = *(const float2*)&Zf[(size_t)j2 * CN + c];
            float2 z3 = *(const float2*)&Zf[(size_t)j3 * CN + c];
            acc.x += z0.x; acc.y += z0.y;
            acc.x += z1.x; acc.y += z1.y;
            acc.x += z2.x; acc.y += z2.y;
            acc.x += z3.x; acc.y += z3.y;
        }
        for (; q < dg; q++) {
            float2 z = *(const float2*)&Zf[(size_t)nb[q] * CN + c];
            acc.x += z.x; acc.y += z.y;
        }
        float d = 1.f / sqrtf(rs[row] + 2.f);
        float2 zi = *(const float2*)&Zf[(size_t)row * CN + c];
        float2 g;
        g.x = d * acc.x + 2.f * d * zi.x + b[c];
        g.y = d * acc.y + 2.f * d * zi.y + b[c + 1];
        if (RELU) { g.x = fmaxf(g.x, 0.f); g.y = fmaxf(g.y, 0.f); }
        *(float2*)&out[(size_t)row * CN + c] = g;
    }
}

// fused: reduce AZ slices + GCN epilogue (+inv scatter) (+compile-time score)
template<int SC>
__global__ void gcn_final(const float* __restrict__ Cp, int S,
                          const short* __restrict__ Zh, const short* __restrict__ Zl,
                          const float* __restrict__ rs, const float* __restrict__ b,
                          float* __restrict__ out, short* __restrict__ oh,
                          short* __restrict__ ol, int k, int C, int relu,
                          const int* __restrict__ inv, const float* __restrict__ res,
                          const float* __restrict__ pvec, float* __restrict__ score)
{
    int t4 = (blockIdx.x * 256 + threadIdx.x) * 4;
    int j = t4 / C, c = t4 - j * C;
    int r = inv ? inv[j] : j;
    f32x4 v = res ? *(const f32x4*)&res[t4] : (f32x4){0.f, 0.f, 0.f, 0.f};
    if (r >= 0) {
        size_t base = (size_t)r * C + c;
        size_t stride = (size_t)k * C;
        f32x4 az = {0.f, 0.f, 0.f, 0.f};
        for (int s = 0; s < S; s++) az += *(const f32x4*)&Cp[base + s * stride];
        float d = 1.f / sqrtf(rs[r] + 2.f);
        f32x4 bb = *(const f32x4*)&b[c];
#pragma unroll
        for (int q = 0; q < 4; q++) {
            size_t zi = (size_t)(c + q) * k + r;
            float zz = bf2f(Zh[zi]) + bf2f(Zl[zi]);      // zz ~= d * xw
            float g = d * az[q] + 2.f * d * zz + bb[q];
            if (relu && g < 0.f) g = 0.f;
            v[q] += g;
        }
    }
    *(f32x4*)&out[t4] = v;
    if (oh) {
        s16x4 hh, ll;
#pragma unroll
        for (int q = 0; q < 4; q++) {
            short h = f2bf(v[q]);
            hh[q] = h; ll[q] = f2bf(v[q] - bf2f(h));
        }
        *(s16x4*)&oh[t4] = hh;
        *(s16x4*)&ol[t4] = ll;
    }
    if (SC) {
        // C==256: one wave per row (64 lanes x 4 cols) -> free score reduce,
        // math identical to the old score_kernel (double dot / double norm).
        const int lane = threadIdx.x & 63;
        float4 pv = *(const float4*)&pvec[c];
        double nn  = (double)pv.x * pv.x + (double)pv.y * pv.y +
                     (double)pv.z * pv.z + (double)pv.w * pv.w;
        double acd = (double)v[0] * pv.x + (double)v[1] * pv.y +
                     (double)v[2] * pv.z + (double)v[3] * pv.w;
        for (int off = 32; off; off >>= 1) {
            acd += __shfl_down(acd, off);
            nn  += __shfl_down(nn, off);
        }
        if (lane == 0) score[j] = tanhf((float)(acd / sqrt(nn)));
    }
}

__device__ __forceinline__ unsigned long long packkey(float s, int i) {
    unsigned u = __builtin_bit_cast(unsigned, s);
    u = (u & 0x80000000u) ? ~u : (u | 0x80000000u);
    return ((unsigned long long)u << 32) | (unsigned)(0xFFFFFFFFu - (unsigned)i);
}

// fused rank + select + gather: block owns 64 rows; scans all n keys from LDS
// chunks (512 threads = 8 j-slices); then scatter-writes perm/inv and the
// gathered+scaled hi/lo x rows (wave per selected row, C=256).
__global__ __launch_bounds__(512)
void rank_pool(const float* __restrict__ score, int n, int k,
               const float* __restrict__ xold,
               int* __restrict__ perm, int* __restrict__ inv,
               short* __restrict__ Xh, short* __restrict__ Xl)
{
    __shared__ unsigned long long sk[512];
    __shared__ int rk[64];
    __shared__ int selrow[64];
    __shared__ int selrank[64];
    __shared__ float selval[64];
    __shared__ int cnt;
    const int t  = threadIdx.x;
    const int il = t & 63;            // local row
    const int js = t >> 6;            // j-slice (8 slices of 64)
    const int i  = blockIdx.x * 64 + il;
    if (t < 64) rk[t] = 0;
    if (t == 0) cnt = 0;
    const unsigned long long mykey = packkey(score[i], i);
    int r = 0;
    for (int jb = 0; jb < n; jb += 512) {
        __syncthreads();
        if (jb + t < n) sk[t] = packkey(score[jb + t], jb + t);
        __syncthreads();
        const unsigned long long* p = &sk[js * 64];
#pragma unroll 16
        for (int q = 0; q < 64; q++) r += (p[q] > mykey) ? 1 : 0;
    }
    atomicAdd(&rk[il], r);
    __syncthreads();
    if (t < 64) {
        int rank = rk[t];
        int ii = blockIdx.x * 64 + t;
        inv[ii] = (rank < k) ? rank : -1;
        if (rank < k) {
            perm[rank] = ii;
            int s = atomicAdd(&cnt, 1);
            selrow[s]  = ii;
            selrank[s] = rank;
            selval[s]  = score[ii];
        }
    }
    __syncthreads();
    const int wave = t >> 6, lane = t & 63;
    for (int s = wave; s < cnt; s += 8) {
        const int   row = selrow[s];
        const float vv  = selval[s];
        f32x4 x = *(const f32x4*)&xold[(size_t)row * 256 + lane * 4];
        s16x4 hh, ll;
#pragma unroll
        for (int q = 0; q < 4; q++) {
            float v = x[q] * vv;
            short h = f2bf(v);
            hh[q] = h; ll[q] = f2bf(v - bf2f(h));
        }
        size_t o = (size_t)selrank[s] * 256 + lane * 4;
        *(s16x4*)&Xh[o] = hh;
        *(s16x4*)&Xl[o] = ll;
    }
}

// G = (A+I)[perm,:] from bf16 A (small-int exact); zeroes rs_next  (x8 vec)
__global__ void gatherG_h(const short* __restrict__ A, int n,
                          const int* __restrict__ perm,
                          short* __restrict__ Gh, int kk,
                          float* __restrict__ rsz)
{
    int idx = blockIdx.x * 256 + threadIdx.x;
    if (idx < kk) rsz[idx] = 0.f;
    int t8 = idx * 8;
    if (t8 >= kk * n) return;
    int r = t8 / n, c0 = t8 - r * n;
    int pr = perm[r];
    bf16x8 a = *(const bf16x8*)&A[(size_t)pr * n + c0];
    if (pr >= c0 && pr < c0 + 8)
        a[pr - c0] = f2bf(bf2f(a[pr - c0]) + 1.f);
    *(bf16x8*)&Gh[t8] = a;
}

__global__ void gatherG_hl(const short* __restrict__ Ahi, const short* __restrict__ Alo,
                           int n, const int* __restrict__ perm,
                           short* __restrict__ Gh, short* __restrict__ Gl, int kk,
                           float* __restrict__ rsz)
{
    int idx = blockIdx.x * 256 + threadIdx.x;
    if (idx < kk) rsz[idx] = 0.f;
    int t8 = idx * 8;
    if (t8 >= kk * n) return;
    int r = t8 / n, c0 = t8 - r * n;
    int pr = perm[r];
    bf16x8 ah = *(const bf16x8*)&Ahi[(size_t)pr * n + c0];
    bf16x8 al = *(const bf16x8*)&Alo[(size_t)pr * n + c0];
    bf16x8 gh, gl;
#pragma unroll
    for (int q = 0; q < 8; q++) {
        float v = bf2f(ah[q]) + bf2f(al[q]) + ((c0 + q == pr) ? 1.f : 0.f);
        short h = f2bf(v);
        gh[q] = h; gl[q] = f2bf(v - bf2f(h));
    }
    *(bf16x8*)&Gh[t8] = gh;
    *(bf16x8*)&Gl[t8] = gl;
}

// fp32 mirrored slices -> A hi(/lo), rowsums  (x4 vectorized)
template<bool LO>
__global__ void aug_finish_f(const float* __restrict__ Cp, int S, int kk,
                             short* __restrict__ Ahs, short* __restrict__ Als,
                             float* __restrict__ rs)
{
    int t4 = (blockIdx.x * 256 + threadIdx.x) * 4;
    int r = t4 / kk, c0 = t4 - r * kk;
    size_t stride = (size_t)kk * kk;
    f32x4 v = {0.f, 0.f, 0.f, 0.f};
    for (int s = 0; s < S; s++) v += *(const f32x4*)&Cp[t4 + s * stride];
    if (r >= c0 && r < c0 + 4) v[r - c0] = 0.f;
    s16x4 hh, ll;
    float ws = 0.f;
#pragma unroll
    for (int q = 0; q < 4; q++) {
        short h = f2bf(v[q]);
        hh[q] = h;
        if (LO) ll[q] = f2bf(v[q] - bf2f(h));
        ws += v[q];
    }
    *(s16x4*)&Ahs[t4] = hh;
    if (LO) *(s16x4*)&Als[t4] = ll;
    for (int off = 32; off; off >>= 1) ws += __shfl_down(ws, off);
    if ((threadIdx.x & 63) == 0) atomicAdd(&rs[r], ws);
}

// ---------------------------------------------------------------------------
// Host orchestration
// ---------------------------------------------------------------------------

extern "C" void kernel_launch(void* const* d_in, const int* in_sizes, int n_in,
                              void* d_out, int out_size, void* d_ws, size_t ws_size,
                              hipStream_t stream)
{
    const float* x0  = (const float*)d_in[0];
    const int*   ei  = (const int*)d_in[1];
    const float* Wd0 = (const float*)d_in[2];  const float* bd0 = (const float*)d_in[3];
    const float* Wd1 = (const float*)d_in[4];  const float* bd1 = (const float*)d_in[5];
    const float* Wd2 = (const float*)d_in[6];  const float* bd2 = (const float*)d_in[7];
    const float* Wd3 = (const float*)d_in[8];  const float* bd3 = (const float*)d_in[9];
    const float* p1  = (const float*)d_in[10];
    const float* p2  = (const float*)d_in[11];
    const float* p3  = (const float*)d_in[12];
    const float* Wu0 = (const float*)d_in[13]; const float* bu0 = (const float*)d_in[14];
    const float* Wu1 = (const float*)d_in[15]; const float* bu1 = (const float*)d_in[16];
    const float* Wu2 = (const float*)d_in[17]; const float* bu2 = (const float*)d_in[18];

    const int E = in_sizes[1] / 2;

    char* ws = (char*)d_ws;
    size_t off = 0;
    auto alloc = [&](size_t bytes) -> void* {
        void* p = ws + off;
        off += (bytes + 255) & ~(size_t)255;
        return p;
    };
    unsigned long long* M0 = (unsigned long long*)alloc((size_t)4096 * 64 * 8);
    short* A1h  = (short*)alloc((size_t)2048 * 2048 * 2);
    short* A2h  = (short*)alloc((size_t)1024 * 1024 * 2);
    short* A2l  = (short*)alloc((size_t)1024 * 1024 * 2);
    short* A3h  = (short*)alloc((size_t)512 * 512 * 2);
    short* A3l  = (short*)alloc((size_t)512 * 512 * 2);
    short* Gh   = (short*)alloc((size_t)1024 * 2048 * 2);
    short* Gl   = (short*)alloc((size_t)512 * 1024 * 2);
    int*   csr  = (int*)alloc((size_t)4096 * 128 * 4);
    unsigned long long* maskb = (unsigned long long*)alloc((size_t)2048 * 64 * 8);
    float* Zf   = (float*)alloc((size_t)4096 * 256 * 4);
    float* Cp   = (float*)alloc((size_t)64 * 1024 * 1024);   // partial arena
    float* xs0  = (float*)alloc((size_t)4096 * 256 * 4);
    float* xs1  = (float*)alloc((size_t)2048 * 256 * 4);
    float* xs2  = (float*)alloc((size_t)1024 * 256 * 4);
    float* xu0  = (float*)alloc((size_t)4096 * 256 * 4);
    float* xu1  = (float*)alloc((size_t)2048 * 256 * 4);
    float* xu2  = (float*)alloc((size_t)1024 * 256 * 4);
    short* xu0h = (short*)alloc((size_t)4096 * 256 * 2);
    short* xu0l = (short*)alloc((size_t)4096 * 256 * 2);
    short* xu1h = (short*)alloc((size_t)2048 * 256 * 2);
    short* xu1l = (short*)alloc((size_t)2048 * 256 * 2);
    short* xu2h = (short*)alloc((size_t)1024 * 256 * 2);
    short* xu2l = (short*)alloc((size_t)1024 * 256 * 2);
    short* X0h  = (short*)alloc((size_t)4096 * 128 * 2);
    short* X0l  = (short*)alloc((size_t)4096 * 128 * 2);
    short* xah  = (short*)alloc((size_t)2048 * 256 * 2);
    short* xal  = (short*)alloc((size_t)2048 * 256 * 2);
    short* Wth  = (short*)alloc((size_t)393216 * 2);
    short* Wtl  = (short*)alloc((size_t)393216 * 2);
    short* Zh   = (short*)alloc((size_t)256 * 4096 * 2);
    short* Zl   = (short*)alloc((size_t)256 * 4096 * 2);
    float* rs0  = (float*)alloc(4096 * 4);
    float* rs1  = (float*)alloc(2048 * 4);
    float* rs2  = (float*)alloc(1024 * 4);
    float* rs3  = (float*)alloc(512 * 4);
    float* scoreb = (float*)alloc(4096 * 4);
    int*   perm1  = (int*)alloc(2048 * 4);
    int*   perm2  = (int*)alloc(1024 * 4);
    int*   perm3  = (int*)alloc(512 * 4);
    int*   inv1   = (int*)alloc(4096 * 4);
    int*   inv2   = (int*)alloc(2048 * 4);
    int*   inv3   = (int*)alloc(1024 * 4);

    // dense-A GCN layer (levels 1..3): EPI3 xw -> z_reduce -> AZ -> gcn_final
    auto gcn_dense = [&](const short* Xh, const short* Xl, int n, int Kc, int Cout,
                         const short* pAh, const short* pAl, const float* rsA,
                         int wtoff, const float* b,
                         float* out, short* oh, short* ol, int relu, int modeA,
                         int Saz, const int* inv, const float* res, int nout,
                         const float* pvec) {
        int Sxw = 4;
        gemm_bt<2, 3><<<dim3(Cout / 128, n / 128, Sxw), 256, 0, stream>>>(
            Xh, Xl, Wth + wtoff, Wtl + wtoff, Cp, n, Cout, Kc, Kc / Sxw);
        z_reduce<<<(n * Cout) / 1024, 256, 0, stream>>>(Cp, Sxw, rsA, Zh, Zl, n, Cout);
        dim3 g(Cout / 128, n / 128, Saz);
        if (modeA == 1)
            gemm_bt<1, 0><<<g, 256, 0, stream>>>(pAh, nullptr, Zh, Zl, Cp, n, Cout, n, n / Saz);
        else
            gemm_bt<2, 0><<<g, 256, 0, stream>>>(pAh, pAl, Zh, Zl, Cp, n, Cout, n, n / Saz);
        if (pvec)
            gcn_final<1><<<(nout * Cout) / 1024, 256, 0, stream>>>(
                Cp, Saz, Zh, Zl, rsA, b, out, oh, ol, n, Cout, relu, inv, res,
                pvec, scoreb);
        else
            gcn_final<0><<<(nout * Cout) / 1024, 256, 0, stream>>>(
                Cp, Saz, Zh, Zl, rsA, b, out, oh, ol, n, Cout, relu, inv, res,
                nullptr, nullptr);
    };

    // fused pool: scoreb already filled by the producing kernel's epilogue
    auto pool = [&](const float* xlev, int n, int* perm, int* inv) {
        int k = n / 2;
        rank_pool<<<n / 64, 512, 0, stream>>>(scoreb, n, k, xlev, perm, inv, xah, xal);
    };

    // ---- prep (weights + x0 split + M0 zero) + bitmask adjacency + CSR ----
    prep<<<4608, 256, 0, stream>>>(Wd0, Wd1, Wd2, Wd3, Wu0, Wu1, Wu2, x0,
                                   Wth, Wtl, X0h, X0l, M0);
    build_bits<<<(E + 255) / 256, 256, 0, stream>>>(ei, E, M0);
    row_compact_bits<<<1024, 256, 0, stream>>>(M0, csr, rs0);

    // ---- down 0 (A0 sparse): x@W -> Zf -> SpMM+epilogue (+p1 score) ----
    gemm_bt<2, 0><<<dim3(2, 32, 4), 256, 0, stream>>>(
        X0h, X0l, Wth, Wtl, Cp, 4096, 256, 128, 32);
    zf_reduce<<<1024, 256, 0, stream>>>(Cp, 4, rs0, Zf, 4096, 256);
    spmm_gcn<256, 1, 1><<<1024, 256, 0, stream>>>(csr, rs0, Zf, bd0, xs0, p1, scoreb);

    // ---- level 0 -> 1: pool + fused full-K bitset popcount augment ----
    pool(xs0, 4096, perm1, inv1);
    mask_gather<<<512, 256, 0, stream>>>(M0, perm1, maskb, rs1, 2048);
    popc_aug_full<<<dim3(32, 32), 256, 0, stream>>>(maskb, 2048, A1h, rs1);
    gcn_dense(xah, xal, 2048, 256, 256, A1h, nullptr, rs1, 32768, bd1,
              xs1, nullptr, nullptr, 1, 1, 8, nullptr, nullptr, 2048, p2);

    // ---- level 1 -> 2 (dense TRI) ----
    pool(xs1, 2048, perm2, inv2);
    gatherG_h<<<(1024 * 2048 / 8) / 256, 256, 0, stream>>>(A1h, 2048, perm2, Gh, 1024, rs2);
    gemm_bt<0, 1><<<dim3(8, 8, 8), 256, 0, stream>>>(Gh, nullptr, Gh, nullptr, Cp, 1024, 1024, 2048, 256);
    aug_finish_f<true><<<(1024 * 1024 / 4) / 256, 256, 0, stream>>>(Cp, 8, 1024, A2h, A2l, rs2);
    gcn_dense(xah, xal, 1024, 256, 256, A2h, A2l, rs2, 98304, bd2,
              xs2, nullptr, nullptr, 1, 2, 8, nullptr, nullptr, 1024, p3);

    // ---- level 2 -> 3 (dense TRI) ----
    pool(xs2, 1024, perm3, inv3);
    gatherG_hl<<<(512 * 1024 / 8) / 256, 256, 0, stream>>>(A2h, A2l, 1024, perm3, Gh, Gl, 512, rs3);
    gemm_bt<2, 1><<<dim3(4, 4, 8), 256, 0, stream>>>(Gh, Gl, Gh, Gl, Cp, 512, 512, 1024, 128);
    aug_finish_f<true><<<(512 * 512 / 4) / 256, 256, 0, stream>>>(Cp, 8, 512, A3h, A3l, rs3);

    // ---- down 3: out scattered into xu2 = xs2 + u (inv3) ----
    gcn_dense(xah, xal, 512, 256, 256, A3h, A3l, rs3, 163840, bd3,
              xu2, xu2h, xu2l, 1, 2, 8, inv3, xs2, 1024, nullptr);

    // ---- up 0: out scattered into xu1 = xs1 + u (inv2) ----
    gcn_dense(xu2h, xu2l, 1024, 256, 256, A2h, A2l, rs2, 229376, bu0,
              xu1, xu1h, xu1l, 1, 2, 8, inv2, xs1, 2048, nullptr);

    // ---- up 1: out scattered into xu0 = xs0 + u (inv1) ----
    gcn_dense(xu1h, xu1l, 2048, 256, 256, A1h, nullptr, rs1, 294912, bu1,
              xu0, xu0h, xu0l, 1, 1, 8, inv1, xs0, 4096, nullptr);

    // ---- up 2 (A0 sparse, Cout=128, no relu) -> d_out ----
    gemm_bt<2, 0><<<dim3(1, 32, 8), 256, 0, stream>>>(
        xu0h, xu0l, Wth + 360448, Wtl + 360448, Cp, 4096, 128, 256, 32);
    zf_reduce<<<512, 256, 0, stream>>>(Cp, 8, rs0, Zf, 4096, 128);
    spmm_gcn<128, 0, 0><<<1024, 256, 0, stream>>>(csr, rs0, Zf, bu2, (float*)d_out,
                                                  nullptr, nullptr);
}

// Round 7
// 440.375 us; speedup vs baseline: 1.0579x; 1.0579x over previous
//
#include <hip/hip_runtime.h>

// ---------------------------------------------------------------------------
// GraphUNet on MI355X.  Round-21 = exact revert to R16 (measured best,
// 440.5 us).  R19/20's popc fusion regressed +25 us: counters showed
// popc_aug_full at 69 us/dispatch, latency-bound (VALUBusy 22%, occ 15.6%) —
// 528-block grid starved the machine and maskb re-fetch crossed XCD L2s.
// Rule extended: >=256 schedulable blocks for EVERY critical-path kernel.
//
// Structure: split-K GEMMs (Sxw=4, Saz=8, all grids >=256 blocks),
// z_reduce/zf_reduce, split popc_aug_p + aug_merge, score fused into
// producer epilogues (spmm_gcn<SC> / gcn_final<1>), rank_pool fuses
// rank+select+gather (512 threads).
// ---------------------------------------------------------------------------

typedef __attribute__((ext_vector_type(8))) short bf16x8;
typedef __attribute__((ext_vector_type(4))) short s16x4;
typedef __attribute__((ext_vector_type(4))) float f32x4;

__device__ __forceinline__ short f2bf(float f) {
    unsigned u = __builtin_bit_cast(unsigned, f);
    u += 0x7FFFu + ((u >> 16) & 1u);          // RNE
    return (short)(u >> 16);
}
__device__ __forceinline__ float bf2f(short s) {
    unsigned u = ((unsigned)(unsigned short)s) << 16;
    return __builtin_bit_cast(float, u);
}

#define GLL16(gsrc, ldst)                                                        \
    __builtin_amdgcn_global_load_lds(                                            \
        (__attribute__((address_space(1))) void*)(gsrc),                         \
        (__attribute__((address_space(3))) void*)(ldst), 16, 0, 0)

// ---------------------------------------------------------------------------
// bf16 BT GEMM: C(MxN) = A(MxK) @ B^T, B stored N x K row-major.
// MODE 0: Ah@Bh ; 1: +Ah@Bl ; 2: +Al@Bh   (lo*lo dropped, ~2^-18 rel)
// EPI 0: fp32 partial slice [z][M][N]
// EPI 1: fp32 mirrored square slices (TRI: blocks by>bx exit)
// EPI 3: fp32 TRANSPOSED partial slice [z][N][M] (f32x4 stores)
// ---------------------------------------------------------------------------
template<int MODE, int EPI>
__global__ __launch_bounds__(256, 2)
void gemm_bt(const short* __restrict__ Ah, const short* __restrict__ Al,
             const short* __restrict__ Bh, const short* __restrict__ Bl,
             float* __restrict__ Cf, int M, int N, int K, int kChunk)
{
    if (EPI == 1 && (int)blockIdx.y > (int)blockIdx.x) return;

    __shared__ short sAh[128 * 32];
    __shared__ short sBh[128 * 32];
    __shared__ short sAl[(MODE == 2) ? 128 * 32 : 8];
    __shared__ short sBl[(MODE >= 1) ? 128 * 32 : 8];

    const int t    = threadIdx.x;
    const int lane = t & 63;
    const int wave = t >> 6;
    const int tM   = blockIdx.y * 128;
    const int tN   = blockIdx.x * 128;
    const int k0   = blockIdx.z * kChunk;

    const int wm  = (wave >> 1) * 64;
    const int wn  = (wave & 1) * 64;
    const int l15 = lane & 15;
    const int g8  = (lane >> 4) * 8;

    f32x4 acc[4][4];
    const f32x4 zero = {0.f, 0.f, 0.f, 0.f};
#pragma unroll
    for (int i = 0; i < 4; i++)
#pragma unroll
        for (int j = 0; j < 4; j++) acc[i][j] = zero;

    const int i0 = t, i1 = t + 256;
    const short* a0 = Ah + (size_t)(tM + (i0 >> 2)) * K + (i0 & 3) * 8;
    const short* a1 = Ah + (size_t)(tM + (i1 >> 2)) * K + (i1 & 3) * 8;
    const short* b0 = Bh + (size_t)(tN + (i0 >> 2)) * K + (i0 & 3) * 8;
    const short* b1 = Bh + (size_t)(tN + (i1 >> 2)) * K + (i1 & 3) * 8;
    const short *bl0 = nullptr, *bl1 = nullptr, *al0 = nullptr, *al1 = nullptr;
    if (MODE >= 1) {
        bl0 = Bl + (size_t)(tN + (i0 >> 2)) * K + (i0 & 3) * 8;
        bl1 = Bl + (size_t)(tN + (i1 >> 2)) * K + (i1 & 3) * 8;
    }
    if (MODE == 2) {
        al0 = Al + (size_t)(tM + (i0 >> 2)) * K + (i0 & 3) * 8;
        al1 = Al + (size_t)(tM + (i1 >> 2)) * K + (i1 & 3) * 8;
    }

    for (int kb = k0; kb < k0 + kChunk; kb += 32) {
        GLL16(a0 + kb, &sAh[i0 * 8]);
        GLL16(a1 + kb, &sAh[i1 * 8]);
        GLL16(b0 + kb, &sBh[i0 * 8]);
        GLL16(b1 + kb, &sBh[i1 * 8]);
        if (MODE >= 1) { GLL16(bl0 + kb, &sBl[i0 * 8]); GLL16(bl1 + kb, &sBl[i1 * 8]); }
        if (MODE == 2) { GLL16(al0 + kb, &sAl[i0 * 8]); GLL16(al1 + kb, &sAl[i1 * 8]); }
        __syncthreads();

        bf16x8 aF[4], bF[4], aL[4], bL[4];
#pragma unroll
        for (int i = 0; i < 4; i++)
            aF[i] = *(const bf16x8*)&sAh[(wm + i * 16 + l15) * 32 + g8];
#pragma unroll
        for (int j = 0; j < 4; j++)
            bF[j] = *(const bf16x8*)&sBh[(wn + j * 16 + l15) * 32 + g8];
        if (MODE >= 1)
#pragma unroll
            for (int j = 0; j < 4; j++)
                bL[j] = *(const bf16x8*)&sBl[(wn + j * 16 + l15) * 32 + g8];
        if (MODE == 2)
#pragma unroll
            for (int i = 0; i < 4; i++)
                aL[i] = *(const bf16x8*)&sAl[(wm + i * 16 + l15) * 32 + g8];

#pragma unroll
        for (int i = 0; i < 4; i++)
#pragma unroll
            for (int j = 0; j < 4; j++) {
                acc[i][j] = __builtin_amdgcn_mfma_f32_16x16x32_bf16(aF[i], bF[j], acc[i][j], 0, 0, 0);
                if (MODE >= 1)
                    acc[i][j] = __builtin_amdgcn_mfma_f32_16x16x32_bf16(aF[i], bL[j], acc[i][j], 0, 0, 0);
                if (MODE == 2)
                    acc[i][j] = __builtin_amdgcn_mfma_f32_16x16x32_bf16(aL[i], bF[j], acc[i][j], 0, 0, 0);
            }
        __syncthreads();
    }

    // C/D layout: col=lane&15, row=(lane>>4)*4+reg  [m89-verified]
    const int r4 = (lane >> 4) * 4;
    if (EPI == 3) {
        float* CT = Cf + (size_t)blockIdx.z * M * N;   // [N][M]
#pragma unroll
        for (int i = 0; i < 4; i++)
#pragma unroll
            for (int j = 0; j < 4; j++) {
                const int col   = tN + wn + j * 16 + l15;
                const int rbase = tM + wm + i * 16 + r4;
                *(f32x4*)&CT[(size_t)col * M + rbase] = acc[i][j];
            }
    } else {
        float* Cg = Cf + (size_t)blockIdx.z * M * N;
#pragma unroll
        for (int i = 0; i < 4; i++)
#pragma unroll
            for (int j = 0; j < 4; j++) {
                const int col = tN + wn + j * 16 + l15;
                float* cp = Cg + (size_t)(tM + wm + i * 16 + r4) * N + col;
#pragma unroll
                for (int r = 0; r < 4; r++) cp[(size_t)r * N] = acc[i][j][r];
            }
        if (EPI == 1 && tM != tN) {
#pragma unroll
            for (int i = 0; i < 4; i++)
#pragma unroll
                for (int j = 0; j < 4; j++) {
                    const int col   = tN + wn + j * 16 + l15;
                    const int rbase = tM + wm + i * 16 + r4;
                    *(f32x4*)&Cg[(size_t)col * N + rbase] = acc[i][j];
                }
        }
    }
}

// ---------------------------------------------------------------------------
// Utility kernels
// ---------------------------------------------------------------------------

// one-shot prep: W^T hi/lo for all 7 layers + x0 hi/lo split + zero M0 bitmask
__global__ void prep(const float* __restrict__ Wd0, const float* __restrict__ Wd1,
                     const float* __restrict__ Wd2, const float* __restrict__ Wd3,
                     const float* __restrict__ Wu0, const float* __restrict__ Wu1,
                     const float* __restrict__ Wu2, const float* __restrict__ x0,
                     short* __restrict__ Wth, short* __restrict__ Wtl,
                     short* __restrict__ Xh, short* __restrict__ Xl,
                     unsigned long long* __restrict__ M0)
{
    int t = blockIdx.x * 256 + threadIdx.x;
    float v; int dst;
    if (t < 32768)       { int e = t;          v = Wd0[e]; dst = 0      + (e & 255) * 128 + (e >> 8); }
    else if (t < 98304)  { int e = t - 32768;  v = Wd1[e]; dst = 32768  + (e & 255) * 256 + (e >> 8); }
    else if (t < 163840) { int e = t - 98304;  v = Wd2[e]; dst = 98304  + (e & 255) * 256 + (e >> 8); }
    else if (t < 229376) { int e = t - 163840; v = Wd3[e]; dst = 163840 + (e & 255) * 256 + (e >> 8); }
    else if (t < 294912) { int e = t - 229376; v = Wu0[e]; dst = 229376 + (e & 255) * 256 + (e >> 8); }
    else if (t < 360448) { int e = t - 294912; v = Wu1[e]; dst = 294912 + (e & 255) * 256 + (e >> 8); }
    else if (t < 393216) { int e = t - 360448; v = Wu2[e]; dst = 360448 + (e & 127) * 256 + (e >> 7); }
    else if (t < 917504) {
        int e = t - 393216;                      // x0: 4096*128
        v = x0[e];
        short h = f2bf(v);
        Xh[e] = h; Xl[e] = f2bf(v - bf2f(h));
        return;
    } else {
        M0[t - 917504] = 0ull;                   // 4096*64 words
        return;
    }
    short h = f2bf(v);
    Wth[dst] = h; Wtl[dst] = f2bf(v - bf2f(h));
}

// edge list -> symmetric self-loop-free row bitmask (dedup for free)
__global__ void build_bits(const int* __restrict__ ei, int E,
                           unsigned long long* __restrict__ M0)
{
    int e = blockIdx.x * 256 + threadIdx.x;
    if (e >= E) return;
    int i = ei[e], j = ei[E + e];
    if (i != j) {
        atomicOr(&M0[(size_t)i * 64 + (j >> 6)], 1ull << (j & 63));
        atomicOr(&M0[(size_t)j * 64 + (i >> 6)], 1ull << (i & 63));
    }
}

// bitmask -> CSR (<=128 nnz/row, ascending) + degree, via wave prefix scan
__global__ void row_compact_bits(const unsigned long long* __restrict__ M0,
                                 int* __restrict__ csr, float* __restrict__ rs)
{
    int row = blockIdx.x * 4 + (threadIdx.x >> 6);
    int lane = threadIdx.x & 63;
    unsigned long long w = M0[(size_t)row * 64 + lane];
    int c = __popcll(w);
    int incl = c;
    for (int off = 1; off < 64; off <<= 1) {
        int v = __shfl_up(incl, off);
        if (lane >= off) incl += v;
    }
    int base = incl - c;
    int* out = csr + (size_t)row * 128;
    while (w) {
        int b = __ffsll((unsigned long long)w) - 1;
        if (base < 128) out[base] = lane * 64 + b;
        base++;
        w &= w - 1;
    }
    if (lane == 63) rs[row] = (float)incl;
}

// L0 popcount masks: gather selected M0 rows + self bit; zero rs1
__global__ void mask_gather(const unsigned long long* __restrict__ M0,
                            const int* __restrict__ perm,
                            unsigned long long* __restrict__ mask,
                            float* __restrict__ rs, int kk)
{
    int t = blockIdx.x * 256 + threadIdx.x;
    if (t < kk) rs[t] = 0.f;
    int r = t >> 6, l = t & 63;
    int u = perm[r];
    unsigned long long w = M0[(size_t)u * 64 + l];
    if ((u >> 6) == l) w |= 1ull << (u & 63);
    mask[t] = w;
}

// popcount partial: slice z covers words [z*16, z*16+16).  64x64 TRI tiles,
// 18 KB LDS -> 8 blocks/CU.  int16 partial tile at Cp[(z*1024 + by*32+bx)*4096].
#define PSTR2 18
__global__ __launch_bounds__(256, 8)
void popc_aug_p(const unsigned long long* __restrict__ mask,
                short* __restrict__ Cp)
{
    const int bx = blockIdx.x, by = blockIdx.y, z = blockIdx.z;
    if (by > bx) return;
    __shared__ unsigned long long a[64 * PSTR2];
    __shared__ unsigned long long b[64 * PSTR2];
    const int t = threadIdx.x;
#pragma unroll
    for (int p = 0; p < 4; p++) {
        int idx = p * 256 + t;           // 0..1023 = rr*16 + w
        int rr = idx >> 4, w = idx & 15;
        a[rr * PSTR2 + w] = mask[((size_t)(by * 64 + rr)) * 64 + z * 16 + w];
        b[rr * PSTR2 + w] = mask[((size_t)(bx * 64 + rr)) * 64 + z * 16 + w];
    }
    __syncthreads();
    const int i0 = (t >> 4) * 4;         // 4 consecutive rows
    const int j0 = t & 15;               // cols j0 + 16*qj
    int acc[4][4];
#pragma unroll
    for (int qi = 0; qi < 4; qi++)
#pragma unroll
        for (int qj = 0; qj < 4; qj++) acc[qi][qj] = 0;
#pragma unroll
    for (int w = 0; w < 16; w += 2) {
        ulong2 av[4], bv[4];
#pragma unroll
        for (int q = 0; q < 4; q++) av[q] = *(const ulong2*)&a[(i0 + q) * PSTR2 + w];
#pragma unroll
        for (int q = 0; q < 4; q++) bv[q] = *(const ulong2*)&b[(j0 + 16 * q) * PSTR2 + w];
#pragma unroll
        for (int qi = 0; qi < 4; qi++)
#pragma unroll
            for (int qj = 0; qj < 4; qj++) {
                acc[qi][qj] += __builtin_popcountll(av[qi].x & bv[qj].x);
                acc[qi][qj] += __builtin_popcountll(av[qi].y & bv[qj].y);
            }
    }
    short* out = Cp + ((size_t)z * 1024 + (size_t)(by * 32 + bx)) * 4096;
#pragma unroll
    for (int qi = 0; qi < 4; qi++)
#pragma unroll
        for (int qj = 0; qj < 4; qj++)
            out[(i0 + qi) * 64 + j0 + 16 * qj] = (short)acc[qi][qj];
}

// merge 4 int16 slices -> A1h (bf16, diag 0) + LDS-transposed mirror + rowsums
__global__ __launch_bounds__(256)
void aug_merge(const short* __restrict__ Cp, int kk,
               short* __restrict__ Ahs, float* __restrict__ rs)
{
    const int bx = blockIdx.x, by = blockIdx.y;
    if (by > bx) return;
    __shared__ float tile[64][65];
    __shared__ float rsum[64], csum[64];
    const int t = threadIdx.x;
    const int i  = t >> 2;               // row 0..63
    const int c0 = (t & 3) * 16;         // 16 consecutive cols
    const size_t tb = (size_t)(by * 32 + bx) * 4096;
    const size_t ss = (size_t)1024 * 4096;
    if (t < 64) { rsum[t] = 0.f; csum[t] = 0.f; }

    int v[16];
#pragma unroll
    for (int q = 0; q < 16; q++) v[q] = 0;
    for (int s = 0; s < 4; s++) {
        bf16x8 p0 = *(const bf16x8*)&Cp[tb + s * ss + i * 64 + c0];
        bf16x8 p1 = *(const bf16x8*)&Cp[tb + s * ss + i * 64 + c0 + 8];
#pragma unroll
        for (int q = 0; q < 8; q++) { v[q] += (int)p0[q]; v[8 + q] += (int)p1[q]; }
    }
    const int gi = by * 64 + i;
    float rp = 0.f;
    s16x4 pk[4];
#pragma unroll
    for (int q = 0; q < 16; q++) {
        const int gj = bx * 64 + c0 + q;
        float val = (gi == gj) ? 0.f : (float)v[q];
        tile[i][c0 + q] = val;
        rp += val;
        pk[q >> 2][q & 3] = f2bf(val);
    }
#pragma unroll
    for (int q = 0; q < 4; q++)
        *(s16x4*)&Ahs[(size_t)gi * kk + bx * 64 + c0 + q * 4] = pk[q];
    __syncthreads();
    atomicAdd(&rsum[i], rp);
    if (bx != by) {
        float cpv = 0.f;
#pragma unroll
        for (int q = 0; q < 16; q++) {
            float val = tile[c0 + q][i];
            cpv += val;
            pk[q >> 2][q & 3] = f2bf(val);
        }
#pragma unroll
        for (int q = 0; q < 4; q++)
            *(s16x4*)&Ahs[(size_t)(bx * 64 + i) * kk + by * 64 + c0 + q * 4] = pk[q];
        atomicAdd(&csum[i], cpv);
    }
    __syncthreads();
    if (t < 64) {
        atomicAdd(&rs[by * 64 + t], rsum[t]);
        if (bx != by) atomicAdd(&rs[bx * 64 + t], csum[t]);
    }
}

// reduce transposed xw partial slices -> Z^T hi/lo  (x4 vectorized)
__global__ void z_reduce(const float* __restrict__ Cp, int S,
                         const float* __restrict__ rs,
                         short* __restrict__ Zh, short* __restrict__ Zl,
                         int n, int C)
{
    int t4 = (blockIdx.x * 256 + threadIdx.x) * 4;   // t = c*n + r layout
    int r = t4 % n;
    size_t stride = (size_t)n * C;
    f32x4 v = {0.f, 0.f, 0.f, 0.f};
    for (int s = 0; s < S; s++) v += *(const f32x4*)&Cp[t4 + s * stride];
    f32x4 rsv = *(const f32x4*)&rs[r];
    s16x4 zh, zl;
#pragma unroll
    for (int q = 0; q < 4; q++) {
        float z = v[q] / sqrtf(rsv[q] + 2.f);
        short h = f2bf(z);
        zh[q] = h; zl[q] = f2bf(z - bf2f(h));
    }
    *(s16x4*)&Zh[t4] = zh;
    *(s16x4*)&Zl[t4] = zl;
}

// reduce row-major xw partial slices -> Zf fp32 [r][C]  (x4 vectorized)
__global__ void zf_reduce(const float* __restrict__ Cp, int S,
                          const float* __restrict__ rs,
                          float* __restrict__ Zf, int n, int C)
{
    int t4 = (blockIdx.x * 256 + threadIdx.x) * 4;   // t = r*C + c
    int r = t4 / C;
    size_t stride = (size_t)n * C;
    f32x4 v = {0.f, 0.f, 0.f, 0.f};
    for (int s = 0; s < S; s++) v += *(const f32x4*)&Cp[t4 + s * stride];
    float d = 1.f / sqrtf(rs[r] + 2.f);
    v *= d;
    *(f32x4*)&Zf[t4] = v;
}

// CSR SpMM + fused GCN epilogue (+ optional fused pool score: SC=1)
template<int CN, int RELU, int SC>
__global__ __launch_bounds__(256)
void spmm_gcn(const int* __restrict__ csr, const float* __restrict__ rs,
              const float* __restrict__ Zf, const float* __restrict__ b,
              float* __restrict__ out,
              const float* __restrict__ pvec, float* __restrict__ score)
{
    const int lane = threadIdx.x & 63;
    const int row  = blockIdx.x * 4 + (threadIdx.x >> 6);
    const int dg   = (int)rs[row];
    const int* nb  = csr + (size_t)row * 128;
    if (CN == 256) {
        const int c = lane * 4;
        float4 acc = {0.f, 0.f, 0.f, 0.f};
        int q = 0;
        for (; q + 4 <= dg; q += 4) {
            int j0 = nb[q], j1 = nb[q+1], j2 = nb[q+2], j3 = nb[q+3];
            float4 z0 = *(const float4*)&Zf[(size_t)j0 * CN + c];
            float4 z1 = *(const float4*)&Zf[(size_t)j1 * CN + c];
            float4 z2 = *(const float4*)&Zf[(size_t)j2 * CN + c];
            float4 z3 = *(const float4*)&Zf[(size_t)j3 * CN + c];
            acc.x += z0.x; acc.y += z0.y; acc.z += z0.z; acc.w += z0.w;
            acc.x += z1.x; acc.y += z1.y; acc.z += z1.z; acc.w += z1.w;
            acc.x += z2.x; acc.y += z2.y; acc.z += z2.z; acc.w += z2.w;
            acc.x += z3.x; acc.y += z3.y; acc.z += z3.z; acc.w += z3.w;
        }
        for (; q < dg; q++) {
            float4 z = *(const float4*)&Zf[(size_t)nb[q] * CN + c];
            acc.x += z.x; acc.y += z.y; acc.z += z.z; acc.w += z.w;
        }
        float d = 1.f / sqrtf(rs[row] + 2.f);
        float4 zi = *(const float4*)&Zf[(size_t)row * CN + c];
        float4 bb = *(const float4*)&b[c];
        float4 g;
        g.x = d * acc.x + 2.f * d * zi.x + bb.x;
        g.y = d * acc.y + 2.f * d * zi.y + bb.y;
        g.z = d * acc.z + 2.f * d * zi.z + bb.z;
        g.w = d * acc.w + 2.f * d * zi.w + bb.w;
        if (RELU) {
            g.x = fmaxf(g.x, 0.f); g.y = fmaxf(g.y, 0.f);
            g.z = fmaxf(g.z, 0.f); g.w = fmaxf(g.w, 0.f);
        }
        *(float4*)&out[(size_t)row * CN + c] = g;
        if (SC) {
            float4 pv = ((const float4*)pvec)[lane];
            double nn  = (double)pv.x * pv.x + (double)pv.y * pv.y +
                         (double)pv.z * pv.z + (double)pv.w * pv.w;
            double acd = (double)g.x * pv.x + (double)g.y * pv.y +
                         (double)g.z * pv.z + (double)g.w * pv.w;
            for (int off = 32; off; off >>= 1) {
                acd += __shfl_down(acd, off);
                nn  += __shfl_down(nn, off);
            }
            if (lane == 0) score[row] = tanhf((float)(acd / sqrt(nn)));
        }
    } else {
        const int c = lane * 2;
        float2 acc = {0.f, 0.f};
        int q = 0;
        for (; q + 4 <= dg; q += 4) {
            int j0 = nb[q], j1 = nb[q+1], j2 = nb[q+2], j3 = nb[q+3];
            float2 z0 = *(const float2*)&Zf[(size_t)j0 * CN + c];
            float2 z1 = *(const float2*)&Zf[(size_t)j1 * CN + c];
            float2 z2 = *(const float2*)&Zf[(size_t)j2 * CN + c];
            float2 z3 = *(const float2*)&Zf[(size_t)j3 * CN + c];
            acc.x += z0.x; acc.y += z0.y;
            acc.x += z1.x; acc.y += z1.y;
            acc.x += z2.x; acc.y += z2.y;
            acc.x += z3.x; acc.y += z3.y;
        }
        for (; q < dg; q++) {
            float2 z = *(const float2*)&Zf[(size_t)nb[q] * CN + c];
            acc.x += z.x; acc.y += z.y;
        }
        float d = 1.f / sqrtf(rs[row] + 2.f);
        float2 zi = *(const float2*)&Zf[(size_t)row * CN + c];
        float2 g;
        g.x = d * acc.x + 2.f * d * zi.x + b[c];
        g.y = d * acc.y + 2.f * d * zi.y + b[c + 1];
        if (RELU) { g.x = fmaxf(g.x, 0.f); g.y = fmaxf(g.y, 0.f); }
        *(float2*)&out[(size_t)row * CN + c] = g;
    }
}

// fused: reduce AZ slices + GCN epilogue (+inv scatter) (+compile-time score)
template<int SC>
__global__ void gcn_final(const float* __restrict__ Cp, int S,
                          const short* __restrict__ Zh, const short* __restrict__ Zl,
                          const float* __restrict__ rs, const float* __restrict__ b,
                          float* __restrict__ out, short* __restrict__ oh,
                          short* __restrict__ ol, int k, int C, int relu,
                          const int* __restrict__ inv, const float* __restrict__ res,
                          const float* __restrict__ pvec, float* __restrict__ score)
{
    int t4 = (blockIdx.x * 256 + threadIdx.x) * 4;
    int j = t4 / C, c = t4 - j * C;
    int r = inv ? inv[j] : j;
    f32x4 v = res ? *(const f32x4*)&res[t4] : (f32x4){0.f, 0.f, 0.f, 0.f};
    if (r >= 0) {
        size_t base = (size_t)r * C + c;
        size_t stride = (size_t)k * C;
        f32x4 az = {0.f, 0.f, 0.f, 0.f};
        for (int s = 0; s < S; s++) az += *(const f32x4*)&Cp[base + s * stride];
        float d = 1.f / sqrtf(rs[r] + 2.f);
        f32x4 bb = *(const f32x4*)&b[c];
#pragma unroll
        for (int q = 0; q < 4; q++) {
            size_t zi = (size_t)(c + q) * k + r;
            float zz = bf2f(Zh[zi]) + bf2f(Zl[zi]);      // zz ~= d * xw
            float g = d * az[q] + 2.f * d * zz + bb[q];
            if (relu && g < 0.f) g = 0.f;
            v[q] += g;
        }
    }
    *(f32x4*)&out[t4] = v;
    if (oh) {
        s16x4 hh, ll;
#pragma unroll
        for (int q = 0; q < 4; q++) {
            short h = f2bf(v[q]);
            hh[q] = h; ll[q] = f2bf(v[q] - bf2f(h));
        }
        *(s16x4*)&oh[t4] = hh;
        *(s16x4*)&ol[t4] = ll;
    }
    if (SC) {
        // C==256: one wave per row (64 lanes x 4 cols) -> free score reduce,
        // math identical to the old score_kernel (double dot / double norm).
        const int lane = threadIdx.x & 63;
        float4 pv = *(const float4*)&pvec[c];
        double nn  = (double)pv.x * pv.x + (double)pv.y * pv.y +
                     (double)pv.z * pv.z + (double)pv.w * pv.w;
        double acd = (double)v[0] * pv.x + (double)v[1] * pv.y +
                     (double)v[2] * pv.z + (double)v[3] * pv.w;
        for (int off = 32; off; off >>= 1) {
            acd += __shfl_down(acd, off);
            nn  += __shfl_down(nn, off);
        }
        if (lane == 0) score[j] = tanhf((float)(acd / sqrt(nn)));
    }
}

__device__ __forceinline__ unsigned long long packkey(float s, int i) {
    unsigned u = __builtin_bit_cast(unsigned, s);
    u = (u & 0x80000000u) ? ~u : (u | 0x80000000u);
    return ((unsigned long long)u << 32) | (unsigned)(0xFFFFFFFFu - (unsigned)i);
}

// fused rank + select + gather: block owns 64 rows; scans all n keys from LDS
// chunks (512 threads = 8 j-slices); then scatter-writes perm/inv and the
// gathered+scaled hi/lo x rows (wave per selected row, C=256).
__global__ __launch_bounds__(512)
void rank_pool(const float* __restrict__ score, int n, int k,
               const float* __restrict__ xold,
               int* __restrict__ perm, int* __restrict__ inv,
               short* __restrict__ Xh, short* __restrict__ Xl)
{
    __shared__ unsigned long long sk[512];
    __shared__ int rk[64];
    __shared__ int selrow[64];
    __shared__ int selrank[64];
    __shared__ float selval[64];
    __shared__ int cnt;
    const int t  = threadIdx.x;
    const int il = t & 63;            // local row
    const int js = t >> 6;            // j-slice (8 slices of 64)
    const int i  = blockIdx.x * 64 + il;
    if (t < 64) rk[t] = 0;
    if (t == 0) cnt = 0;
    const unsigned long long mykey = packkey(score[i], i);
    int r = 0;
    for (int jb = 0; jb < n; jb += 512) {
        __syncthreads();
        if (jb + t < n) sk[t] = packkey(score[jb + t], jb + t);
        __syncthreads();
        const unsigned long long* p = &sk[js * 64];
#pragma unroll 16
        for (int q = 0; q < 64; q++) r += (p[q] > mykey) ? 1 : 0;
    }
    atomicAdd(&rk[il], r);
    __syncthreads();
    if (t < 64) {
        int rank = rk[t];
        int ii = blockIdx.x * 64 + t;
        inv[ii] = (rank < k) ? rank : -1;
        if (rank < k) {
            perm[rank] = ii;
            int s = atomicAdd(&cnt, 1);
            selrow[s]  = ii;
            selrank[s] = rank;
            selval[s]  = score[ii];
        }
    }
    __syncthreads();
    const int wave = t >> 6, lane = t & 63;
    for (int s = wave; s < cnt; s += 8) {
        const int   row = selrow[s];
        const float vv  = selval[s];
        f32x4 x = *(const f32x4*)&xold[(size_t)row * 256 + lane * 4];
        s16x4 hh, ll;
#pragma unroll
        for (int q = 0; q < 4; q++) {
            float v = x[q] * vv;
            short h = f2bf(v);
            hh[q] = h; ll[q] = f2bf(v - bf2f(h));
        }
        size_t o = (size_t)selrank[s] * 256 + lane * 4;
        *(s16x4*)&Xh[o] = hh;
        *(s16x4*)&Xl[o] = ll;
    }
}

// G = (A+I)[perm,:] from bf16 A (small-int exact); zeroes rs_next  (x8 vec)
__global__ void gatherG_h(const short* __restrict__ A, int n,
                          const int* __restrict__ perm,
                          short* __restrict__ Gh, int kk,
                          float* __restrict__ rsz)
{
    int idx = blockIdx.x * 256 + threadIdx.x;
    if (idx < kk) rsz[idx] = 0.f;
    int t8 = idx * 8;
    if (t8 >= kk * n) return;
    int r = t8 / n, c0 = t8 - r * n;
    int pr = perm[r];
    bf16x8 a = *(const bf16x8*)&A[(size_t)pr * n + c0];
    if (pr >= c0 && pr < c0 + 8)
        a[pr - c0] = f2bf(bf2f(a[pr - c0]) + 1.f);
    *(bf16x8*)&Gh[t8] = a;
}

__global__ void gatherG_hl(const short* __restrict__ Ahi, const short* __restrict__ Alo,
                           int n, const int* __restrict__ perm,
                           short* __restrict__ Gh, short* __restrict__ Gl, int kk,
                           float* __restrict__ rsz)
{
    int idx = blockIdx.x * 256 + threadIdx.x;
    if (idx < kk) rsz[idx] = 0.f;
    int t8 = idx * 8;
    if (t8 >= kk * n) return;
    int r = t8 / n, c0 = t8 - r * n;
    int pr = perm[r];
    bf16x8 ah = *(const bf16x8*)&Ahi[(size_t)pr * n + c0];
    bf16x8 al = *(const bf16x8*)&Alo[(size_t)pr * n + c0];
    bf16x8 gh, gl;
#pragma unroll
    for (int q = 0; q < 8; q++) {
        float v = bf2f(ah[q]) + bf2f(al[q]) + ((c0 + q == pr) ? 1.f : 0.f);
        short h = f2bf(v);
        gh[q] = h; gl[q] = f2bf(v - bf2f(h));
    }
    *(bf16x8*)&Gh[t8] = gh;
    *(bf16x8*)&Gl[t8] = gl;
}

// fp32 mirrored slices -> A hi(/lo), rowsums  (x4 vectorized)
template<bool LO>
__global__ void aug_finish_f(const float* __restrict__ Cp, int S, int kk,
                             short* __restrict__ Ahs, short* __restrict__ Als,
                             float* __restrict__ rs)
{
    int t4 = (blockIdx.x * 256 + threadIdx.x) * 4;
    int r = t4 / kk, c0 = t4 - r * kk;
    size_t stride = (size_t)kk * kk;
    f32x4 v = {0.f, 0.f, 0.f, 0.f};
    for (int s = 0; s < S; s++) v += *(const f32x4*)&Cp[t4 + s * stride];
    if (r >= c0 && r < c0 + 4) v[r - c0] = 0.f;
    s16x4 hh, ll;
    float ws = 0.f;
#pragma unroll
    for (int q = 0; q < 4; q++) {
        short h = f2bf(v[q]);
        hh[q] = h;
        if (LO) ll[q] = f2bf(v[q] - bf2f(h));
        ws += v[q];
    }
    *(s16x4*)&Ahs[t4] = hh;
    if (LO) *(s16x4*)&Als[t4] = ll;
    for (int off = 32; off; off >>= 1) ws += __shfl_down(ws, off);
    if ((threadIdx.x & 63) == 0) atomicAdd(&rs[r], ws);
}

// ---------------------------------------------------------------------------
// Host orchestration
// ---------------------------------------------------------------------------

extern "C" void kernel_launch(void* const* d_in, const int* in_sizes, int n_in,
                              void* d_out, int out_size, void* d_ws, size_t ws_size,
                              hipStream_t stream)
{
    const float* x0  = (const float*)d_in[0];
    const int*   ei  = (const int*)d_in[1];
    const float* Wd0 = (const float*)d_in[2];  const float* bd0 = (const float*)d_in[3];
    const float* Wd1 = (const float*)d_in[4];  const float* bd1 = (const float*)d_in[5];
    const float* Wd2 = (const float*)d_in[6];  const float* bd2 = (const float*)d_in[7];
    const float* Wd3 = (const float*)d_in[8];  const float* bd3 = (const float*)d_in[9];
    const float* p1  = (const float*)d_in[10];
    const float* p2  = (const float*)d_in[11];
    const float* p3  = (const float*)d_in[12];
    const float* Wu0 = (const float*)d_in[13]; const float* bu0 = (const float*)d_in[14];
    const float* Wu1 = (const float*)d_in[15]; const float* bu1 = (const float*)d_in[16];
    const float* Wu2 = (const float*)d_in[17]; const float* bu2 = (const float*)d_in[18];

    const int E = in_sizes[1] / 2;

    char* ws = (char*)d_ws;
    size_t off = 0;
    auto alloc = [&](size_t bytes) -> void* {
        void* p = ws + off;
        off += (bytes + 255) & ~(size_t)255;
        return p;
    };
    unsigned long long* M0 = (unsigned long long*)alloc((size_t)4096 * 64 * 8);
    short* A1h  = (short*)alloc((size_t)2048 * 2048 * 2);
    short* A2h  = (short*)alloc((size_t)1024 * 1024 * 2);
    short* A2l  = (short*)alloc((size_t)1024 * 1024 * 2);
    short* A3h  = (short*)alloc((size_t)512 * 512 * 2);
    short* A3l  = (short*)alloc((size_t)512 * 512 * 2);
    short* Gh   = (short*)alloc((size_t)1024 * 2048 * 2);
    short* Gl   = (short*)alloc((size_t)512 * 1024 * 2);
    int*   csr  = (int*)alloc((size_t)4096 * 128 * 4);
    unsigned long long* maskb = (unsigned long long*)alloc((size_t)2048 * 64 * 8);
    float* Zf   = (float*)alloc((size_t)4096 * 256 * 4);
    float* Cp   = (float*)alloc((size_t)64 * 1024 * 1024);   // partial arena
    float* xs0  = (float*)alloc((size_t)4096 * 256 * 4);
    float* xs1  = (float*)alloc((size_t)2048 * 256 * 4);
    float* xs2  = (float*)alloc((size_t)1024 * 256 * 4);
    float* xu0  = (float*)alloc((size_t)4096 * 256 * 4);
    float* xu1  = (float*)alloc((size_t)2048 * 256 * 4);
    float* xu2  = (float*)alloc((size_t)1024 * 256 * 4);
    short* xu0h = (short*)alloc((size_t)4096 * 256 * 2);
    short* xu0l = (short*)alloc((size_t)4096 * 256 * 2);
    short* xu1h = (short*)alloc((size_t)2048 * 256 * 2);
    short* xu1l = (short*)alloc((size_t)2048 * 256 * 2);
    short* xu2h = (short*)alloc((size_t)1024 * 256 * 2);
    short* xu2l = (short*)alloc((size_t)1024 * 256 * 2);
    short* X0h  = (short*)alloc((size_t)4096 * 128 * 2);
    short* X0l  = (short*)alloc((size_t)4096 * 128 * 2);
    short* xah  = (short*)alloc((size_t)2048 * 256 * 2);
    short* xal  = (short*)alloc((size_t)2048 * 256 * 2);
    short* Wth  = (short*)alloc((size_t)393216 * 2);
    short* Wtl  = (short*)alloc((size_t)393216 * 2);
    short* Zh   = (short*)alloc((size_t)256 * 4096 * 2);
    short* Zl   = (short*)alloc((size_t)256 * 4096 * 2);
    float* rs0  = (float*)alloc(4096 * 4);
    float* rs1  = (float*)alloc(2048 * 4);
    float* rs2  = (float*)alloc(1024 * 4);
    float* rs3  = (float*)alloc(512 * 4);
    float* scoreb = (float*)alloc(4096 * 4);
    int*   perm1  = (int*)alloc(2048 * 4);
    int*   perm2  = (int*)alloc(1024 * 4);
    int*   perm3  = (int*)alloc(512 * 4);
    int*   inv1   = (int*)alloc(4096 * 4);
    int*   inv2   = (int*)alloc(2048 * 4);
    int*   inv3   = (int*)alloc(1024 * 4);

    // dense-A GCN layer (levels 1..3): EPI3 xw -> z_reduce -> AZ -> gcn_final
    auto gcn_dense = [&](const short* Xh, const short* Xl, int n, int Kc, int Cout,
                         const short* pAh, const short* pAl, const float* rsA,
                         int wtoff, const float* b,
                         float* out, short* oh, short* ol, int relu, int modeA,
                         int Saz, const int* inv, const float* res, int nout,
                         const float* pvec) {
        int Sxw = 4;
        gemm_bt<2, 3><<<dim3(Cout / 128, n / 128, Sxw), 256, 0, stream>>>(
            Xh, Xl, Wth + wtoff, Wtl + wtoff, Cp, n, Cout, Kc, Kc / Sxw);
        z_reduce<<<(n * Cout) / 1024, 256, 0, stream>>>(Cp, Sxw, rsA, Zh, Zl, n, Cout);
        dim3 g(Cout / 128, n / 128, Saz);
        if (modeA == 1)
            gemm_bt<1, 0><<<g, 256, 0, stream>>>(pAh, nullptr, Zh, Zl, Cp, n, Cout, n, n / Saz);
        else
            gemm_bt<2, 0><<<g, 256, 0, stream>>>(pAh, pAl, Zh, Zl, Cp, n, Cout, n, n / Saz);
        if (pvec)
            gcn_final<1><<<(nout * Cout) / 1024, 256, 0, stream>>>(
                Cp, Saz, Zh, Zl, rsA, b, out, oh, ol, n, Cout, relu, inv, res,
                pvec, scoreb);
        else
            gcn_final<0><<<(nout * Cout) / 1024, 256, 0, stream>>>(
                Cp, Saz, Zh, Zl, rsA, b, out, oh, ol, n, Cout, relu, inv, res,
                nullptr, nullptr);
    };

    // fused pool: scoreb already filled by the producing kernel's epilogue
    auto pool = [&](const float* xlev, int n, int* perm, int* inv) {
        int k = n / 2;
        rank_pool<<<n / 64, 512, 0, stream>>>(scoreb, n, k, xlev, perm, inv, xah, xal);
    };

    // ---- prep (weights + x0 split + M0 zero) + bitmask adjacency + CSR ----
    prep<<<4608, 256, 0, stream>>>(Wd0, Wd1, Wd2, Wd3, Wu0, Wu1, Wu2, x0,
                                   Wth, Wtl, X0h, X0l, M0);
    build_bits<<<(E + 255) / 256, 256, 0, stream>>>(ei, E, M0);
    row_compact_bits<<<1024, 256, 0, stream>>>(M0, csr, rs0);

    // ---- down 0 (A0 sparse): x@W -> Zf -> SpMM+epilogue (+p1 score) ----
    gemm_bt<2, 0><<<dim3(2, 32, 4), 256, 0, stream>>>(
        X0h, X0l, Wth, Wtl, Cp, 4096, 256, 128, 32);
    zf_reduce<<<1024, 256, 0, stream>>>(Cp, 4, rs0, Zf, 4096, 256);
    spmm_gcn<256, 1, 1><<<1024, 256, 0, stream>>>(csr, rs0, Zf, bd0, xs0, p1, scoreb);

    // ---- level 0 -> 1: pool + split-K bitset popcount augment ----
    pool(xs0, 4096, perm1, inv1);
    mask_gather<<<512, 256, 0, stream>>>(M0, perm1, maskb, rs1, 2048);
    popc_aug_p<<<dim3(32, 32, 4), 256, 0, stream>>>(maskb, (short*)Cp);
    aug_merge<<<dim3(32, 32), 256, 0, stream>>>((const short*)Cp, 2048, A1h, rs1);
    gcn_dense(xah, xal, 2048, 256, 256, A1h, nullptr, rs1, 32768, bd1,
              xs1, nullptr, nullptr, 1, 1, 8, nullptr, nullptr, 2048, p2);

    // ---- level 1 -> 2 (dense TRI) ----
    pool(xs1, 2048, perm2, inv2);
    gatherG_h<<<(1024 * 2048 / 8) / 256, 256, 0, stream>>>(A1h, 2048, perm2, Gh, 1024, rs2);
    gemm_bt<0, 1><<<dim3(8, 8, 8), 256, 0, stream>>>(Gh, nullptr, Gh, nullptr, Cp, 1024, 1024, 2048, 256);
    aug_finish_f<true><<<(1024 * 1024 / 4) / 256, 256, 0, stream>>>(Cp, 8, 1024, A2h, A2l, rs2);
    gcn_dense(xah, xal, 1024, 256, 256, A2h, A2l, rs2, 98304, bd2,
              xs2, nullptr, nullptr, 1, 2, 8, nullptr, nullptr, 1024, p3);

    // ---- level 2 -> 3 (dense TRI) ----
    pool(xs2, 1024, perm3, inv3);
    gatherG_hl<<<(512 * 1024 / 8) / 256, 256, 0, stream>>>(A2h, A2l, 1024, perm3, Gh, Gl, 512, rs3);
    gemm_bt<2, 1><<<dim3(4, 4, 8), 256, 0, stream>>>(Gh, Gl, Gh, Gl, Cp, 512, 512, 1024, 128);
    aug_finish_f<true><<<(512 * 512 / 4) / 256, 256, 0, stream>>>(Cp, 8, 512, A3h, A3l, rs3);

    // ---- down 3: out scattered into xu2 = xs2 + u (inv3) ----
    gcn_dense(xah, xal, 512, 256, 256, A3h, A3l, rs3, 163840, bd3,
              xu2, xu2h, xu2l, 1, 2, 8, inv3, xs2, 1024, nullptr);

    // ---- up 0: out scattered into xu1 = xs1 + u (inv2) ----
    gcn_dense(xu2h, xu2l, 1024, 256, 256, A2h, A2l, rs2, 229376, bu0,
              xu1, xu1h, xu1l, 1, 2, 8, inv2, xs1, 2048, nullptr);

    // ---- up 1: out scattered into xu0 = xs0 + u (inv1) ----
    gcn_dense(xu1h, xu1l, 2048, 256, 256, A1h, nullptr, rs1, 294912, bu1,
              xu0, xu0h, xu0l, 1, 1, 8, inv1, xs0, 4096, nullptr);

    // ---- up 2 (A0 sparse, Cout=128, no relu) -> d_out ----
    gemm_bt<2, 0><<<dim3(1, 32, 8), 256, 0, stream>>>(
        xu0h, xu0l, Wth + 360448, Wtl + 360448, Cp, 4096, 128, 256, 32);
    zf_reduce<<<512, 256, 0, stream>>>(Cp, 8, rs0, Zf, 4096, 128);
    spmm_gcn<128, 0, 0><<<1024, 256, 0, stream>>>(csr, rs0, Zf, bu2, (float*)d_out,
                                                  nullptr, nullptr);
}

// Round 8
// 432.479 us; speedup vs baseline: 1.0772x; 1.0183x over previous
//
#include <hip/hip_runtime.h>

// ---------------------------------------------------------------------------
// GraphUNet on MI355X.  Round-22 = R16 structure (measured best 440.4 us)
// + fat-merge of independent chains at each pool boundary:
//   xw GEMM (blocks [0,GB), the long pole) co-launched with the adjacency
//   gather payload (blocks [GB,..): mask_gather / gatherG_h / gatherG_hl).
//   Gather work hides under the GEMM; 3 launches removed; live blocks per
//   launch INCREASE (288-1088) — obeys the >=256-blocks rule that killed
//   R17/R18/R19.
// Cp aliasing: xw slices write at Cp+32MiB (popc/TRI spans = [0,32MiB)).
// rs zeroing moved into fat payloads (same as old gather kernels did).
// Everything else identical to R16/R21.
// ---------------------------------------------------------------------------

typedef __attribute__((ext_vector_type(8))) short bf16x8;
typedef __attribute__((ext_vector_type(4))) short s16x4;
typedef __attribute__((ext_vector_type(4))) float f32x4;

__device__ __forceinline__ short f2bf(float f) {
    unsigned u = __builtin_bit_cast(unsigned, f);
    u += 0x7FFFu + ((u >> 16) & 1u);          // RNE
    return (short)(u >> 16);
}
__device__ __forceinline__ float bf2f(short s) {
    unsigned u = ((unsigned)(unsigned short)s) << 16;
    return __builtin_bit_cast(float, u);
}

#define GLL16(gsrc, ldst)                                                        \
    __builtin_amdgcn_global_load_lds(                                            \
        (__attribute__((address_space(1))) void*)(gsrc),                         \
        (__attribute__((address_space(3))) void*)(ldst), 16, 0, 0)

// ---------------------------------------------------------------------------
// bf16 BT GEMM: C(MxN) = A(MxK) @ B^T, B stored N x K row-major.
// MODE 0: Ah@Bh ; 1: +Ah@Bl ; 2: +Al@Bh   (lo*lo dropped, ~2^-18 rel)
// EPI 0: fp32 partial slice [z][M][N]
// EPI 1: fp32 mirrored square slices (TRI: blocks by>bx exit)
// EPI 3: fp32 TRANSPOSED partial slice [z][N][M] (f32x4 stores)
// ---------------------------------------------------------------------------
template<int MODE, int EPI>
__global__ __launch_bounds__(256, 2)
void gemm_bt(const short* __restrict__ Ah, const short* __restrict__ Al,
             const short* __restrict__ Bh, const short* __restrict__ Bl,
             float* __restrict__ Cf, int M, int N, int K, int kChunk)
{
    if (EPI == 1 && (int)blockIdx.y > (int)blockIdx.x) return;

    __shared__ short sAh[128 * 32];
    __shared__ short sBh[128 * 32];
    __shared__ short sAl[(MODE == 2) ? 128 * 32 : 8];
    __shared__ short sBl[(MODE >= 1) ? 128 * 32 : 8];

    const int t    = threadIdx.x;
    const int lane = t & 63;
    const int wave = t >> 6;
    const int tM   = blockIdx.y * 128;
    const int tN   = blockIdx.x * 128;
    const int k0   = blockIdx.z * kChunk;

    const int wm  = (wave >> 1) * 64;
    const int wn  = (wave & 1) * 64;
    const int l15 = lane & 15;
    const int g8  = (lane >> 4) * 8;

    f32x4 acc[4][4];
    const f32x4 zero = {0.f, 0.f, 0.f, 0.f};
#pragma unroll
    for (int i = 0; i < 4; i++)
#pragma unroll
        for (int j = 0; j < 4; j++) acc[i][j] = zero;

    const int i0 = t, i1 = t + 256;
    const short* a0 = Ah + (size_t)(tM + (i0 >> 2)) * K + (i0 & 3) * 8;
    const short* a1 = Ah + (size_t)(tM + (i1 >> 2)) * K + (i1 & 3) * 8;
    const short* b0 = Bh + (size_t)(tN + (i0 >> 2)) * K + (i0 & 3) * 8;
    const short* b1 = Bh + (size_t)(tN + (i1 >> 2)) * K + (i1 & 3) * 8;
    const short *bl0 = nullptr, *bl1 = nullptr, *al0 = nullptr, *al1 = nullptr;
    if (MODE >= 1) {
        bl0 = Bl + (size_t)(tN + (i0 >> 2)) * K + (i0 & 3) * 8;
        bl1 = Bl + (size_t)(tN + (i1 >> 2)) * K + (i1 & 3) * 8;
    }
    if (MODE == 2) {
        al0 = Al + (size_t)(tM + (i0 >> 2)) * K + (i0 & 3) * 8;
        al1 = Al + (size_t)(tM + (i1 >> 2)) * K + (i1 & 3) * 8;
    }

    for (int kb = k0; kb < k0 + kChunk; kb += 32) {
        GLL16(a0 + kb, &sAh[i0 * 8]);
        GLL16(a1 + kb, &sAh[i1 * 8]);
        GLL16(b0 + kb, &sBh[i0 * 8]);
        GLL16(b1 + kb, &sBh[i1 * 8]);
        if (MODE >= 1) { GLL16(bl0 + kb, &sBl[i0 * 8]); GLL16(bl1 + kb, &sBl[i1 * 8]); }
        if (MODE == 2) { GLL16(al0 + kb, &sAl[i0 * 8]); GLL16(al1 + kb, &sAl[i1 * 8]); }
        __syncthreads();

        bf16x8 aF[4], bF[4], aL[4], bL[4];
#pragma unroll
        for (int i = 0; i < 4; i++)
            aF[i] = *(const bf16x8*)&sAh[(wm + i * 16 + l15) * 32 + g8];
#pragma unroll
        for (int j = 0; j < 4; j++)
            bF[j] = *(const bf16x8*)&sBh[(wn + j * 16 + l15) * 32 + g8];
        if (MODE >= 1)
#pragma unroll
            for (int j = 0; j < 4; j++)
                bL[j] = *(const bf16x8*)&sBl[(wn + j * 16 + l15) * 32 + g8];
        if (MODE == 2)
#pragma unroll
            for (int i = 0; i < 4; i++)
                aL[i] = *(const bf16x8*)&sAl[(wm + i * 16 + l15) * 32 + g8];

#pragma unroll
        for (int i = 0; i < 4; i++)
#pragma unroll
            for (int j = 0; j < 4; j++) {
                acc[i][j] = __builtin_amdgcn_mfma_f32_16x16x32_bf16(aF[i], bF[j], acc[i][j], 0, 0, 0);
                if (MODE >= 1)
                    acc[i][j] = __builtin_amdgcn_mfma_f32_16x16x32_bf16(aF[i], bL[j], acc[i][j], 0, 0, 0);
                if (MODE == 2)
                    acc[i][j] = __builtin_amdgcn_mfma_f32_16x16x32_bf16(aL[i], bF[j], acc[i][j], 0, 0, 0);
            }
        __syncthreads();
    }

    // C/D layout: col=lane&15, row=(lane>>4)*4+reg  [m89-verified]
    const int r4 = (lane >> 4) * 4;
    if (EPI == 3) {
        float* CT = Cf + (size_t)blockIdx.z * M * N;   // [N][M]
#pragma unroll
        for (int i = 0; i < 4; i++)
#pragma unroll
            for (int j = 0; j < 4; j++) {
                const int col   = tN + wn + j * 16 + l15;
                const int rbase = tM + wm + i * 16 + r4;
                *(f32x4*)&CT[(size_t)col * M + rbase] = acc[i][j];
            }
    } else {
        float* Cg = Cf + (size_t)blockIdx.z * M * N;
#pragma unroll
        for (int i = 0; i < 4; i++)
#pragma unroll
            for (int j = 0; j < 4; j++) {
                const int col = tN + wn + j * 16 + l15;
                float* cp = Cg + (size_t)(tM + wm + i * 16 + r4) * N + col;
#pragma unroll
                for (int r = 0; r < 4; r++) cp[(size_t)r * N] = acc[i][j][r];
            }
        if (EPI == 1 && tM != tN) {
#pragma unroll
            for (int i = 0; i < 4; i++)
#pragma unroll
                for (int j = 0; j < 4; j++) {
                    const int col   = tN + wn + j * 16 + l15;
                    const int rbase = tM + wm + i * 16 + r4;
                    *(f32x4*)&Cg[(size_t)col * N + rbase] = acc[i][j];
                }
        }
    }
}

// ---------------------------------------------------------------------------
// FAT kernel: xw GEMM (MODE2, EPI3) in blocks [0,GB), gather payload after.
// PAY 0: gatherG_h  (pA row gather +I -> pGh; zero rsz[pkk])
// PAY 1: gatherG_hl (pA/pAlo hi-lo gather +I -> pGh/pGl; zero rsz[pkk])
// PAY 2: mask_gather (M0 row gather +self bit -> masko; zero rsz[pkk])
// GEMM blocks dispatch first (long pole); gather blocks backfill CUs.
// ---------------------------------------------------------------------------
template<int PAY>
__global__ __launch_bounds__(256, 2)
void xw_fat(const short* __restrict__ Ah, const short* __restrict__ Al,
            const short* __restrict__ Bh, const short* __restrict__ Bl,
            float* __restrict__ Cf, int M, int N, int K, int kChunk,
            int gx, int gy, int GB,
            const short* __restrict__ pA, const short* __restrict__ pAlo,
            int pn, const int* __restrict__ perm,
            short* __restrict__ pGh, short* __restrict__ pGl, int pkk,
            float* __restrict__ rsz,
            const unsigned long long* __restrict__ M0s,
            unsigned long long* __restrict__ masko)
{
    __shared__ short sAh[128 * 32];
    __shared__ short sBh[128 * 32];
    __shared__ short sAl[128 * 32];
    __shared__ short sBl[128 * 32];

    const int bid = (int)blockIdx.x;
    const int t   = threadIdx.x;

    if (bid >= GB) {
        const int pidx = (bid - GB) * 256 + t;
        if (PAY == 2) {
            if (pidx < pkk) rsz[pidx] = 0.f;
            int r = pidx >> 6, l = pidx & 63;
            int u = perm[r];
            unsigned long long w = M0s[(size_t)u * 64 + l];
            if ((u >> 6) == l) w |= 1ull << (u & 63);
            masko[pidx] = w;
        } else if (PAY == 0) {
            if (pidx < pkk) rsz[pidx] = 0.f;
            int t8 = pidx * 8;
            if (t8 < pkk * pn) {
                int r = t8 / pn, c0 = t8 - r * pn;
                int pr = perm[r];
                bf16x8 a = *(const bf16x8*)&pA[(size_t)pr * pn + c0];
                if (pr >= c0 && pr < c0 + 8)
                    a[pr - c0] = f2bf(bf2f(a[pr - c0]) + 1.f);
                *(bf16x8*)&pGh[t8] = a;
            }
        } else {
            if (pidx < pkk) rsz[pidx] = 0.f;
            int t8 = pidx * 8;
            if (t8 < pkk * pn) {
                int r = t8 / pn, c0 = t8 - r * pn;
                int pr = perm[r];
                bf16x8 ah = *(const bf16x8*)&pA[(size_t)pr * pn + c0];
                bf16x8 al = *(const bf16x8*)&pAlo[(size_t)pr * pn + c0];
                bf16x8 gh, gl;
#pragma unroll
                for (int q = 0; q < 8; q++) {
                    float v = bf2f(ah[q]) + bf2f(al[q]) + ((c0 + q == pr) ? 1.f : 0.f);
                    short h = f2bf(v);
                    gh[q] = h; gl[q] = f2bf(v - bf2f(h));
                }
                *(bf16x8*)&pGh[t8] = gh;
                *(bf16x8*)&pGl[t8] = gl;
            }
        }
        return;
    }

    // ---- xw GEMM: MODE2, EPI3 (identical math to gemm_bt<2,3>) ----
    const int bx = bid % gx;
    const int by = (bid / gx) % gy;
    const int bz = bid / (gx * gy);

    const int lane = t & 63;
    const int wave = t >> 6;
    const int tM   = by * 128;
    const int tN   = bx * 128;
    const int k0   = bz * kChunk;

    const int wm  = (wave >> 1) * 64;
    const int wn  = (wave & 1) * 64;
    const int l15 = lane & 15;
    const int g8  = (lane >> 4) * 8;

    f32x4 acc[4][4];
    const f32x4 zero = {0.f, 0.f, 0.f, 0.f};
#pragma unroll
    for (int i = 0; i < 4; i++)
#pragma unroll
        for (int j = 0; j < 4; j++) acc[i][j] = zero;

    const int i0 = t, i1 = t + 256;
    const short* a0  = Ah + (size_t)(tM + (i0 >> 2)) * K + (i0 & 3) * 8;
    const short* a1  = Ah + (size_t)(tM + (i1 >> 2)) * K + (i1 & 3) * 8;
    const short* b0  = Bh + (size_t)(tN + (i0 >> 2)) * K + (i0 & 3) * 8;
    const short* b1  = Bh + (size_t)(tN + (i1 >> 2)) * K + (i1 & 3) * 8;
    const short* bl0 = Bl + (size_t)(tN + (i0 >> 2)) * K + (i0 & 3) * 8;
    const short* bl1 = Bl + (size_t)(tN + (i1 >> 2)) * K + (i1 & 3) * 8;
    const short* al0 = Al + (size_t)(tM + (i0 >> 2)) * K + (i0 & 3) * 8;
    const short* al1 = Al + (size_t)(tM + (i1 >> 2)) * K + (i1 & 3) * 8;

    for (int kb = k0; kb < k0 + kChunk; kb += 32) {
        GLL16(a0 + kb, &sAh[i0 * 8]);
        GLL16(a1 + kb, &sAh[i1 * 8]);
        GLL16(b0 + kb, &sBh[i0 * 8]);
        GLL16(b1 + kb, &sBh[i1 * 8]);
        GLL16(bl0 + kb, &sBl[i0 * 8]);
        GLL16(bl1 + kb, &sBl[i1 * 8]);
        GLL16(al0 + kb, &sAl[i0 * 8]);
        GLL16(al1 + kb, &sAl[i1 * 8]);
        __syncthreads();

        bf16x8 aF[4], bF[4], aL[4], bL[4];
#pragma unroll
        for (int i = 0; i < 4; i++)
            aF[i] = *(const bf16x8*)&sAh[(wm + i * 16 + l15) * 32 + g8];
#pragma unroll
        for (int j = 0; j < 4; j++)
            bF[j] = *(const bf16x8*)&sBh[(wn + j * 16 + l15) * 32 + g8];
#pragma unroll
        for (int j = 0; j < 4; j++)
            bL[j] = *(const bf16x8*)&sBl[(wn + j * 16 + l15) * 32 + g8];
#pragma unroll
        for (int i = 0; i < 4; i++)
            aL[i] = *(const bf16x8*)&sAl[(wm + i * 16 + l15) * 32 + g8];

#pragma unroll
        for (int i = 0; i < 4; i++)
#pragma unroll
            for (int j = 0; j < 4; j++) {
                acc[i][j] = __builtin_amdgcn_mfma_f32_16x16x32_bf16(aF[i], bF[j], acc[i][j], 0, 0, 0);
                acc[i][j] = __builtin_amdgcn_mfma_f32_16x16x32_bf16(aF[i], bL[j], acc[i][j], 0, 0, 0);
                acc[i][j] = __builtin_amdgcn_mfma_f32_16x16x32_bf16(aL[i], bF[j], acc[i][j], 0, 0, 0);
            }
        __syncthreads();
    }

    const int r4 = (lane >> 4) * 4;
    float* CT = Cf + (size_t)bz * M * N;   // [N][M]
#pragma unroll
    for (int i = 0; i < 4; i++)
#pragma unroll
        for (int j = 0; j < 4; j++) {
            const int col   = tN + wn + j * 16 + l15;
            const int rbase = tM + wm + i * 16 + r4;
            *(f32x4*)&CT[(size_t)col * M + rbase] = acc[i][j];
        }
}

// ---------------------------------------------------------------------------
// Utility kernels
// ---------------------------------------------------------------------------

// one-shot prep: W^T hi/lo for all 7 layers + x0 hi/lo split + zero M0 bitmask
__global__ void prep(const float* __restrict__ Wd0, const float* __restrict__ Wd1,
                     const float* __restrict__ Wd2, const float* __restrict__ Wd3,
                     const float* __restrict__ Wu0, const float* __restrict__ Wu1,
                     const float* __restrict__ Wu2, const float* __restrict__ x0,
                     short* __restrict__ Wth, short* __restrict__ Wtl,
                     short* __restrict__ Xh, short* __restrict__ Xl,
                     unsigned long long* __restrict__ M0)
{
    int t = blockIdx.x * 256 + threadIdx.x;
    float v; int dst;
    if (t < 32768)       { int e = t;          v = Wd0[e]; dst = 0      + (e & 255) * 128 + (e >> 8); }
    else if (t < 98304)  { int e = t - 32768;  v = Wd1[e]; dst = 32768  + (e & 255) * 256 + (e >> 8); }
    else if (t < 163840) { int e = t - 98304;  v = Wd2[e]; dst = 98304  + (e & 255) * 256 + (e >> 8); }
    else if (t < 229376) { int e = t - 163840; v = Wd3[e]; dst = 163840 + (e & 255) * 256 + (e >> 8); }
    else if (t < 294912) { int e = t - 229376; v = Wu0[e]; dst = 229376 + (e & 255) * 256 + (e >> 8); }
    else if (t < 360448) { int e = t - 294912; v = Wu1[e]; dst = 294912 + (e & 255) * 256 + (e >> 8); }
    else if (t < 393216) { int e = t - 360448; v = Wu2[e]; dst = 360448 + (e & 127) * 256 + (e >> 7); }
    else if (t < 917504) {
        int e = t - 393216;                      // x0: 4096*128
        v = x0[e];
        short h = f2bf(v);
        Xh[e] = h; Xl[e] = f2bf(v - bf2f(h));
        return;
    } else {
        M0[t - 917504] = 0ull;                   // 4096*64 words
        return;
    }
    short h = f2bf(v);
    Wth[dst] = h; Wtl[dst] = f2bf(v - bf2f(h));
}

// edge list -> symmetric self-loop-free row bitmask (dedup for free)
__global__ void build_bits(const int* __restrict__ ei, int E,
                           unsigned long long* __restrict__ M0)
{
    int e = blockIdx.x * 256 + threadIdx.x;
    if (e >= E) return;
    int i = ei[e], j = ei[E + e];
    if (i != j) {
        atomicOr(&M0[(size_t)i * 64 + (j >> 6)], 1ull << (j & 63));
        atomicOr(&M0[(size_t)j * 64 + (i >> 6)], 1ull << (i & 63));
    }
}

// bitmask -> CSR (<=128 nnz/row, ascending) + degree, via wave prefix scan
__global__ void row_compact_bits(const unsigned long long* __restrict__ M0,
                                 int* __restrict__ csr, float* __restrict__ rs)
{
    int row = blockIdx.x * 4 + (threadIdx.x >> 6);
    int lane = threadIdx.x & 63;
    unsigned long long w = M0[(size_t)row * 64 + lane];
    int c = __popcll(w);
    int incl = c;
    for (int off = 1; off < 64; off <<= 1) {
        int v = __shfl_up(incl, off);
        if (lane >= off) incl += v;
    }
    int base = incl - c;
    int* out = csr + (size_t)row * 128;
    while (w) {
        int b = __ffsll((unsigned long long)w) - 1;
        if (base < 128) out[base] = lane * 64 + b;
        base++;
        w &= w - 1;
    }
    if (lane == 63) rs[row] = (float)incl;
}

// popcount partial: slice z covers words [z*16, z*16+16).  64x64 TRI tiles,
// 18 KB LDS -> 8 blocks/CU.  int16 partial tile at Cp[(z*1024 + by*32+bx)*4096].
#define PSTR2 18
__global__ __launch_bounds__(256, 8)
void popc_aug_p(const unsigned long long* __restrict__ mask,
                short* __restrict__ Cp)
{
    const int bx = blockIdx.x, by = blockIdx.y, z = blockIdx.z;
    if (by > bx) return;
    __shared__ unsigned long long a[64 * PSTR2];
    __shared__ unsigned long long b[64 * PSTR2];
    const int t = threadIdx.x;
#pragma unroll
    for (int p = 0; p < 4; p++) {
        int idx = p * 256 + t;           // 0..1023 = rr*16 + w
        int rr = idx >> 4, w = idx & 15;
        a[rr * PSTR2 + w] = mask[((size_t)(by * 64 + rr)) * 64 + z * 16 + w];
        b[rr * PSTR2 + w] = mask[((size_t)(bx * 64 + rr)) * 64 + z * 16 + w];
    }
    __syncthreads();
    const int i0 = (t >> 4) * 4;         // 4 consecutive rows
    const int j0 = t & 15;               // cols j0 + 16*qj
    int acc[4][4];
#pragma unroll
    for (int qi = 0; qi < 4; qi++)
#pragma unroll
        for (int qj = 0; qj < 4; qj++) acc[qi][qj] = 0;
#pragma unroll
    for (int w = 0; w < 16; w += 2) {
        ulong2 av[4], bv[4];
#pragma unroll
        for (int q = 0; q < 4; q++) av[q] = *(const ulong2*)&a[(i0 + q) * PSTR2 + w];
#pragma unroll
        for (int q = 0; q < 4; q++) bv[q] = *(const ulong2*)&b[(j0 + 16 * q) * PSTR2 + w];
#pragma unroll
        for (int qi = 0; qi < 4; qi++)
#pragma unroll
            for (int qj = 0; qj < 4; qj++) {
                acc[qi][qj] += __builtin_popcountll(av[qi].x & bv[qj].x);
                acc[qi][qj] += __builtin_popcountll(av[qi].y & bv[qj].y);
            }
    }
    short* out = Cp + ((size_t)z * 1024 + (size_t)(by * 32 + bx)) * 4096;
#pragma unroll
    for (int qi = 0; qi < 4; qi++)
#pragma unroll
        for (int qj = 0; qj < 4; qj++)
            out[(i0 + qi) * 64 + j0 + 16 * qj] = (short)acc[qi][qj];
}

// merge 4 int16 slices -> A1h (bf16, diag 0) + LDS-transposed mirror + rowsums
__global__ __launch_bounds__(256)
void aug_merge(const short* __restrict__ Cp, int kk,
               short* __restrict__ Ahs, float* __restrict__ rs)
{
    const int bx = blockIdx.x, by = blockIdx.y;
    if (by > bx) return;
    __shared__ float tile[64][65];
    __shared__ float rsum[64], csum[64];
    const int t = threadIdx.x;
    const int i  = t >> 2;               // row 0..63
    const int c0 = (t & 3) * 16;         // 16 consecutive cols
    const size_t tb = (size_t)(by * 32 + bx) * 4096;
    const size_t ss = (size_t)1024 * 4096;
    if (t < 64) { rsum[t] = 0.f; csum[t] = 0.f; }

    int v[16];
#pragma unroll
    for (int q = 0; q < 16; q++) v[q] = 0;
    for (int s = 0; s < 4; s++) {
        bf16x8 p0 = *(const bf16x8*)&Cp[tb + s * ss + i * 64 + c0];
        bf16x8 p1 = *(const bf16x8*)&Cp[tb + s * ss + i * 64 + c0 + 8];
#pragma unroll
        for (int q = 0; q < 8; q++) { v[q] += (int)p0[q]; v[8 + q] += (int)p1[q]; }
    }
    const int gi = by * 64 + i;
    float rp = 0.f;
    s16x4 pk[4];
#pragma unroll
    for (int q = 0; q < 16; q++) {
        const int gj = bx * 64 + c0 + q;
        float val = (gi == gj) ? 0.f : (float)v[q];
        tile[i][c0 + q] = val;
        rp += val;
        pk[q >> 2][q & 3] = f2bf(val);
    }
#pragma unroll
    for (int q = 0; q < 4; q++)
        *(s16x4*)&Ahs[(size_t)gi * kk + bx * 64 + c0 + q * 4] = pk[q];
    __syncthreads();
    atomicAdd(&rsum[i], rp);
    if (bx != by) {
        float cpv = 0.f;
#pragma unroll
        for (int q = 0; q < 16; q++) {
            float val = tile[c0 + q][i];
            cpv += val;
            pk[q >> 2][q & 3] = f2bf(val);
        }
#pragma unroll
        for (int q = 0; q < 4; q++)
            *(s16x4*)&Ahs[(size_t)(bx * 64 + i) * kk + by * 64 + c0 + q * 4] = pk[q];
        atomicAdd(&csum[i], cpv);
    }
    __syncthreads();
    if (t < 64) {
        atomicAdd(&rs[by * 64 + t], rsum[t]);
        if (bx != by) atomicAdd(&rs[bx * 64 + t], csum[t]);
    }
}

// reduce transposed xw partial slices -> Z^T hi/lo  (x4 vectorized)
__global__ void z_reduce(const float* __restrict__ Cp, int S,
                         const float* __restrict__ rs,
                         short* __restrict__ Zh, short* __restrict__ Zl,
                         int n, int C)
{
    int t4 = (blockIdx.x * 256 + threadIdx.x) * 4;   // t = c*n + r layout
    int r = t4 % n;
    size_t stride = (size_t)n * C;
    f32x4 v = {0.f, 0.f, 0.f, 0.f};
    for (int s = 0; s < S; s++) v += *(const f32x4*)&Cp[t4 + s * stride];
    f32x4 rsv = *(const f32x4*)&rs[r];
    s16x4 zh, zl;
#pragma unroll
    for (int q = 0; q < 4; q++) {
        float z = v[q] / sqrtf(rsv[q] + 2.f);
        short h = f2bf(z);
        zh[q] = h; zl[q] = f2bf(z - bf2f(h));
    }
    *(s16x4*)&Zh[t4] = zh;
    *(s16x4*)&Zl[t4] = zl;
}

// reduce row-major xw partial slices -> Zf fp32 [r][C]  (x4 vectorized)
__global__ void zf_reduce(const float* __restrict__ Cp, int S,
                          const float* __restrict__ rs,
                          float* __restrict__ Zf, int n, int C)
{
    int t4 = (blockIdx.x * 256 + threadIdx.x) * 4;   // t = r*C + c
    int r = t4 / C;
    size_t stride = (size_t)n * C;
    f32x4 v = {0.f, 0.f, 0.f, 0.f};
    for (int s = 0; s < S; s++) v += *(const f32x4*)&Cp[t4 + s * stride];
    float d = 1.f / sqrtf(rs[r] + 2.f);
    v *= d;
    *(f32x4*)&Zf[t4] = v;
}

// CSR SpMM + fused GCN epilogue (+ optional fused pool score: SC=1)
template<int CN, int RELU, int SC>
__global__ __launch_bounds__(256)
void spmm_gcn(const int* __restrict__ csr, const float* __restrict__ rs,
              const float* __restrict__ Zf, const float* __restrict__ b,
              float* __restrict__ out,
              const float* __restrict__ pvec, float* __restrict__ score)
{
    const int lane = threadIdx.x & 63;
    const int row  = blockIdx.x * 4 + (threadIdx.x >> 6);
    const int dg   = (int)rs[row];
    const int* nb  = csr + (size_t)row * 128;
    if (CN == 256) {
        const int c = lane * 4;
        float4 acc = {0.f, 0.f, 0.f, 0.f};
        int q = 0;
        for (; q + 4 <= dg; q += 4) {
            int j0 = nb[q], j1 = nb[q+1], j2 = nb[q+2], j3 = nb[q+3];
            float4 z0 = *(const float4*)&Zf[(size_t)j0 * CN + c];
            float4 z1 = *(const float4*)&Zf[(size_t)j1 * CN + c];
            float4 z2 = *(const float4*)&Zf[(size_t)j2 * CN + c];
            float4 z3 = *(const float4*)&Zf[(size_t)j3 * CN + c];
            acc.x += z0.x; acc.y += z0.y; acc.z += z0.z; acc.w += z0.w;
            acc.x += z1.x; acc.y += z1.y; acc.z += z1.z; acc.w += z1.w;
            acc.x += z2.x; acc.y += z2.y; acc.z += z2.z; acc.w += z2.w;
            acc.x += z3.x; acc.y += z3.y; acc.z += z3.z; acc.w += z3.w;
        }
        for (; q < dg; q++) {
            float4 z = *(const float4*)&Zf[(size_t)nb[q] * CN + c];
            acc.x += z.x; acc.y += z.y; acc.z += z.z; acc.w += z.w;
        }
        float d = 1.f / sqrtf(rs[row] + 2.f);
        float4 zi = *(const float4*)&Zf[(size_t)row * CN + c];
        float4 bb = *(const float4*)&b[c];
        float4 g;
        g.x = d * acc.x + 2.f * d * zi.x + bb.x;
        g.y = d * acc.y + 2.f * d * zi.y + bb.y;
        g.z = d * acc.z + 2.f * d * zi.z + bb.z;
        g.w = d * acc.w + 2.f * d * zi.w + bb.w;
        if (RELU) {
            g.x = fmaxf(g.x, 0.f); g.y = fmaxf(g.y, 0.f);
            g.z = fmaxf(g.z, 0.f); g.w = fmaxf(g.w, 0.f);
        }
        *(float4*)&out[(size_t)row * CN + c] = g;
        if (SC) {
            float4 pv = ((const float4*)pvec)[lane];
            double nn  = (double)pv.x * pv.x + (double)pv.y * pv.y +
                         (double)pv.z * pv.z + (double)pv.w * pv.w;
            double acd = (double)g.x * pv.x + (double)g.y * pv.y +
                         (double)g.z * pv.z + (double)g.w * pv.w;
            for (int off = 32; off; off >>= 1) {
                acd += __shfl_down(acd, off);
                nn  += __shfl_down(nn, off);
            }
            if (lane == 0) score[row] = tanhf((float)(acd / sqrt(nn)));
        }
    } else {
        const int c = lane * 2;
        float2 acc = {0.f, 0.f};
        int q = 0;
        for (; q + 4 <= dg; q += 4) {
            int j0 = nb[q], j1 = nb[q+1], j2 = nb[q+2], j3 = nb[q+3];
            float2 z0 = *(const float2*)&Zf[(size_t)j0 * CN + c];
            float2 z1 = *(const float2*)&Zf[(size_t)j1 * CN + c];
            float2 z2 = *(const float2*)&Zf[(size_t)j2 * CN + c];
            float2 z3 = *(const float2*)&Zf[(size_t)j3 * CN + c];
            acc.x += z0.x; acc.y += z0.y;
            acc.x += z1.x; acc.y += z1.y;
            acc.x += z2.x; acc.y += z2.y;
            acc.x += z3.x; acc.y += z3.y;
        }
        for (; q < dg; q++) {
            float2 z = *(const float2*)&Zf[(size_t)nb[q] * CN + c];
            acc.x += z.x; acc.y += z.y;
        }
        float d = 1.f / sqrtf(rs[row] + 2.f);
        float2 zi = *(const float2*)&Zf[(size_t)row * CN + c];
        float2 g;
        g.x = d * acc.x + 2.f * d * zi.x + b[c];
        g.y = d * acc.y + 2.f * d * zi.y + b[c + 1];
        if (RELU) { g.x = fmaxf(g.x, 0.f); g.y = fmaxf(g.y, 0.f); }
        *(float2*)&out[(size_t)row * CN + c] = g;
    }
}

// fused: reduce AZ slices + GCN epilogue (+inv scatter) (+compile-time score)
template<int SC>
__global__ void gcn_final(const float* __restrict__ Cp, int S,
                          const short* __restrict__ Zh, const short* __restrict__ Zl,
                          const float* __restrict__ rs, const float* __restrict__ b,
                          float* __restrict__ out, short* __restrict__ oh,
                          short* __restrict__ ol, int k, int C, int relu,
                          const int* __restrict__ inv, const float* __restrict__ res,
                          const float* __restrict__ pvec, float* __restrict__ score)
{
    int t4 = (blockIdx.x * 256 + threadIdx.x) * 4;
    int j = t4 / C, c = t4 - j * C;
    int r = inv ? inv[j] : j;
    f32x4 v = res ? *(const f32x4*)&res[t4] : (f32x4){0.f, 0.f, 0.f, 0.f};
    if (r >= 0) {
        size_t base = (size_t)r * C + c;
        size_t stride = (size_t)k * C;
        f32x4 az = {0.f, 0.f, 0.f, 0.f};
        for (int s = 0; s < S; s++) az += *(const f32x4*)&Cp[base + s * stride];
        float d = 1.f / sqrtf(rs[r] + 2.f);
        f32x4 bb = *(const f32x4*)&b[c];
#pragma unroll
        for (int q = 0; q < 4; q++) {
            size_t zi = (size_t)(c + q) * k + r;
            float zz = bf2f(Zh[zi]) + bf2f(Zl[zi]);      // zz ~= d * xw
            float g = d * az[q] + 2.f * d * zz + bb[q];
            if (relu && g < 0.f) g = 0.f;
            v[q] += g;
        }
    }
    *(f32x4*)&out[t4] = v;
    if (oh) {
        s16x4 hh, ll;
#pragma unroll
        for (int q = 0; q < 4; q++) {
            short h = f2bf(v[q]);
            hh[q] = h; ll[q] = f2bf(v[q] - bf2f(h));
        }
        *(s16x4*)&oh[t4] = hh;
        *(s16x4*)&ol[t4] = ll;
    }
    if (SC) {
        // C==256: one wave per row (64 lanes x 4 cols) -> free score reduce,
        // math identical to the old score_kernel (double dot / double norm).
        const int lane = threadIdx.x & 63;
        float4 pv = *(const float4*)&pvec[c];
        double nn  = (double)pv.x * pv.x + (double)pv.y * pv.y +
                     (double)pv.z * pv.z + (double)pv.w * pv.w;
        double acd = (double)v[0] * pv.x + (double)v[1] * pv.y +
                     (double)v[2] * pv.z + (double)v[3] * pv.w;
        for (int off = 32; off; off >>= 1) {
            acd += __shfl_down(acd, off);
            nn  += __shfl_down(nn, off);
        }
        if (lane == 0) score[j] = tanhf((float)(acd / sqrt(nn)));
    }
}

__device__ __forceinline__ unsigned long long packkey(float s, int i) {
    unsigned u = __builtin_bit_cast(unsigned, s);
    u = (u & 0x80000000u) ? ~u : (u | 0x80000000u);
    return ((unsigned long long)u << 32) | (unsigned)(0xFFFFFFFFu - (unsigned)i);
}

// fused rank + select + gather: block owns 64 rows; scans all n keys from LDS
// chunks (512 threads = 8 j-slices); then scatter-writes perm/inv and the
// gathered+scaled hi/lo x rows (wave per selected row, C=256).
__global__ __launch_bounds__(512)
void rank_pool(const float* __restrict__ score, int n, int k,
               const float* __restrict__ xold,
               int* __restrict__ perm, int* __restrict__ inv,
               short* __restrict__ Xh, short* __restrict__ Xl)
{
    __shared__ unsigned long long sk[512];
    __shared__ int rk[64];
    __shared__ int selrow[64];
    __shared__ int selrank[64];
    __shared__ float selval[64];
    __shared__ int cnt;
    const int t  = threadIdx.x;
    const int il = t & 63;            // local row
    const int js = t >> 6;            // j-slice (8 slices of 64)
    const int i  = blockIdx.x * 64 + il;
    if (t < 64) rk[t] = 0;
    if (t == 0) cnt = 0;
    const unsigned long long mykey = packkey(score[i], i);
    int r = 0;
    for (int jb = 0; jb < n; jb += 512) {
        __syncthreads();
        if (jb + t < n) sk[t] = packkey(score[jb + t], jb + t);
        __syncthreads();
        const unsigned long long* p = &sk[js * 64];
#pragma unroll 16
        for (int q = 0; q < 64; q++) r += (p[q] > mykey) ? 1 : 0;
    }
    atomicAdd(&rk[il], r);
    __syncthreads();
    if (t < 64) {
        int rank = rk[t];
        int ii = blockIdx.x * 64 + t;
        inv[ii] = (rank < k) ? rank : -1;
        if (rank < k) {
            perm[rank] = ii;
            int s = atomicAdd(&cnt, 1);
            selrow[s]  = ii;
            selrank[s] = rank;
            selval[s]  = score[ii];
        }
    }
    __syncthreads();
    const int wave = t >> 6, lane = t & 63;
    for (int s = wave; s < cnt; s += 8) {
        const int   row = selrow[s];
        const float vv  = selval[s];
        f32x4 x = *(const f32x4*)&xold[(size_t)row * 256 + lane * 4];
        s16x4 hh, ll;
#pragma unroll
        for (int q = 0; q < 4; q++) {
            float v = x[q] * vv;
            short h = f2bf(v);
            hh[q] = h; ll[q] = f2bf(v - bf2f(h));
        }
        size_t o = (size_t)selrank[s] * 256 + lane * 4;
        *(s16x4*)&Xh[o] = hh;
        *(s16x4*)&Xl[o] = ll;
    }
}

// fp32 mirrored slices -> A hi(/lo), rowsums  (x4 vectorized)
template<bool LO>
__global__ void aug_finish_f(const float* __restrict__ Cp, int S, int kk,
                             short* __restrict__ Ahs, short* __restrict__ Als,
                             float* __restrict__ rs)
{
    int t4 = (blockIdx.x * 256 + threadIdx.x) * 4;
    int r = t4 / kk, c0 = t4 - r * kk;
    size_t stride = (size_t)kk * kk;
    f32x4 v = {0.f, 0.f, 0.f, 0.f};
    for (int s = 0; s < S; s++) v += *(const f32x4*)&Cp[t4 + s * stride];
    if (r >= c0 && r < c0 + 4) v[r - c0] = 0.f;
    s16x4 hh, ll;
    float ws = 0.f;
#pragma unroll
    for (int q = 0; q < 4; q++) {
        short h = f2bf(v[q]);
        hh[q] = h;
        if (LO) ll[q] = f2bf(v[q] - bf2f(h));
        ws += v[q];
    }
    *(s16x4*)&Ahs[t4] = hh;
    if (LO) *(s16x4*)&Als[t4] = ll;
    for (int off = 32; off; off >>= 1) ws += __shfl_down(ws, off);
    if ((threadIdx.x & 63) == 0) atomicAdd(&rs[r], ws);
}

// ---------------------------------------------------------------------------
// Host orchestration
// ---------------------------------------------------------------------------

extern "C" void kernel_launch(void* const* d_in, const int* in_sizes, int n_in,
                              void* d_out, int out_size, void* d_ws, size_t ws_size,
                              hipStream_t stream)
{
    const float* x0  = (const float*)d_in[0];
    const int*   ei  = (const int*)d_in[1];
    const float* Wd0 = (const float*)d_in[2];  const float* bd0 = (const float*)d_in[3];
    const float* Wd1 = (const float*)d_in[4];  const float* bd1 = (const float*)d_in[5];
    const float* Wd2 = (const float*)d_in[6];  const float* bd2 = (const float*)d_in[7];
    const float* Wd3 = (const float*)d_in[8];  const float* bd3 = (const float*)d_in[9];
    const float* p1  = (const float*)d_in[10];
    const float* p2  = (const float*)d_in[11];
    const float* p3  = (const float*)d_in[12];
    const float* Wu0 = (const float*)d_in[13]; const float* bu0 = (const float*)d_in[14];
    const float* Wu1 = (const float*)d_in[15]; const float* bu1 = (const float*)d_in[16];
    const float* Wu2 = (const float*)d_in[17]; const float* bu2 = (const float*)d_in[18];

    const int E = in_sizes[1] / 2;

    char* ws = (char*)d_ws;
    size_t off = 0;
    auto alloc = [&](size_t bytes) -> void* {
        void* p = ws + off;
        off += (bytes + 255) & ~(size_t)255;
        return p;
    };
    unsigned long long* M0 = (unsigned long long*)alloc((size_t)4096 * 64 * 8);
    short* A1h  = (short*)alloc((size_t)2048 * 2048 * 2);
    short* A2h  = (short*)alloc((size_t)1024 * 1024 * 2);
    short* A2l  = (short*)alloc((size_t)1024 * 1024 * 2);
    short* A3h  = (short*)alloc((size_t)512 * 512 * 2);
    short* A3l  = (short*)alloc((size_t)512 * 512 * 2);
    short* Gh   = (short*)alloc((size_t)1024 * 2048 * 2);
    short* Gl   = (short*)alloc((size_t)512 * 1024 * 2);
    int*   csr  = (int*)alloc((size_t)4096 * 128 * 4);
    unsigned long long* maskb = (unsigned long long*)alloc((size_t)2048 * 64 * 8);
    float* Zf   = (float*)alloc((size_t)4096 * 256 * 4);
    float* Cp   = (float*)alloc((size_t)64 * 1024 * 1024);   // partial arena
    float* xs0  = (float*)alloc((size_t)4096 * 256 * 4);
    float* xs1  = (float*)alloc((size_t)2048 * 256 * 4);
    float* xs2  = (float*)alloc((size_t)1024 * 256 * 4);
    float* xu0  = (float*)alloc((size_t)4096 * 256 * 4);
    float* xu1  = (float*)alloc((size_t)2048 * 256 * 4);
    float* xu2  = (float*)alloc((size_t)1024 * 256 * 4);
    short* xu0h = (short*)alloc((size_t)4096 * 256 * 2);
    short* xu0l = (short*)alloc((size_t)4096 * 256 * 2);
    short* xu1h = (short*)alloc((size_t)2048 * 256 * 2);
    short* xu1l = (short*)alloc((size_t)2048 * 256 * 2);
    short* xu2h = (short*)alloc((size_t)1024 * 256 * 2);
    short* xu2l = (short*)alloc((size_t)1024 * 256 * 2);
    short* X0h  = (short*)alloc((size_t)4096 * 128 * 2);
    short* X0l  = (short*)alloc((size_t)4096 * 128 * 2);
    short* xah  = (short*)alloc((size_t)2048 * 256 * 2);
    short* xal  = (short*)alloc((size_t)2048 * 256 * 2);
    short* Wth  = (short*)alloc((size_t)393216 * 2);
    short* Wtl  = (short*)alloc((size_t)393216 * 2);
    short* Zh   = (short*)alloc((size_t)256 * 4096 * 2);
    short* Zl   = (short*)alloc((size_t)256 * 4096 * 2);
    float* rs0  = (float*)alloc(4096 * 4);
    float* rs1  = (float*)alloc(2048 * 4);
    float* rs2  = (float*)alloc(1024 * 4);
    float* rs3  = (float*)alloc(512 * 4);
    float* scoreb = (float*)alloc(4096 * 4);
    int*   perm1  = (int*)alloc(2048 * 4);
    int*   perm2  = (int*)alloc(1024 * 4);
    int*   perm3  = (int*)alloc(512 * 4);
    int*   inv1   = (int*)alloc(4096 * 4);
    int*   inv2   = (int*)alloc(2048 * 4);
    int*   inv3   = (int*)alloc(1024 * 4);

    float* Cp2 = Cp + (size_t)8 * 1024 * 1024;   // +32 MiB: xw slice region

    // post-xw stages of a dense-A GCN layer: z_reduce -> AZ -> gcn_final
    auto gcn_rest = [&](int n, int Cout, const short* pAh, const short* pAl,
                        const float* rsA, const float* b, float* out,
                        short* oh, short* ol, int relu, int modeA, int Saz,
                        const int* inv, const float* res, int nout,
                        const float* pvec, const float* CpXw, int Sxw) {
        z_reduce<<<(n * Cout) / 1024, 256, 0, stream>>>(CpXw, Sxw, rsA, Zh, Zl, n, Cout);
        dim3 g(Cout / 128, n / 128, Saz);
        if (modeA == 1)
            gemm_bt<1, 0><<<g, 256, 0, stream>>>(pAh, nullptr, Zh, Zl, Cp, n, Cout, n, n / Saz);
        else
            gemm_bt<2, 0><<<g, 256, 0, stream>>>(pAh, pAl, Zh, Zl, Cp, n, Cout, n, n / Saz);
        if (pvec)
            gcn_final<1><<<(nout * Cout) / 1024, 256, 0, stream>>>(
                Cp, Saz, Zh, Zl, rsA, b, out, oh, ol, n, Cout, relu, inv, res,
                pvec, scoreb);
        else
            gcn_final<0><<<(nout * Cout) / 1024, 256, 0, stream>>>(
                Cp, Saz, Zh, Zl, rsA, b, out, oh, ol, n, Cout, relu, inv, res,
                nullptr, nullptr);
    };

    // full dense layer (up path, no overlap partner): xw at Cp base
    auto gcn_dense = [&](const short* Xh, const short* Xl, int n, int Kc, int Cout,
                         const short* pAh, const short* pAl, const float* rsA,
                         int wtoff, const float* b,
                         float* out, short* oh, short* ol, int relu, int modeA,
                         int Saz, const int* inv, const float* res, int nout,
                         const float* pvec) {
        int Sxw = 4;
        gemm_bt<2, 3><<<dim3(Cout / 128, n / 128, Sxw), 256, 0, stream>>>(
            Xh, Xl, Wth + wtoff, Wtl + wtoff, Cp, n, Cout, Kc, Kc / Sxw);
        gcn_rest(n, Cout, pAh, pAl, rsA, b, out, oh, ol, relu, modeA, Saz,
                 inv, res, nout, pvec, Cp, Sxw);
    };

    auto pool = [&](const float* xlev, int n, int* perm, int* inv) {
        int k = n / 2;
        rank_pool<<<n / 64, 512, 0, stream>>>(scoreb, n, k, xlev, perm, inv, xah, xal);
    };

    // ---- prep (weights + x0 split + M0 zero) + bitmask adjacency + CSR ----
    prep<<<4608, 256, 0, stream>>>(Wd0, Wd1, Wd2, Wd3, Wu0, Wu1, Wu2, x0,
                                   Wth, Wtl, X0h, X0l, M0);
    build_bits<<<(E + 255) / 256, 256, 0, stream>>>(ei, E, M0);
    row_compact_bits<<<1024, 256, 0, stream>>>(M0, csr, rs0);

    // ---- down 0 (A0 sparse): x@W -> Zf -> SpMM+epilogue (+p1 score) ----
    gemm_bt<2, 0><<<dim3(2, 32, 4), 256, 0, stream>>>(
        X0h, X0l, Wth, Wtl, Cp, 4096, 256, 128, 32);
    zf_reduce<<<1024, 256, 0, stream>>>(Cp, 4, rs0, Zf, 4096, 256);
    spmm_gcn<256, 1, 1><<<1024, 256, 0, stream>>>(csr, rs0, Zf, bd0, xs0, p1, scoreb);

    // ---- level 0 -> 1: pool, FAT{xw(L1)->Cp2 || mask_gather}, popc, merge ----
    pool(xs0, 4096, perm1, inv1);
    xw_fat<2><<<128 + 512, 256, 0, stream>>>(
        xah, xal, Wth + 32768, Wtl + 32768, Cp2, 2048, 256, 256, 64,
        2, 16, 128,
        nullptr, nullptr, 0, perm1, nullptr, nullptr, 2048, rs1, M0, maskb);
    popc_aug_p<<<dim3(32, 32, 4), 256, 0, stream>>>(maskb, (short*)Cp);
    aug_merge<<<dim3(32, 32), 256, 0, stream>>>((const short*)Cp, 2048, A1h, rs1);
    gcn_rest(2048, 256, A1h, nullptr, rs1, bd1, xs1, nullptr, nullptr, 1, 1, 8,
             nullptr, nullptr, 2048, p2, Cp2, 4);

    // ---- level 1 -> 2: pool, FAT{xw(L2)->Cp2 || gatherG_h}, TRI, finish ----
    pool(xs1, 2048, perm2, inv2);
    xw_fat<0><<<64 + 1024, 256, 0, stream>>>(
        xah, xal, Wth + 98304, Wtl + 98304, Cp2, 1024, 256, 256, 64,
        2, 8, 64,
        A1h, nullptr, 2048, perm2, Gh, nullptr, 1024, rs2, nullptr, nullptr);
    gemm_bt<0, 1><<<dim3(8, 8, 8), 256, 0, stream>>>(Gh, nullptr, Gh, nullptr, Cp, 1024, 1024, 2048, 256);
    aug_finish_f<true><<<(1024 * 1024 / 4) / 256, 256, 0, stream>>>(Cp, 8, 1024, A2h, A2l, rs2);
    gcn_rest(1024, 256, A2h, A2l, rs2, bd2, xs2, nullptr, nullptr, 1, 2, 8,
             nullptr, nullptr, 1024, p3, Cp2, 4);

    // ---- level 2 -> 3: pool, FAT{xw(down3)->Cp2 || gatherG_hl}, TRI, finish ----
    pool(xs2, 1024, perm3, inv3);
    xw_fat<1><<<32 + 256, 256, 0, stream>>>(
        xah, xal, Wth + 163840, Wtl + 163840, Cp2, 512, 256, 256, 64,
        2, 4, 32,
        A2h, A2l, 1024, perm3, Gh, Gl, 512, rs3, nullptr, nullptr);
    gemm_bt<2, 1><<<dim3(4, 4, 8), 256, 0, stream>>>(Gh, Gl, Gh, Gl, Cp, 512, 512, 1024, 128);
    aug_finish_f<true><<<(512 * 512 / 4) / 256, 256, 0, stream>>>(Cp, 8, 512, A3h, A3l, rs3);

    // ---- down 3: out scattered into xu2 = xs2 + u (inv3) ----
    gcn_rest(512, 256, A3h, A3l, rs3, bd3, xu2, xu2h, xu2l, 1, 2, 8,
             inv3, xs2, 1024, nullptr, Cp2, 4);

    // ---- up 0: out scattered into xu1 = xs1 + u (inv2) ----
    gcn_dense(xu2h, xu2l, 1024, 256, 256, A2h, A2l, rs2, 229376, bu0,
              xu1, xu1h, xu1l, 1, 2, 8, inv2, xs1, 2048, nullptr);

    // ---- up 1: out scattered into xu0 = xs0 + u (inv1) ----
    gcn_dense(xu1h, xu1l, 2048, 256, 256, A1h, nullptr, rs1, 294912, bu1,
              xu0, xu0h, xu0l, 1, 1, 8, inv1, xs0, 4096, nullptr);

    // ---- up 2 (A0 sparse, Cout=128, no relu) -> d_out ----
    gemm_bt<2, 0><<<dim3(1, 32, 8), 256, 0, stream>>>(
        xu0h, xu0l, Wth + 360448, Wtl + 360448, Cp, 4096, 128, 256, 32);
    zf_reduce<<<512, 256, 0, stream>>>(Cp, 8, rs0, Zf, 4096, 128);
    spmm_gcn<128, 0, 0><<<1024, 256, 0, stream>>>(csr, rs0, Zf, bu2, (float*)d_out,
                                                  nullptr, nullptr);
}

// Round 9
// 429.512 us; speedup vs baseline: 1.0847x; 1.0069x over previous
//
#include <hip/hip_runtime.h>

// ---------------------------------------------------------------------------
// GraphUNet on MI355X.  Round-23 = R22 (432.5 us) + one more fat-merge:
//   down-0 xw GEMM (256 blocks) co-launched with row_compact_bits payload
//   (1024 blocks) — the two are independent (GEMM needs prep, CSR needs
//   build_bits).  xw_fat gains template<PAY,EPI>: PAY=3 row-compact payload,
//   EPI=0 plain-slice epilogue.  -1 launch, ~3 us CSR build hidden.
// NOTE: z_reduce CANNOT be fat-merged with popc/TRI (reads rs accumulated
// by aug_merge/aug_finish atomics) — dependency checked on paper.
// Everything else identical to R22.
// ---------------------------------------------------------------------------

typedef __attribute__((ext_vector_type(8))) short bf16x8;
typedef __attribute__((ext_vector_type(4))) short s16x4;
typedef __attribute__((ext_vector_type(4))) float f32x4;

__device__ __forceinline__ short f2bf(float f) {
    unsigned u = __builtin_bit_cast(unsigned, f);
    u += 0x7FFFu + ((u >> 16) & 1u);          // RNE
    return (short)(u >> 16);
}
__device__ __forceinline__ float bf2f(short s) {
    unsigned u = ((unsigned)(unsigned short)s) << 16;
    return __builtin_bit_cast(float, u);
}

#define GLL16(gsrc, ldst)                                                        \
    __builtin_amdgcn_global_load_lds(                                            \
        (__attribute__((address_space(1))) void*)(gsrc),                         \
        (__attribute__((address_space(3))) void*)(ldst), 16, 0, 0)

// ---------------------------------------------------------------------------
// bf16 BT GEMM: C(MxN) = A(MxK) @ B^T, B stored N x K row-major.
// MODE 0: Ah@Bh ; 1: +Ah@Bl ; 2: +Al@Bh   (lo*lo dropped, ~2^-18 rel)
// EPI 0: fp32 partial slice [z][M][N]
// EPI 1: fp32 mirrored square slices (TRI: blocks by>bx exit)
// EPI 3: fp32 TRANSPOSED partial slice [z][N][M] (f32x4 stores)
// ---------------------------------------------------------------------------
template<int MODE, int EPI>
__global__ __launch_bounds__(256, 2)
void gemm_bt(const short* __restrict__ Ah, const short* __restrict__ Al,
             const short* __restrict__ Bh, const short* __restrict__ Bl,
             float* __restrict__ Cf, int M, int N, int K, int kChunk)
{
    if (EPI == 1 && (int)blockIdx.y > (int)blockIdx.x) return;

    __shared__ short sAh[128 * 32];
    __shared__ short sBh[128 * 32];
    __shared__ short sAl[(MODE == 2) ? 128 * 32 : 8];
    __shared__ short sBl[(MODE >= 1) ? 128 * 32 : 8];

    const int t    = threadIdx.x;
    const int lane = t & 63;
    const int wave = t >> 6;
    const int tM   = blockIdx.y * 128;
    const int tN   = blockIdx.x * 128;
    const int k0   = blockIdx.z * kChunk;

    const int wm  = (wave >> 1) * 64;
    const int wn  = (wave & 1) * 64;
    const int l15 = lane & 15;
    const int g8  = (lane >> 4) * 8;

    f32x4 acc[4][4];
    const f32x4 zero = {0.f, 0.f, 0.f, 0.f};
#pragma unroll
    for (int i = 0; i < 4; i++)
#pragma unroll
        for (int j = 0; j < 4; j++) acc[i][j] = zero;

    const int i0 = t, i1 = t + 256;
    const short* a0 = Ah + (size_t)(tM + (i0 >> 2)) * K + (i0 & 3) * 8;
    const short* a1 = Ah + (size_t)(tM + (i1 >> 2)) * K + (i1 & 3) * 8;
    const short* b0 = Bh + (size_t)(tN + (i0 >> 2)) * K + (i0 & 3) * 8;
    const short* b1 = Bh + (size_t)(tN + (i1 >> 2)) * K + (i1 & 3) * 8;
    const short *bl0 = nullptr, *bl1 = nullptr, *al0 = nullptr, *al1 = nullptr;
    if (MODE >= 1) {
        bl0 = Bl + (size_t)(tN + (i0 >> 2)) * K + (i0 & 3) * 8;
        bl1 = Bl + (size_t)(tN + (i1 >> 2)) * K + (i1 & 3) * 8;
    }
    if (MODE == 2) {
        al0 = Al + (size_t)(tM + (i0 >> 2)) * K + (i0 & 3) * 8;
        al1 = Al + (size_t)(tM + (i1 >> 2)) * K + (i1 & 3) * 8;
    }

    for (int kb = k0; kb < k0 + kChunk; kb += 32) {
        GLL16(a0 + kb, &sAh[i0 * 8]);
        GLL16(a1 + kb, &sAh[i1 * 8]);
        GLL16(b0 + kb, &sBh[i0 * 8]);
        GLL16(b1 + kb, &sBh[i1 * 8]);
        if (MODE >= 1) { GLL16(bl0 + kb, &sBl[i0 * 8]); GLL16(bl1 + kb, &sBl[i1 * 8]); }
        if (MODE == 2) { GLL16(al0 + kb, &sAl[i0 * 8]); GLL16(al1 + kb, &sAl[i1 * 8]); }
        __syncthreads();

        bf16x8 aF[4], bF[4], aL[4], bL[4];
#pragma unroll
        for (int i = 0; i < 4; i++)
            aF[i] = *(const bf16x8*)&sAh[(wm + i * 16 + l15) * 32 + g8];
#pragma unroll
        for (int j = 0; j < 4; j++)
            bF[j] = *(const bf16x8*)&sBh[(wn + j * 16 + l15) * 32 + g8];
        if (MODE >= 1)
#pragma unroll
            for (int j = 0; j < 4; j++)
                bL[j] = *(const bf16x8*)&sBl[(wn + j * 16 + l15) * 32 + g8];
        if (MODE == 2)
#pragma unroll
            for (int i = 0; i < 4; i++)
                aL[i] = *(const bf16x8*)&sAl[(wm + i * 16 + l15) * 32 + g8];

#pragma unroll
        for (int i = 0; i < 4; i++)
#pragma unroll
            for (int j = 0; j < 4; j++) {
                acc[i][j] = __builtin_amdgcn_mfma_f32_16x16x32_bf16(aF[i], bF[j], acc[i][j], 0, 0, 0);
                if (MODE >= 1)
                    acc[i][j] = __builtin_amdgcn_mfma_f32_16x16x32_bf16(aF[i], bL[j], acc[i][j], 0, 0, 0);
                if (MODE == 2)
                    acc[i][j] = __builtin_amdgcn_mfma_f32_16x16x32_bf16(aL[i], bF[j], acc[i][j], 0, 0, 0);
            }
        __syncthreads();
    }

    // C/D layout: col=lane&15, row=(lane>>4)*4+reg  [m89-verified]
    const int r4 = (lane >> 4) * 4;
    if (EPI == 3) {
        float* CT = Cf + (size_t)blockIdx.z * M * N;   // [N][M]
#pragma unroll
        for (int i = 0; i < 4; i++)
#pragma unroll
            for (int j = 0; j < 4; j++) {
                const int col   = tN + wn + j * 16 + l15;
                const int rbase = tM + wm + i * 16 + r4;
                *(f32x4*)&CT[(size_t)col * M + rbase] = acc[i][j];
            }
    } else {
        float* Cg = Cf + (size_t)blockIdx.z * M * N;
#pragma unroll
        for (int i = 0; i < 4; i++)
#pragma unroll
            for (int j = 0; j < 4; j++) {
                const int col = tN + wn + j * 16 + l15;
                float* cp = Cg + (size_t)(tM + wm + i * 16 + r4) * N + col;
#pragma unroll
                for (int r = 0; r < 4; r++) cp[(size_t)r * N] = acc[i][j][r];
            }
        if (EPI == 1 && tM != tN) {
#pragma unroll
            for (int i = 0; i < 4; i++)
#pragma unroll
                for (int j = 0; j < 4; j++) {
                    const int col   = tN + wn + j * 16 + l15;
                    const int rbase = tM + wm + i * 16 + r4;
                    *(f32x4*)&Cg[(size_t)col * N + rbase] = acc[i][j];
                }
        }
    }
}

// ---------------------------------------------------------------------------
// FAT kernel: xw GEMM (MODE2, EPI template) in blocks [0,GB), payload after.
// PAY 0: gatherG_h  (pA row gather +I -> pGh; zero rsz[pkk])
// PAY 1: gatherG_hl (pA/pAlo hi-lo gather +I -> pGh/pGl; zero rsz[pkk])
// PAY 2: mask_gather (M0 row gather +self bit -> masko; zero rsz[pkk])
// PAY 3: row_compact_bits (M0 bitmask -> csrOut + rsz degrees)
// GEMM blocks dispatch first (long pole); payload blocks backfill CUs.
// ---------------------------------------------------------------------------
template<int PAY, int EPI>
__global__ __launch_bounds__(256, 2)
void xw_fat(const short* __restrict__ Ah, const short* __restrict__ Al,
            const short* __restrict__ Bh, const short* __restrict__ Bl,
            float* __restrict__ Cf, int M, int N, int K, int kChunk,
            int gx, int gy, int GB,
            const short* __restrict__ pA, const short* __restrict__ pAlo,
            int pn, const int* __restrict__ perm,
            short* __restrict__ pGh, short* __restrict__ pGl, int pkk,
            float* __restrict__ rsz,
            const unsigned long long* __restrict__ M0s,
            unsigned long long* __restrict__ masko,
            int* __restrict__ csrOut)
{
    __shared__ short sAh[128 * 32];
    __shared__ short sBh[128 * 32];
    __shared__ short sAl[128 * 32];
    __shared__ short sBl[128 * 32];

    const int bid = (int)blockIdx.x;
    const int t   = threadIdx.x;

    if (bid >= GB) {
        const int pidx = (bid - GB) * 256 + t;
        if (PAY == 3) {
            // row_compact_bits: 4 rows per block, wave prefix-scan compaction
            const int prow = (bid - GB) * 4 + (t >> 6);
            const int lane = t & 63;
            unsigned long long w = M0s[(size_t)prow * 64 + lane];
            int c = __popcll(w);
            int incl = c;
            for (int off2 = 1; off2 < 64; off2 <<= 1) {
                int vv = __shfl_up(incl, off2);
                if (lane >= off2) incl += vv;
            }
            int base = incl - c;
            int* outp = csrOut + (size_t)prow * 128;
            while (w) {
                int b = __ffsll((unsigned long long)w) - 1;
                if (base < 128) outp[base] = lane * 64 + b;
                base++;
                w &= w - 1;
            }
            if (lane == 63) rsz[prow] = (float)incl;
        } else if (PAY == 2) {
            if (pidx < pkk) rsz[pidx] = 0.f;
            int r = pidx >> 6, l = pidx & 63;
            int u = perm[r];
            unsigned long long w = M0s[(size_t)u * 64 + l];
            if ((u >> 6) == l) w |= 1ull << (u & 63);
            masko[pidx] = w;
        } else if (PAY == 0) {
            if (pidx < pkk) rsz[pidx] = 0.f;
            int t8 = pidx * 8;
            if (t8 < pkk * pn) {
                int r = t8 / pn, c0 = t8 - r * pn;
                int pr = perm[r];
                bf16x8 a = *(const bf16x8*)&pA[(size_t)pr * pn + c0];
                if (pr >= c0 && pr < c0 + 8)
                    a[pr - c0] = f2bf(bf2f(a[pr - c0]) + 1.f);
                *(bf16x8*)&pGh[t8] = a;
            }
        } else {
            if (pidx < pkk) rsz[pidx] = 0.f;
            int t8 = pidx * 8;
            if (t8 < pkk * pn) {
                int r = t8 / pn, c0 = t8 - r * pn;
                int pr = perm[r];
                bf16x8 ah = *(const bf16x8*)&pA[(size_t)pr * pn + c0];
                bf16x8 al = *(const bf16x8*)&pAlo[(size_t)pr * pn + c0];
                bf16x8 gh, gl;
#pragma unroll
                for (int q = 0; q < 8; q++) {
                    float v = bf2f(ah[q]) + bf2f(al[q]) + ((c0 + q == pr) ? 1.f : 0.f);
                    short h = f2bf(v);
                    gh[q] = h; gl[q] = f2bf(v - bf2f(h));
                }
                *(bf16x8*)&pGh[t8] = gh;
                *(bf16x8*)&pGl[t8] = gl;
            }
        }
        return;
    }

    // ---- xw GEMM: MODE2 (identical math to gemm_bt<2,EPI>) ----
    const int bx = bid % gx;
    const int by = (bid / gx) % gy;
    const int bz = bid / (gx * gy);

    const int lane = t & 63;
    const int wave = t >> 6;
    const int tM   = by * 128;
    const int tN   = bx * 128;
    const int k0   = bz * kChunk;

    const int wm  = (wave >> 1) * 64;
    const int wn  = (wave & 1) * 64;
    const int l15 = lane & 15;
    const int g8  = (lane >> 4) * 8;

    f32x4 acc[4][4];
    const f32x4 zero = {0.f, 0.f, 0.f, 0.f};
#pragma unroll
    for (int i = 0; i < 4; i++)
#pragma unroll
        for (int j = 0; j < 4; j++) acc[i][j] = zero;

    const int i0 = t, i1 = t + 256;
    const short* a0  = Ah + (size_t)(tM + (i0 >> 2)) * K + (i0 & 3) * 8;
    const short* a1  = Ah + (size_t)(tM + (i1 >> 2)) * K + (i1 & 3) * 8;
    const short* b0  = Bh + (size_t)(tN + (i0 >> 2)) * K + (i0 & 3) * 8;
    const short* b1  = Bh + (size_t)(tN + (i1 >> 2)) * K + (i1 & 3) * 8;
    const short* bl0 = Bl + (size_t)(tN + (i0 >> 2)) * K + (i0 & 3) * 8;
    const short* bl1 = Bl + (size_t)(tN + (i1 >> 2)) * K + (i1 & 3) * 8;
    const short* al0 = Al + (size_t)(tM + (i0 >> 2)) * K + (i0 & 3) * 8;
    const short* al1 = Al + (size_t)(tM + (i1 >> 2)) * K + (i1 & 3) * 8;

    for (int kb = k0; kb < k0 + kChunk; kb += 32) {
        GLL16(a0 + kb, &sAh[i0 * 8]);
        GLL16(a1 + kb, &sAh[i1 * 8]);
        GLL16(b0 + kb, &sBh[i0 * 8]);
        GLL16(b1 + kb, &sBh[i1 * 8]);
        GLL16(bl0 + kb, &sBl[i0 * 8]);
        GLL16(bl1 + kb, &sBl[i1 * 8]);
        GLL16(al0 + kb, &sAl[i0 * 8]);
        GLL16(al1 + kb, &sAl[i1 * 8]);
        __syncthreads();

        bf16x8 aF[4], bF[4], aL[4], bL[4];
#pragma unroll
        for (int i = 0; i < 4; i++)
            aF[i] = *(const bf16x8*)&sAh[(wm + i * 16 + l15) * 32 + g8];
#pragma unroll
        for (int j = 0; j < 4; j++)
            bF[j] = *(const bf16x8*)&sBh[(wn + j * 16 + l15) * 32 + g8];
#pragma unroll
        for (int j = 0; j < 4; j++)
            bL[j] = *(const bf16x8*)&sBl[(wn + j * 16 + l15) * 32 + g8];
#pragma unroll
        for (int i = 0; i < 4; i++)
            aL[i] = *(const bf16x8*)&sAl[(wm + i * 16 + l15) * 32 + g8];

#pragma unroll
        for (int i = 0; i < 4; i++)
#pragma unroll
            for (int j = 0; j < 4; j++) {
                acc[i][j] = __builtin_amdgcn_mfma_f32_16x16x32_bf16(aF[i], bF[j], acc[i][j], 0, 0, 0);
                acc[i][j] = __builtin_amdgcn_mfma_f32_16x16x32_bf16(aF[i], bL[j], acc[i][j], 0, 0, 0);
                acc[i][j] = __builtin_amdgcn_mfma_f32_16x16x32_bf16(aL[i], bF[j], acc[i][j], 0, 0, 0);
            }
        __syncthreads();
    }

    const int r4 = (lane >> 4) * 4;
    if (EPI == 3) {
        float* CT = Cf + (size_t)bz * M * N;   // [N][M]
#pragma unroll
        for (int i = 0; i < 4; i++)
#pragma unroll
            for (int j = 0; j < 4; j++) {
                const int col   = tN + wn + j * 16 + l15;
                const int rbase = tM + wm + i * 16 + r4;
                *(f32x4*)&CT[(size_t)col * M + rbase] = acc[i][j];
            }
    } else {
        float* Cg = Cf + (size_t)bz * M * N;   // [M][N]
#pragma unroll
        for (int i = 0; i < 4; i++)
#pragma unroll
            for (int j = 0; j < 4; j++) {
                const int col = tN + wn + j * 16 + l15;
                float* cp = Cg + (size_t)(tM + wm + i * 16 + r4) * N + col;
#pragma unroll
                for (int r = 0; r < 4; r++) cp[(size_t)r * N] = acc[i][j][r];
            }
    }
}

// ---------------------------------------------------------------------------
// Utility kernels
// ---------------------------------------------------------------------------

// one-shot prep: W^T hi/lo for all 7 layers + x0 hi/lo split + zero M0 bitmask
__global__ void prep(const float* __restrict__ Wd0, const float* __restrict__ Wd1,
                     const float* __restrict__ Wd2, const float* __restrict__ Wd3,
                     const float* __restrict__ Wu0, const float* __restrict__ Wu1,
                     const float* __restrict__ Wu2, const float* __restrict__ x0,
                     short* __restrict__ Wth, short* __restrict__ Wtl,
                     short* __restrict__ Xh, short* __restrict__ Xl,
                     unsigned long long* __restrict__ M0)
{
    int t = blockIdx.x * 256 + threadIdx.x;
    float v; int dst;
    if (t < 32768)       { int e = t;          v = Wd0[e]; dst = 0      + (e & 255) * 128 + (e >> 8); }
    else if (t < 98304)  { int e = t - 32768;  v = Wd1[e]; dst = 32768  + (e & 255) * 256 + (e >> 8); }
    else if (t < 163840) { int e = t - 98304;  v = Wd2[e]; dst = 98304  + (e & 255) * 256 + (e >> 8); }
    else if (t < 229376) { int e = t - 163840; v = Wd3[e]; dst = 163840 + (e & 255) * 256 + (e >> 8); }
    else if (t < 294912) { int e = t - 229376; v = Wu0[e]; dst = 229376 + (e & 255) * 256 + (e >> 8); }
    else if (t < 360448) { int e = t - 294912; v = Wu1[e]; dst = 294912 + (e & 255) * 256 + (e >> 8); }
    else if (t < 393216) { int e = t - 360448; v = Wu2[e]; dst = 360448 + (e & 127) * 256 + (e >> 7); }
    else if (t < 917504) {
        int e = t - 393216;                      // x0: 4096*128
        v = x0[e];
        short h = f2bf(v);
        Xh[e] = h; Xl[e] = f2bf(v - bf2f(h));
        return;
    } else {
        M0[t - 917504] = 0ull;                   // 4096*64 words
        return;
    }
    short h = f2bf(v);
    Wth[dst] = h; Wtl[dst] = f2bf(v - bf2f(h));
}

// edge list -> symmetric self-loop-free row bitmask (dedup for free)
__global__ void build_bits(const int* __restrict__ ei, int E,
                           unsigned long long* __restrict__ M0)
{
    int e = blockIdx.x * 256 + threadIdx.x;
    if (e >= E) return;
    int i = ei[e], j = ei[E + e];
    if (i != j) {
        atomicOr(&M0[(size_t)i * 64 + (j >> 6)], 1ull << (j & 63));
        atomicOr(&M0[(size_t)j * 64 + (i >> 6)], 1ull << (i & 63));
    }
}

// popcount partial: slice z covers words [z*16, z*16+16).  64x64 TRI tiles,
// 18 KB LDS -> 8 blocks/CU.  int16 partial tile at Cp[(z*1024 + by*32+bx)*4096].
#define PSTR2 18
__global__ __launch_bounds__(256, 8)
void popc_aug_p(const unsigned long long* __restrict__ mask,
                short* __restrict__ Cp)
{
    const int bx = blockIdx.x, by = blockIdx.y, z = blockIdx.z;
    if (by > bx) return;
    __shared__ unsigned long long a[64 * PSTR2];
    __shared__ unsigned long long b[64 * PSTR2];
    const int t = threadIdx.x;
#pragma unroll
    for (int p = 0; p < 4; p++) {
        int idx = p * 256 + t;           // 0..1023 = rr*16 + w
        int rr = idx >> 4, w = idx & 15;
        a[rr * PSTR2 + w] = mask[((size_t)(by * 64 + rr)) * 64 + z * 16 + w];
        b[rr * PSTR2 + w] = mask[((size_t)(bx * 64 + rr)) * 64 + z * 16 + w];
    }
    __syncthreads();
    const int i0 = (t >> 4) * 4;         // 4 consecutive rows
    const int j0 = t & 15;               // cols j0 + 16*qj
    int acc[4][4];
#pragma unroll
    for (int qi = 0; qi < 4; qi++)
#pragma unroll
        for (int qj = 0; qj < 4; qj++) acc[qi][qj] = 0;
#pragma unroll
    for (int w = 0; w < 16; w += 2) {
        ulong2 av[4], bv[4];
#pragma unroll
        for (int q = 0; q < 4; q++) av[q] = *(const ulong2*)&a[(i0 + q) * PSTR2 + w];
#pragma unroll
        for (int q = 0; q < 4; q++) bv[q] = *(const ulong2*)&b[(j0 + 16 * q) * PSTR2 + w];
#pragma unroll
        for (int qi = 0; qi < 4; qi++)
#pragma unroll
            for (int qj = 0; qj < 4; qj++) {
                acc[qi][qj] += __builtin_popcountll(av[qi].x & bv[qj].x);
                acc[qi][qj] += __builtin_popcountll(av[qi].y & bv[qj].y);
            }
    }
    short* out = Cp + ((size_t)z * 1024 + (size_t)(by * 32 + bx)) * 4096;
#pragma unroll
    for (int qi = 0; qi < 4; qi++)
#pragma unroll
        for (int qj = 0; qj < 4; qj++)
            out[(i0 + qi) * 64 + j0 + 16 * qj] = (short)acc[qi][qj];
}

// merge 4 int16 slices -> A1h (bf16, diag 0) + LDS-transposed mirror + rowsums
__global__ __launch_bounds__(256)
void aug_merge(const short* __restrict__ Cp, int kk,
               short* __restrict__ Ahs, float* __restrict__ rs)
{
    const int bx = blockIdx.x, by = blockIdx.y;
    if (by > bx) return;
    __shared__ float tile[64][65];
    __shared__ float rsum[64], csum[64];
    const int t = threadIdx.x;
    const int i  = t >> 2;               // row 0..63
    const int c0 = (t & 3) * 16;         // 16 consecutive cols
    const size_t tb = (size_t)(by * 32 + bx) * 4096;
    const size_t ss = (size_t)1024 * 4096;
    if (t < 64) { rsum[t] = 0.f; csum[t] = 0.f; }

    int v[16];
#pragma unroll
    for (int q = 0; q < 16; q++) v[q] = 0;
    for (int s = 0; s < 4; s++) {
        bf16x8 p0 = *(const bf16x8*)&Cp[tb + s * ss + i * 64 + c0];
        bf16x8 p1 = *(const bf16x8*)&Cp[tb + s * ss + i * 64 + c0 + 8];
#pragma unroll
        for (int q = 0; q < 8; q++) { v[q] += (int)p0[q]; v[8 + q] += (int)p1[q]; }
    }
    const int gi = by * 64 + i;
    float rp = 0.f;
    s16x4 pk[4];
#pragma unroll
    for (int q = 0; q < 16; q++) {
        const int gj = bx * 64 + c0 + q;
        float val = (gi == gj) ? 0.f : (float)v[q];
        tile[i][c0 + q] = val;
        rp += val;
        pk[q >> 2][q & 3] = f2bf(val);
    }
#pragma unroll
    for (int q = 0; q < 4; q++)
        *(s16x4*)&Ahs[(size_t)gi * kk + bx * 64 + c0 + q * 4] = pk[q];
    __syncthreads();
    atomicAdd(&rsum[i], rp);
    if (bx != by) {
        float cpv = 0.f;
#pragma unroll
        for (int q = 0; q < 16; q++) {
            float val = tile[c0 + q][i];
            cpv += val;
            pk[q >> 2][q & 3] = f2bf(val);
        }
#pragma unroll
        for (int q = 0; q < 4; q++)
            *(s16x4*)&Ahs[(size_t)(bx * 64 + i) * kk + by * 64 + c0 + q * 4] = pk[q];
        atomicAdd(&csum[i], cpv);
    }
    __syncthreads();
    if (t < 64) {
        atomicAdd(&rs[by * 64 + t], rsum[t]);
        if (bx != by) atomicAdd(&rs[bx * 64 + t], csum[t]);
    }
}

// reduce transposed xw partial slices -> Z^T hi/lo  (x4 vectorized)
__global__ void z_reduce(const float* __restrict__ Cp, int S,
                         const float* __restrict__ rs,
                         short* __restrict__ Zh, short* __restrict__ Zl,
                         int n, int C)
{
    int t4 = (blockIdx.x * 256 + threadIdx.x) * 4;   // t = c*n + r layout
    int r = t4 % n;
    size_t stride = (size_t)n * C;
    f32x4 v = {0.f, 0.f, 0.f, 0.f};
    for (int s = 0; s < S; s++) v += *(const f32x4*)&Cp[t4 + s * stride];
    f32x4 rsv = *(const f32x4*)&rs[r];
    s16x4 zh, zl;
#pragma unroll
    for (int q = 0; q < 4; q++) {
        float z = v[q] / sqrtf(rsv[q] + 2.f);
        short h = f2bf(z);
        zh[q] = h; zl[q] = f2bf(z - bf2f(h));
    }
    *(s16x4*)&Zh[t4] = zh;
    *(s16x4*)&Zl[t4] = zl;
}

// reduce row-major xw partial slices -> Zf fp32 [r][C]  (x4 vectorized)
__global__ void zf_reduce(const float* __restrict__ Cp, int S,
                          const float* __restrict__ rs,
                          float* __restrict__ Zf, int n, int C)
{
    int t4 = (blockIdx.x * 256 + threadIdx.x) * 4;   // t = r*C + c
    int r = t4 / C;
    size_t stride = (size_t)n * C;
    f32x4 v = {0.f, 0.f, 0.f, 0.f};
    for (int s = 0; s < S; s++) v += *(const f32x4*)&Cp[t4 + s * stride];
    float d = 1.f / sqrtf(rs[r] + 2.f);
    v *= d;
    *(f32x4*)&Zf[t4] = v;
}

// CSR SpMM + fused GCN epilogue (+ optional fused pool score: SC=1)
template<int CN, int RELU, int SC>
__global__ __launch_bounds__(256)
void spmm_gcn(const int* __restrict__ csr, const float* __restrict__ rs,
              const float* __restrict__ Zf, const float* __restrict__ b,
              float* __restrict__ out,
              const float* __restrict__ pvec, float* __restrict__ score)
{
    const int lane = threadIdx.x & 63;
    const int row  = blockIdx.x * 4 + (threadIdx.x >> 6);
    const int dg   = (int)rs[row];
    const int* nb  = csr + (size_t)row * 128;
    if (CN == 256) {
        const int c = lane * 4;
        float4 acc = {0.f, 0.f, 0.f, 0.f};
        int q = 0;
        for (; q + 4 <= dg; q += 4) {
            int j0 = nb[q], j1 = nb[q+1], j2 = nb[q+2], j3 = nb[q+3];
            float4 z0 = *(const float4*)&Zf[(size_t)j0 * CN + c];
            float4 z1 = *(const float4*)&Zf[(size_t)j1 * CN + c];
            float4 z2 = *(const float4*)&Zf[(size_t)j2 * CN + c];
            float4 z3 = *(const float4*)&Zf[(size_t)j3 * CN + c];
            acc.x += z0.x; acc.y += z0.y; acc.z += z0.z; acc.w += z0.w;
            acc.x += z1.x; acc.y += z1.y; acc.z += z1.z; acc.w += z1.w;
            acc.x += z2.x; acc.y += z2.y; acc.z += z2.z; acc.w += z2.w;
            acc.x += z3.x; acc.y += z3.y; acc.z += z3.z; acc.w += z3.w;
        }
        for (; q < dg; q++) {
            float4 z = *(const float4*)&Zf[(size_t)nb[q] * CN + c];
            acc.x += z.x; acc.y += z.y; acc.z += z.z; acc.w += z.w;
        }
        float d = 1.f / sqrtf(rs[row] + 2.f);
        float4 zi = *(const float4*)&Zf[(size_t)row * CN + c];
        float4 bb = *(const float4*)&b[c];
        float4 g;
        g.x = d * acc.x + 2.f * d * zi.x + bb.x;
        g.y = d * acc.y + 2.f * d * zi.y + bb.y;
        g.z = d * acc.z + 2.f * d * zi.z + bb.z;
        g.w = d * acc.w + 2.f * d * zi.w + bb.w;
        if (RELU) {
            g.x = fmaxf(g.x, 0.f); g.y = fmaxf(g.y, 0.f);
            g.z = fmaxf(g.z, 0.f); g.w = fmaxf(g.w, 0.f);
        }
        *(float4*)&out[(size_t)row * CN + c] = g;
        if (SC) {
            float4 pv = ((const float4*)pvec)[lane];
            double nn  = (double)pv.x * pv.x + (double)pv.y * pv.y +
                         (double)pv.z * pv.z + (double)pv.w * pv.w;
            double acd = (double)g.x * pv.x + (double)g.y * pv.y +
                         (double)g.z * pv.z + (double)g.w * pv.w;
            for (int off = 32; off; off >>= 1) {
                acd += __shfl_down(acd, off);
                nn  += __shfl_down(nn, off);
            }
            if (lane == 0) score[row] = tanhf((float)(acd / sqrt(nn)));
        }
    } else {
        const int c = lane * 2;
        float2 acc = {0.f, 0.f};
        int q = 0;
        for (; q + 4 <= dg; q += 4) {
            int j0 = nb[q], j1 = nb[q+1], j2 = nb[q+2], j3 = nb[q+3];
            float2 z0 = *(const float2*)&Zf[(size_t)j0 * CN + c];
            float2 z1 = *(const float2*)&Zf[(size_t)j1 * CN + c];
            float2 z2 = *(const float2*)&Zf[(size_t)j2 * CN + c];
            float2 z3 = *(const float2*)&Zf[(size_t)j3 * CN + c];
            acc.x += z0.x; acc.y += z0.y;
            acc.x += z1.x; acc.y += z1.y;
            acc.x += z2.x; acc.y += z2.y;
            acc.x += z3.x; acc.y += z3.y;
        }
        for (; q < dg; q++) {
            float2 z = *(const float2*)&Zf[(size_t)nb[q] * CN + c];
            acc.x += z.x; acc.y += z.y;
        }
        float d = 1.f / sqrtf(rs[row] + 2.f);
        float2 zi = *(const float2*)&Zf[(size_t)row * CN + c];
        float2 g;
        g.x = d * acc.x + 2.f * d * zi.x + b[c];
        g.y = d * acc.y + 2.f * d * zi.y + b[c + 1];
        if (RELU) { g.x = fmaxf(g.x, 0.f); g.y = fmaxf(g.y, 0.f); }
        *(float2*)&out[(size_t)row * CN + c] = g;
    }
}

// fused: reduce AZ slices + GCN epilogue (+inv scatter) (+compile-time score)
template<int SC>
__global__ void gcn_final(const float* __restrict__ Cp, int S,
                          const short* __restrict__ Zh, const short* __restrict__ Zl,
                          const float* __restrict__ rs, const float* __restrict__ b,
                          float* __restrict__ out, short* __restrict__ oh,
                          short* __restrict__ ol, int k, int C, int relu,
                          const int* __restrict__ inv, const float* __restrict__ res,
                          const float* __restrict__ pvec, float* __restrict__ score)
{
    int t4 = (blockIdx.x * 256 + threadIdx.x) * 4;
    int j = t4 / C, c = t4 - j * C;
    int r = inv ? inv[j] : j;
    f32x4 v = res ? *(const f32x4*)&res[t4] : (f32x4){0.f, 0.f, 0.f, 0.f};
    if (r >= 0) {
        size_t base = (size_t)r * C + c;
        size_t stride = (size_t)k * C;
        f32x4 az = {0.f, 0.f, 0.f, 0.f};
        for (int s = 0; s < S; s++) az += *(const f32x4*)&Cp[base + s * stride];
        float d = 1.f / sqrtf(rs[r] + 2.f);
        f32x4 bb = *(const f32x4*)&b[c];
#pragma unroll
        for (int q = 0; q < 4; q++) {
            size_t zi = (size_t)(c + q) * k + r;
            float zz = bf2f(Zh[zi]) + bf2f(Zl[zi]);      // zz ~= d * xw
            float g = d * az[q] + 2.f * d * zz + bb[q];
            if (relu && g < 0.f) g = 0.f;
            v[q] += g;
        }
    }
    *(f32x4*)&out[t4] = v;
    if (oh) {
        s16x4 hh, ll;
#pragma unroll
        for (int q = 0; q < 4; q++) {
            short h = f2bf(v[q]);
            hh[q] = h; ll[q] = f2bf(v[q] - bf2f(h));
        }
        *(s16x4*)&oh[t4] = hh;
        *(s16x4*)&ol[t4] = ll;
    }
    if (SC) {
        // C==256: one wave per row (64 lanes x 4 cols) -> free score reduce,
        // math identical to the old score_kernel (double dot / double norm).
        const int lane = threadIdx.x & 63;
        float4 pv = *(const float4*)&pvec[c];
        double nn  = (double)pv.x * pv.x + (double)pv.y * pv.y +
                     (double)pv.z * pv.z + (double)pv.w * pv.w;
        double acd = (double)v[0] * pv.x + (double)v[1] * pv.y +
                     (double)v[2] * pv.z + (double)v[3] * pv.w;
        for (int off = 32; off; off >>= 1) {
            acd += __shfl_down(acd, off);
            nn  += __shfl_down(nn, off);
        }
        if (lane == 0) score[j] = tanhf((float)(acd / sqrt(nn)));
    }
}

__device__ __forceinline__ unsigned long long packkey(float s, int i) {
    unsigned u = __builtin_bit_cast(unsigned, s);
    u = (u & 0x80000000u) ? ~u : (u | 0x80000000u);
    return ((unsigned long long)u << 32) | (unsigned)(0xFFFFFFFFu - (unsigned)i);
}

// fused rank + select + gather: block owns 64 rows; scans all n keys from LDS
// chunks (512 threads = 8 j-slices); then scatter-writes perm/inv and the
// gathered+scaled hi/lo x rows (wave per selected row, C=256).
__global__ __launch_bounds__(512)
void rank_pool(const float* __restrict__ score, int n, int k,
               const float* __restrict__ xold,
               int* __restrict__ perm, int* __restrict__ inv,
               short* __restrict__ Xh, short* __restrict__ Xl)
{
    __shared__ unsigned long long sk[512];
    __shared__ int rk[64];
    __shared__ int selrow[64];
    __shared__ int selrank[64];
    __shared__ float selval[64];
    __shared__ int cnt;
    const int t  = threadIdx.x;
    const int il = t & 63;            // local row
    const int js = t >> 6;            // j-slice (8 slices of 64)
    const int i  = blockIdx.x * 64 + il;
    if (t < 64) rk[t] = 0;
    if (t == 0) cnt = 0;
    const unsigned long long mykey = packkey(score[i], i);
    int r = 0;
    for (int jb = 0; jb < n; jb += 512) {
        __syncthreads();
        if (jb + t < n) sk[t] = packkey(score[jb + t], jb + t);
        __syncthreads();
        const unsigned long long* p = &sk[js * 64];
#pragma unroll 16
        for (int q = 0; q < 64; q++) r += (p[q] > mykey) ? 1 : 0;
    }
    atomicAdd(&rk[il], r);
    __syncthreads();
    if (t < 64) {
        int rank = rk[t];
        int ii = blockIdx.x * 64 + t;
        inv[ii] = (rank < k) ? rank : -1;
        if (rank < k) {
            perm[rank] = ii;
            int s = atomicAdd(&cnt, 1);
            selrow[s]  = ii;
            selrank[s] = rank;
            selval[s]  = score[ii];
        }
    }
    __syncthreads();
    const int wave = t >> 6, lane = t & 63;
    for (int s = wave; s < cnt; s += 8) {
        const int   row = selrow[s];
        const float vv  = selval[s];
        f32x4 x = *(const f32x4*)&xold[(size_t)row * 256 + lane * 4];
        s16x4 hh, ll;
#pragma unroll
        for (int q = 0; q < 4; q++) {
            float v = x[q] * vv;
            short h = f2bf(v);
            hh[q] = h; ll[q] = f2bf(v - bf2f(h));
        }
        size_t o = (size_t)selrank[s] * 256 + lane * 4;
        *(s16x4*)&Xh[o] = hh;
        *(s16x4*)&Xl[o] = ll;
    }
}

// fp32 mirrored slices -> A hi(/lo), rowsums  (x4 vectorized)
template<bool LO>
__global__ void aug_finish_f(const float* __restrict__ Cp, int S, int kk,
                             short* __restrict__ Ahs, short* __restrict__ Als,
                             float* __restrict__ rs)
{
    int t4 = (blockIdx.x * 256 + threadIdx.x) * 4;
    int r = t4 / kk, c0 = t4 - r * kk;
    size_t stride = (size_t)kk * kk;
    f32x4 v = {0.f, 0.f, 0.f, 0.f};
    for (int s = 0; s < S; s++) v += *(const f32x4*)&Cp[t4 + s * stride];
    if (r >= c0 && r < c0 + 4) v[r - c0] = 0.f;
    s16x4 hh, ll;
    float ws = 0.f;
#pragma unroll
    for (int q = 0; q < 4; q++) {
        short h = f2bf(v[q]);
        hh[q] = h;
        if (LO) ll[q] = f2bf(v[q] - bf2f(h));
        ws += v[q];
    }
    *(s16x4*)&Ahs[t4] = hh;
    if (LO) *(s16x4*)&Als[t4] = ll;
    for (int off = 32; off; off >>= 1) ws += __shfl_down(ws, off);
    if ((threadIdx.x & 63) == 0) atomicAdd(&rs[r], ws);
}

// ---------------------------------------------------------------------------
// Host orchestration
// ---------------------------------------------------------------------------

extern "C" void kernel_launch(void* const* d_in, const int* in_sizes, int n_in,
                              void* d_out, int out_size, void* d_ws, size_t ws_size,
                              hipStream_t stream)
{
    const float* x0  = (const float*)d_in[0];
    const int*   ei  = (const int*)d_in[1];
    const float* Wd0 = (const float*)d_in[2];  const float* bd0 = (const float*)d_in[3];
    const float* Wd1 = (const float*)d_in[4];  const float* bd1 = (const float*)d_in[5];
    const float* Wd2 = (const float*)d_in[6];  const float* bd2 = (const float*)d_in[7];
    const float* Wd3 = (const float*)d_in[8];  const float* bd3 = (const float*)d_in[9];
    const float* p1  = (const float*)d_in[10];
    const float* p2  = (const float*)d_in[11];
    const float* p3  = (const float*)d_in[12];
    const float* Wu0 = (const float*)d_in[13]; const float* bu0 = (const float*)d_in[14];
    const float* Wu1 = (const float*)d_in[15]; const float* bu1 = (const float*)d_in[16];
    const float* Wu2 = (const float*)d_in[17]; const float* bu2 = (const float*)d_in[18];

    const int E = in_sizes[1] / 2;

    char* ws = (char*)d_ws;
    size_t off = 0;
    auto alloc = [&](size_t bytes) -> void* {
        void* p = ws + off;
        off += (bytes + 255) & ~(size_t)255;
        return p;
    };
    unsigned long long* M0 = (unsigned long long*)alloc((size_t)4096 * 64 * 8);
    short* A1h  = (short*)alloc((size_t)2048 * 2048 * 2);
    short* A2h  = (short*)alloc((size_t)1024 * 1024 * 2);
    short* A2l  = (short*)alloc((size_t)1024 * 1024 * 2);
    short* A3h  = (short*)alloc((size_t)512 * 512 * 2);
    short* A3l  = (short*)alloc((size_t)512 * 512 * 2);
    short* Gh   = (short*)alloc((size_t)1024 * 2048 * 2);
    short* Gl   = (short*)alloc((size_t)512 * 1024 * 2);
    int*   csr  = (int*)alloc((size_t)4096 * 128 * 4);
    unsigned long long* maskb = (unsigned long long*)alloc((size_t)2048 * 64 * 8);
    float* Zf   = (float*)alloc((size_t)4096 * 256 * 4);
    float* Cp   = (float*)alloc((size_t)64 * 1024 * 1024);   // partial arena
    float* xs0  = (float*)alloc((size_t)4096 * 256 * 4);
    float* xs1  = (float*)alloc((size_t)2048 * 256 * 4);
    float* xs2  = (float*)alloc((size_t)1024 * 256 * 4);
    float* xu0  = (float*)alloc((size_t)4096 * 256 * 4);
    float* xu1  = (float*)alloc((size_t)2048 * 256 * 4);
    float* xu2  = (float*)alloc((size_t)1024 * 256 * 4);
    short* xu0h = (short*)alloc((size_t)4096 * 256 * 2);
    short* xu0l = (short*)alloc((size_t)4096 * 256 * 2);
    short* xu1h = (short*)alloc((size_t)2048 * 256 * 2);
    short* xu1l = (short*)alloc((size_t)2048 * 256 * 2);
    short* xu2h = (short*)alloc((size_t)1024 * 256 * 2);
    short* xu2l = (short*)alloc((size_t)1024 * 256 * 2);
    short* X0h  = (short*)alloc((size_t)4096 * 128 * 2);
    short* X0l  = (short*)alloc((size_t)4096 * 128 * 2);
    short* xah  = (short*)alloc((size_t)2048 * 256 * 2);
    short* xal  = (short*)alloc((size_t)2048 * 256 * 2);
    short* Wth  = (short*)alloc((size_t)393216 * 2);
    short* Wtl  = (short*)alloc((size_t)393216 * 2);
    short* Zh   = (short*)alloc((size_t)256 * 4096 * 2);
    short* Zl   = (short*)alloc((size_t)256 * 4096 * 2);
    float* rs0  = (float*)alloc(4096 * 4);
    float* rs1  = (float*)alloc(2048 * 4);
    float* rs2  = (float*)alloc(1024 * 4);
    float* rs3  = (float*)alloc(512 * 4);
    float* scoreb = (float*)alloc(4096 * 4);
    int*   perm1  = (int*)alloc(2048 * 4);
    int*   perm2  = (int*)alloc(1024 * 4);
    int*   perm3  = (int*)alloc(512 * 4);
    int*   inv1   = (int*)alloc(4096 * 4);
    int*   inv2   = (int*)alloc(2048 * 4);
    int*   inv3   = (int*)alloc(1024 * 4);

    float* Cp2 = Cp + (size_t)8 * 1024 * 1024;   // +32 MiB: xw slice region

    // post-xw stages of a dense-A GCN layer: z_reduce -> AZ -> gcn_final
    auto gcn_rest = [&](int n, int Cout, const short* pAh, const short* pAl,
                        const float* rsA, const float* b, float* out,
                        short* oh, short* ol, int relu, int modeA, int Saz,
                        const int* inv, const float* res, int nout,
                        const float* pvec, const float* CpXw, int Sxw) {
        z_reduce<<<(n * Cout) / 1024, 256, 0, stream>>>(CpXw, Sxw, rsA, Zh, Zl, n, Cout);
        dim3 g(Cout / 128, n / 128, Saz);
        if (modeA == 1)
            gemm_bt<1, 0><<<g, 256, 0, stream>>>(pAh, nullptr, Zh, Zl, Cp, n, Cout, n, n / Saz);
        else
            gemm_bt<2, 0><<<g, 256, 0, stream>>>(pAh, pAl, Zh, Zl, Cp, n, Cout, n, n / Saz);
        if (pvec)
            gcn_final<1><<<(nout * Cout) / 1024, 256, 0, stream>>>(
                Cp, Saz, Zh, Zl, rsA, b, out, oh, ol, n, Cout, relu, inv, res,
                pvec, scoreb);
        else
            gcn_final<0><<<(nout * Cout) / 1024, 256, 0, stream>>>(
                Cp, Saz, Zh, Zl, rsA, b, out, oh, ol, n, Cout, relu, inv, res,
                nullptr, nullptr);
    };

    // full dense layer (up path, no overlap partner): xw at Cp base
    auto gcn_dense = [&](const short* Xh, const short* Xl, int n, int Kc, int Cout,
                         const short* pAh, const short* pAl, const float* rsA,
                         int wtoff, const float* b,
                         float* out, short* oh, short* ol, int relu, int modeA,
                         int Saz, const int* inv, const float* res, int nout,
                         const float* pvec) {
        int Sxw = 4;
        gemm_bt<2, 3><<<dim3(Cout / 128, n / 128, Sxw), 256, 0, stream>>>(
            Xh, Xl, Wth + wtoff, Wtl + wtoff, Cp, n, Cout, Kc, Kc / Sxw);
        gcn_rest(n, Cout, pAh, pAl, rsA, b, out, oh, ol, relu, modeA, Saz,
                 inv, res, nout, pvec, Cp, Sxw);
    };

    auto pool = [&](const float* xlev, int n, int* perm, int* inv) {
        int k = n / 2;
        rank_pool<<<n / 64, 512, 0, stream>>>(scoreb, n, k, xlev, perm, inv, xah, xal);
    };

    // ---- prep (weights + x0 split + M0 zero) + bitmask adjacency ----
    prep<<<4608, 256, 0, stream>>>(Wd0, Wd1, Wd2, Wd3, Wu0, Wu1, Wu2, x0,
                                   Wth, Wtl, X0h, X0l, M0);
    build_bits<<<(E + 255) / 256, 256, 0, stream>>>(ei, E, M0);

    // ---- down 0: FAT{x@W (256 blk) || row_compact CSR (1024 blk)} ----
    xw_fat<3, 0><<<256 + 1024, 256, 0, stream>>>(
        X0h, X0l, Wth, Wtl, Cp, 4096, 256, 128, 32,
        2, 32, 256,
        nullptr, nullptr, 0, nullptr, nullptr, nullptr, 0, rs0, M0, nullptr, csr);
    zf_reduce<<<1024, 256, 0, stream>>>(Cp, 4, rs0, Zf, 4096, 256);
    spmm_gcn<256, 1, 1><<<1024, 256, 0, stream>>>(csr, rs0, Zf, bd0, xs0, p1, scoreb);

    // ---- level 0 -> 1: pool, FAT{xw(L1)->Cp2 || mask_gather}, popc, merge ----
    pool(xs0, 4096, perm1, inv1);
    xw_fat<2, 3><<<128 + 512, 256, 0, stream>>>(
        xah, xal, Wth + 32768, Wtl + 32768, Cp2, 2048, 256, 256, 64,
        2, 16, 128,
        nullptr, nullptr, 0, perm1, nullptr, nullptr, 2048, rs1, M0, maskb, nullptr);
    popc_aug_p<<<dim3(32, 32, 4), 256, 0, stream>>>(maskb, (short*)Cp);
    aug_merge<<<dim3(32, 32), 256, 0, stream>>>((const short*)Cp, 2048, A1h, rs1);
    gcn_rest(2048, 256, A1h, nullptr, rs1, bd1, xs1, nullptr, nullptr, 1, 1, 8,
             nullptr, nullptr, 2048, p2, Cp2, 4);

    // ---- level 1 -> 2: pool, FAT{xw(L2)->Cp2 || gatherG_h}, TRI, finish ----
    pool(xs1, 2048, perm2, inv2);
    xw_fat<0, 3><<<64 + 1024, 256, 0, stream>>>(
        xah, xal, Wth + 98304, Wtl + 98304, Cp2, 1024, 256, 256, 64,
        2, 8, 64,
        A1h, nullptr, 2048, perm2, Gh, nullptr, 1024, rs2, nullptr, nullptr, nullptr);
    gemm_bt<0, 1><<<dim3(8, 8, 8), 256, 0, stream>>>(Gh, nullptr, Gh, nullptr, Cp, 1024, 1024, 2048, 256);
    aug_finish_f<true><<<(1024 * 1024 / 4) / 256, 256, 0, stream>>>(Cp, 8, 1024, A2h, A2l, rs2);
    gcn_rest(1024, 256, A2h, A2l, rs2, bd2, xs2, nullptr, nullptr, 1, 2, 8,
             nullptr, nullptr, 1024, p3, Cp2, 4);

    // ---- level 2 -> 3: pool, FAT{xw(down3)->Cp2 || gatherG_hl}, TRI, finish ----
    pool(xs2, 1024, perm3, inv3);
    xw_fat<1, 3><<<32 + 256, 256, 0, stream>>>(
        xah, xal, Wth + 163840, Wtl + 163840, Cp2, 512, 256, 256, 64,
        2, 4, 32,
        A2h, A2l, 1024, perm3, Gh, Gl, 512, rs3, nullptr, nullptr, nullptr);
    gemm_bt<2, 1><<<dim3(4, 4, 8), 256, 0, stream>>>(Gh, Gl, Gh, Gl, Cp, 512, 512, 1024, 128);
    aug_finish_f<true><<<(512 * 512 / 4) / 256, 256, 0, stream>>>(Cp, 8, 512, A3h, A3l, rs3);

    // ---- down 3: out scattered into xu2 = xs2 + u (inv3) ----
    gcn_rest(512, 256, A3h, A3l, rs3, bd3, xu2, xu2h, xu2l, 1, 2, 8,
             inv3, xs2, 1024, nullptr, Cp2, 4);

    // ---- up 0: out scattered into xu1 = xs1 + u (inv2) ----
    gcn_dense(xu2h, xu2l, 1024, 256, 256, A2h, A2l, rs2, 229376, bu0,
              xu1, xu1h, xu1l, 1, 2, 8, inv2, xs1, 2048, nullptr);

    // ---- up 1: out scattered into xu0 = xs0 + u (inv1) ----
    gcn_dense(xu1h, xu1l, 2048, 256, 256, A1h, nullptr, rs1, 294912, bu1,
              xu0, xu0h, xu0l, 1, 1, 8, inv1, xs0, 4096, nullptr);

    // ---- up 2 (A0 sparse, Cout=128, no relu) -> d_out ----
    gemm_bt<2, 0><<<dim3(1, 32, 8), 256, 0, stream>>>(
        xu0h, xu0l, Wth + 360448, Wtl + 360448, Cp, 4096, 128, 256, 32);
    zf_reduce<<<512, 256, 0, stream>>>(Cp, 8, rs0, Zf, 4096, 128);
    spmm_gcn<128, 0, 0><<<1024, 256, 0, stream>>>(csr, rs0, Zf, bu2, (float*)d_out,
                                                  nullptr, nullptr);
}

// Round 11
// 424.069 us; speedup vs baseline: 1.0986x; 1.0128x over previous
//
#include <hip/hip_runtime.h>

// ---------------------------------------------------------------------------
// GraphUNet on MI355X.  Round-25 = round-24 resubmit (container infra failure,
// kernel audited: rank_pool chunking exact for n in {1024,2048,4096}; Cp2
// slice region 8 MiB max inside arena; xw_fat payload coverage exact).
//
// R23 (429.5 us) + narrow-grid widening on strictly-serial stages:
//  * rank_pool: 32 rows/block (16 j-slices x 32 lanes), grid n/32 ->
//    128/64/32 blocks (was 64/32/16).  Same total work, zero extra traffic.
//  * Sxw 4->8 on the three narrowest xw GEMMs: L2-xw (64->128 blocks),
//    down3-xw (32->64), up0-xw (64->128).  Extra slice traffic 2-4 MB x2
//    per level (L2/L3-resident) << TLP gain.  L1/up1 stay Sxw=4 (already
//    128 blocks; 16 MB extra would net negative — R4 lesson).
// Everything else identical to R23.
// ---------------------------------------------------------------------------

typedef __attribute__((ext_vector_type(8))) short bf16x8;
typedef __attribute__((ext_vector_type(4))) short s16x4;
typedef __attribute__((ext_vector_type(4))) float f32x4;

__device__ __forceinline__ short f2bf(float f) {
    unsigned u = __builtin_bit_cast(unsigned, f);
    u += 0x7FFFu + ((u >> 16) & 1u);          // RNE
    return (short)(u >> 16);
}
__device__ __forceinline__ float bf2f(short s) {
    unsigned u = ((unsigned)(unsigned short)s) << 16;
    return __builtin_bit_cast(float, u);
}

#define GLL16(gsrc, ldst)                                                        \
    __builtin_amdgcn_global_load_lds(                                            \
        (__attribute__((address_space(1))) void*)(gsrc),                         \
        (__attribute__((address_space(3))) void*)(ldst), 16, 0, 0)

// ---------------------------------------------------------------------------
// bf16 BT GEMM: C(MxN) = A(MxK) @ B^T, B stored N x K row-major.
// MODE 0: Ah@Bh ; 1: +Ah@Bl ; 2: +Al@Bh   (lo*lo dropped, ~2^-18 rel)
// EPI 0: fp32 partial slice [z][M][N]
// EPI 1: fp32 mirrored square slices (TRI: blocks by>bx exit)
// EPI 3: fp32 TRANSPOSED partial slice [z][N][M] (f32x4 stores)
// ---------------------------------------------------------------------------
template<int MODE, int EPI>
__global__ __launch_bounds__(256, 2)
void gemm_bt(const short* __restrict__ Ah, const short* __restrict__ Al,
             const short* __restrict__ Bh, const short* __restrict__ Bl,
             float* __restrict__ Cf, int M, int N, int K, int kChunk)
{
    if (EPI == 1 && (int)blockIdx.y > (int)blockIdx.x) return;

    __shared__ short sAh[128 * 32];
    __shared__ short sBh[128 * 32];
    __shared__ short sAl[(MODE == 2) ? 128 * 32 : 8];
    __shared__ short sBl[(MODE >= 1) ? 128 * 32 : 8];

    const int t    = threadIdx.x;
    const int lane = t & 63;
    const int wave = t >> 6;
    const int tM   = blockIdx.y * 128;
    const int tN   = blockIdx.x * 128;
    const int k0   = blockIdx.z * kChunk;

    const int wm  = (wave >> 1) * 64;
    const int wn  = (wave & 1) * 64;
    const int l15 = lane & 15;
    const int g8  = (lane >> 4) * 8;

    f32x4 acc[4][4];
    const f32x4 zero = {0.f, 0.f, 0.f, 0.f};
#pragma unroll
    for (int i = 0; i < 4; i++)
#pragma unroll
        for (int j = 0; j < 4; j++) acc[i][j] = zero;

    const int i0 = t, i1 = t + 256;
    const short* a0 = Ah + (size_t)(tM + (i0 >> 2)) * K + (i0 & 3) * 8;
    const short* a1 = Ah + (size_t)(tM + (i1 >> 2)) * K + (i1 & 3) * 8;
    const short* b0 = Bh + (size_t)(tN + (i0 >> 2)) * K + (i0 & 3) * 8;
    const short* b1 = Bh + (size_t)(tN + (i1 >> 2)) * K + (i1 & 3) * 8;
    const short *bl0 = nullptr, *bl1 = nullptr, *al0 = nullptr, *al1 = nullptr;
    if (MODE >= 1) {
        bl0 = Bl + (size_t)(tN + (i0 >> 2)) * K + (i0 & 3) * 8;
        bl1 = Bl + (size_t)(tN + (i1 >> 2)) * K + (i1 & 3) * 8;
    }
    if (MODE == 2) {
        al0 = Al + (size_t)(tM + (i0 >> 2)) * K + (i0 & 3) * 8;
        al1 = Al + (size_t)(tM + (i1 >> 2)) * K + (i1 & 3) * 8;
    }

    for (int kb = k0; kb < k0 + kChunk; kb += 32) {
        GLL16(a0 + kb, &sAh[i0 * 8]);
        GLL16(a1 + kb, &sAh[i1 * 8]);
        GLL16(b0 + kb, &sBh[i0 * 8]);
        GLL16(b1 + kb, &sBh[i1 * 8]);
        if (MODE >= 1) { GLL16(bl0 + kb, &sBl[i0 * 8]); GLL16(bl1 + kb, &sBl[i1 * 8]); }
        if (MODE == 2) { GLL16(al0 + kb, &sAl[i0 * 8]); GLL16(al1 + kb, &sAl[i1 * 8]); }
        __syncthreads();

        bf16x8 aF[4], bF[4], aL[4], bL[4];
#pragma unroll
        for (int i = 0; i < 4; i++)
            aF[i] = *(const bf16x8*)&sAh[(wm + i * 16 + l15) * 32 + g8];
#pragma unroll
        for (int j = 0; j < 4; j++)
            bF[j] = *(const bf16x8*)&sBh[(wn + j * 16 + l15) * 32 + g8];
        if (MODE >= 1)
#pragma unroll
            for (int j = 0; j < 4; j++)
                bL[j] = *(const bf16x8*)&sBl[(wn + j * 16 + l15) * 32 + g8];
        if (MODE == 2)
#pragma unroll
            for (int i = 0; i < 4; i++)
                aL[i] = *(const bf16x8*)&sAl[(wm + i * 16 + l15) * 32 + g8];

#pragma unroll
        for (int i = 0; i < 4; i++)
#pragma unroll
            for (int j = 0; j < 4; j++) {
                acc[i][j] = __builtin_amdgcn_mfma_f32_16x16x32_bf16(aF[i], bF[j], acc[i][j], 0, 0, 0);
                if (MODE >= 1)
                    acc[i][j] = __builtin_amdgcn_mfma_f32_16x16x32_bf16(aF[i], bL[j], acc[i][j], 0, 0, 0);
                if (MODE == 2)
                    acc[i][j] = __builtin_amdgcn_mfma_f32_16x16x32_bf16(aL[i], bF[j], acc[i][j], 0, 0, 0);
            }
        __syncthreads();
    }

    // C/D layout: col=lane&15, row=(lane>>4)*4+reg  [m89-verified]
    const int r4 = (lane >> 4) * 4;
    if (EPI == 3) {
        float* CT = Cf + (size_t)blockIdx.z * M * N;   // [N][M]
#pragma unroll
        for (int i = 0; i < 4; i++)
#pragma unroll
            for (int j = 0; j < 4; j++) {
                const int col   = tN + wn + j * 16 + l15;
                const int rbase = tM + wm + i * 16 + r4;
                *(f32x4*)&CT[(size_t)col * M + rbase] = acc[i][j];
            }
    } else {
        float* Cg = Cf + (size_t)blockIdx.z * M * N;
#pragma unroll
        for (int i = 0; i < 4; i++)
#pragma unroll
            for (int j = 0; j < 4; j++) {
                const int col = tN + wn + j * 16 + l15;
                float* cp = Cg + (size_t)(tM + wm + i * 16 + r4) * N + col;
#pragma unroll
                for (int r = 0; r < 4; r++) cp[(size_t)r * N] = acc[i][j][r];
            }
        if (EPI == 1 && tM != tN) {
#pragma unroll
            for (int i = 0; i < 4; i++)
#pragma unroll
                for (int j = 0; j < 4; j++) {
                    const int col   = tN + wn + j * 16 + l15;
                    const int rbase = tM + wm + i * 16 + r4;
                    *(f32x4*)&Cg[(size_t)col * N + rbase] = acc[i][j];
                }
        }
    }
}

// ---------------------------------------------------------------------------
// FAT kernel: xw GEMM (MODE2, EPI template) in blocks [0,GB), payload after.
// PAY 0: gatherG_h  (pA row gather +I -> pGh; zero rsz[pkk])
// PAY 1: gatherG_hl (pA/pAlo hi-lo gather +I -> pGh/pGl; zero rsz[pkk])
// PAY 2: mask_gather (M0 row gather +self bit -> masko; zero rsz[pkk])
// PAY 3: row_compact_bits (M0 bitmask -> csrOut + rsz degrees)
// GEMM blocks dispatch first (long pole); payload blocks backfill CUs.
// ---------------------------------------------------------------------------
template<int PAY, int EPI>
__global__ __launch_bounds__(256, 2)
void xw_fat(const short* __restrict__ Ah, const short* __restrict__ Al,
            const short* __restrict__ Bh, const short* __restrict__ Bl,
            float* __restrict__ Cf, int M, int N, int K, int kChunk,
            int gx, int gy, int GB,
            const short* __restrict__ pA, const short* __restrict__ pAlo,
            int pn, const int* __restrict__ perm,
            short* __restrict__ pGh, short* __restrict__ pGl, int pkk,
            float* __restrict__ rsz,
            const unsigned long long* __restrict__ M0s,
            unsigned long long* __restrict__ masko,
            int* __restrict__ csrOut)
{
    __shared__ short sAh[128 * 32];
    __shared__ short sBh[128 * 32];
    __shared__ short sAl[128 * 32];
    __shared__ short sBl[128 * 32];

    const int bid = (int)blockIdx.x;
    const int t   = threadIdx.x;

    if (bid >= GB) {
        const int pidx = (bid - GB) * 256 + t;
        if (PAY == 3) {
            // row_compact_bits: 4 rows per block, wave prefix-scan compaction
            const int prow = (bid - GB) * 4 + (t >> 6);
            const int lane = t & 63;
            unsigned long long w = M0s[(size_t)prow * 64 + lane];
            int c = __popcll(w);
            int incl = c;
            for (int off2 = 1; off2 < 64; off2 <<= 1) {
                int vv = __shfl_up(incl, off2);
                if (lane >= off2) incl += vv;
            }
            int base = incl - c;
            int* outp = csrOut + (size_t)prow * 128;
            while (w) {
                int b = __ffsll((unsigned long long)w) - 1;
                if (base < 128) outp[base] = lane * 64 + b;
                base++;
                w &= w - 1;
            }
            if (lane == 63) rsz[prow] = (float)incl;
        } else if (PAY == 2) {
            if (pidx < pkk) rsz[pidx] = 0.f;
            int r = pidx >> 6, l = pidx & 63;
            int u = perm[r];
            unsigned long long w = M0s[(size_t)u * 64 + l];
            if ((u >> 6) == l) w |= 1ull << (u & 63);
            masko[pidx] = w;
        } else if (PAY == 0) {
            if (pidx < pkk) rsz[pidx] = 0.f;
            int t8 = pidx * 8;
            if (t8 < pkk * pn) {
                int r = t8 / pn, c0 = t8 - r * pn;
                int pr = perm[r];
                bf16x8 a = *(const bf16x8*)&pA[(size_t)pr * pn + c0];
                if (pr >= c0 && pr < c0 + 8)
                    a[pr - c0] = f2bf(bf2f(a[pr - c0]) + 1.f);
                *(bf16x8*)&pGh[t8] = a;
            }
        } else {
            if (pidx < pkk) rsz[pidx] = 0.f;
            int t8 = pidx * 8;
            if (t8 < pkk * pn) {
                int r = t8 / pn, c0 = t8 - r * pn;
                int pr = perm[r];
                bf16x8 ah = *(const bf16x8*)&pA[(size_t)pr * pn + c0];
                bf16x8 al = *(const bf16x8*)&pAlo[(size_t)pr * pn + c0];
                bf16x8 gh, gl;
#pragma unroll
                for (int q = 0; q < 8; q++) {
                    float v = bf2f(ah[q]) + bf2f(al[q]) + ((c0 + q == pr) ? 1.f : 0.f);
                    short h = f2bf(v);
                    gh[q] = h; gl[q] = f2bf(v - bf2f(h));
                }
                *(bf16x8*)&pGh[t8] = gh;
                *(bf16x8*)&pGl[t8] = gl;
            }
        }
        return;
    }

    // ---- xw GEMM: MODE2 (identical math to gemm_bt<2,EPI>) ----
    const int bx = bid % gx;
    const int by = (bid / gx) % gy;
    const int bz = bid / (gx * gy);

    const int lane = t & 63;
    const int wave = t >> 6;
    const int tM   = by * 128;
    const int tN   = bx * 128;
    const int k0   = bz * kChunk;

    const int wm  = (wave >> 1) * 64;
    const int wn  = (wave & 1) * 64;
    const int l15 = lane & 15;
    const int g8  = (lane >> 4) * 8;

    f32x4 acc[4][4];
    const f32x4 zero = {0.f, 0.f, 0.f, 0.f};
#pragma unroll
    for (int i = 0; i < 4; i++)
#pragma unroll
        for (int j = 0; j < 4; j++) acc[i][j] = zero;

    const int i0 = t, i1 = t + 256;
    const short* a0  = Ah + (size_t)(tM + (i0 >> 2)) * K + (i0 & 3) * 8;
    const short* a1  = Ah + (size_t)(tM + (i1 >> 2)) * K + (i1 & 3) * 8;
    const short* b0  = Bh + (size_t)(tN + (i0 >> 2)) * K + (i0 & 3) * 8;
    const short* b1  = Bh + (size_t)(tN + (i1 >> 2)) * K + (i1 & 3) * 8;
    const short* bl0 = Bl + (size_t)(tN + (i0 >> 2)) * K + (i0 & 3) * 8;
    const short* bl1 = Bl + (size_t)(tN + (i1 >> 2)) * K + (i1 & 3) * 8;
    const short* al0 = Al + (size_t)(tM + (i0 >> 2)) * K + (i0 & 3) * 8;
    const short* al1 = Al + (size_t)(tM + (i1 >> 2)) * K + (i1 & 3) * 8;

    for (int kb = k0; kb < k0 + kChunk; kb += 32) {
        GLL16(a0 + kb, &sAh[i0 * 8]);
        GLL16(a1 + kb, &sAh[i1 * 8]);
        GLL16(b0 + kb, &sBh[i0 * 8]);
        GLL16(b1 + kb, &sBh[i1 * 8]);
        GLL16(bl0 + kb, &sBl[i0 * 8]);
        GLL16(bl1 + kb, &sBl[i1 * 8]);
        GLL16(al0 + kb, &sAl[i0 * 8]);
        GLL16(al1 + kb, &sAl[i1 * 8]);
        __syncthreads();

        bf16x8 aF[4], bF[4], aL[4], bL[4];
#pragma unroll
        for (int i = 0; i < 4; i++)
            aF[i] = *(const bf16x8*)&sAh[(wm + i * 16 + l15) * 32 + g8];
#pragma unroll
        for (int j = 0; j < 4; j++)
            bF[j] = *(const bf16x8*)&sBh[(wn + j * 16 + l15) * 32 + g8];
#pragma unroll
        for (int j = 0; j < 4; j++)
            bL[j] = *(const bf16x8*)&sBl[(wn + j * 16 + l15) * 32 + g8];
#pragma unroll
        for (int i = 0; i < 4; i++)
            aL[i] = *(const bf16x8*)&sAl[(wm + i * 16 + l15) * 32 + g8];

#pragma unroll
        for (int i = 0; i < 4; i++)
#pragma unroll
            for (int j = 0; j < 4; j++) {
                acc[i][j] = __builtin_amdgcn_mfma_f32_16x16x32_bf16(aF[i], bF[j], acc[i][j], 0, 0, 0);
                acc[i][j] = __builtin_amdgcn_mfma_f32_16x16x32_bf16(aF[i], bL[j], acc[i][j], 0, 0, 0);
                acc[i][j] = __builtin_amdgcn_mfma_f32_16x16x32_bf16(aL[i], bF[j], acc[i][j], 0, 0, 0);
            }
        __syncthreads();
    }

    const int r4 = (lane >> 4) * 4;
    if (EPI == 3) {
        float* CT = Cf + (size_t)bz * M * N;   // [N][M]
#pragma unroll
        for (int i = 0; i < 4; i++)
#pragma unroll
            for (int j = 0; j < 4; j++) {
                const int col   = tN + wn + j * 16 + l15;
                const int rbase = tM + wm + i * 16 + r4;
                *(f32x4*)&CT[(size_t)col * M + rbase] = acc[i][j];
            }
    } else {
        float* Cg = Cf + (size_t)bz * M * N;   // [M][N]
#pragma unroll
        for (int i = 0; i < 4; i++)
#pragma unroll
            for (int j = 0; j < 4; j++) {
                const int col = tN + wn + j * 16 + l15;
                float* cp = Cg + (size_t)(tM + wm + i * 16 + r4) * N + col;
#pragma unroll
                for (int r = 0; r < 4; r++) cp[(size_t)r * N] = acc[i][j][r];
            }
    }
}

// ---------------------------------------------------------------------------
// Utility kernels
// ---------------------------------------------------------------------------

// one-shot prep: W^T hi/lo for all 7 layers + x0 hi/lo split + zero M0 bitmask
__global__ void prep(const float* __restrict__ Wd0, const float* __restrict__ Wd1,
                     const float* __restrict__ Wd2, const float* __restrict__ Wd3,
                     const float* __restrict__ Wu0, const float* __restrict__ Wu1,
                     const float* __restrict__ Wu2, const float* __restrict__ x0,
                     short* __restrict__ Wth, short* __restrict__ Wtl,
                     short* __restrict__ Xh, short* __restrict__ Xl,
                     unsigned long long* __restrict__ M0)
{
    int t = blockIdx.x * 256 + threadIdx.x;
    float v; int dst;
    if (t < 32768)       { int e = t;          v = Wd0[e]; dst = 0      + (e & 255) * 128 + (e >> 8); }
    else if (t < 98304)  { int e = t - 32768;  v = Wd1[e]; dst = 32768  + (e & 255) * 256 + (e >> 8); }
    else if (t < 163840) { int e = t - 98304;  v = Wd2[e]; dst = 98304  + (e & 255) * 256 + (e >> 8); }
    else if (t < 229376) { int e = t - 163840; v = Wd3[e]; dst = 163840 + (e & 255) * 256 + (e >> 8); }
    else if (t < 294912) { int e = t - 229376; v = Wu0[e]; dst = 229376 + (e & 255) * 256 + (e >> 8); }
    else if (t < 360448) { int e = t - 294912; v = Wu1[e]; dst = 294912 + (e & 255) * 256 + (e >> 8); }
    else if (t < 393216) { int e = t - 360448; v = Wu2[e]; dst = 360448 + (e & 127) * 256 + (e >> 7); }
    else if (t < 917504) {
        int e = t - 393216;                      // x0: 4096*128
        v = x0[e];
        short h = f2bf(v);
        Xh[e] = h; Xl[e] = f2bf(v - bf2f(h));
        return;
    } else {
        M0[t - 917504] = 0ull;                   // 4096*64 words
        return;
    }
    short h = f2bf(v);
    Wth[dst] = h; Wtl[dst] = f2bf(v - bf2f(h));
}

// edge list -> symmetric self-loop-free row bitmask (dedup for free)
__global__ void build_bits(const int* __restrict__ ei, int E,
                           unsigned long long* __restrict__ M0)
{
    int e = blockIdx.x * 256 + threadIdx.x;
    if (e >= E) return;
    int i = ei[e], j = ei[E + e];
    if (i != j) {
        atomicOr(&M0[(size_t)i * 64 + (j >> 6)], 1ull << (j & 63));
        atomicOr(&M0[(size_t)j * 64 + (i >> 6)], 1ull << (i & 63));
    }
}

// popcount partial: slice z covers words [z*16, z*16+16).  64x64 TRI tiles,
// 18 KB LDS -> 8 blocks/CU.  int16 partial tile at Cp[(z*1024 + by*32+bx)*4096].
#define PSTR2 18
__global__ __launch_bounds__(256, 8)
void popc_aug_p(const unsigned long long* __restrict__ mask,
                short* __restrict__ Cp)
{
    const int bx = blockIdx.x, by = blockIdx.y, z = blockIdx.z;
    if (by > bx) return;
    __shared__ unsigned long long a[64 * PSTR2];
    __shared__ unsigned long long b[64 * PSTR2];
    const int t = threadIdx.x;
#pragma unroll
    for (int p = 0; p < 4; p++) {
        int idx = p * 256 + t;           // 0..1023 = rr*16 + w
        int rr = idx >> 4, w = idx & 15;
        a[rr * PSTR2 + w] = mask[((size_t)(by * 64 + rr)) * 64 + z * 16 + w];
        b[rr * PSTR2 + w] = mask[((size_t)(bx * 64 + rr)) * 64 + z * 16 + w];
    }
    __syncthreads();
    const int i0 = (t >> 4) * 4;         // 4 consecutive rows
    const int j0 = t & 15;               // cols j0 + 16*qj
    int acc[4][4];
#pragma unroll
    for (int qi = 0; qi < 4; qi++)
#pragma unroll
        for (int qj = 0; qj < 4; qj++) acc[qi][qj] = 0;
#pragma unroll
    for (int w = 0; w < 16; w += 2) {
        ulong2 av[4], bv[4];
#pragma unroll
        for (int q = 0; q < 4; q++) av[q] = *(const ulong2*)&a[(i0 + q) * PSTR2 + w];
#pragma unroll
        for (int q = 0; q < 4; q++) bv[q] = *(const ulong2*)&b[(j0 + 16 * q) * PSTR2 + w];
#pragma unroll
        for (int qi = 0; qi < 4; qi++)
#pragma unroll
            for (int qj = 0; qj < 4; qj++) {
                acc[qi][qj] += __builtin_popcountll(av[qi].x & bv[qj].x);
                acc[qi][qj] += __builtin_popcountll(av[qi].y & bv[qj].y);
            }
    }
    short* out = Cp + ((size_t)z * 1024 + (size_t)(by * 32 + bx)) * 4096;
#pragma unroll
    for (int qi = 0; qi < 4; qi++)
#pragma unroll
        for (int qj = 0; qj < 4; qj++)
            out[(i0 + qi) * 64 + j0 + 16 * qj] = (short)acc[qi][qj];
}

// merge 4 int16 slices -> A1h (bf16, diag 0) + LDS-transposed mirror + rowsums
__global__ __launch_bounds__(256)
void aug_merge(const short* __restrict__ Cp, int kk,
               short* __restrict__ Ahs, float* __restrict__ rs)
{
    const int bx = blockIdx.x, by = blockIdx.y;
    if (by > bx) return;
    __shared__ float tile[64][65];
    __shared__ float rsum[64], csum[64];
    const int t = threadIdx.x;
    const int i  = t >> 2;               // row 0..63
    const int c0 = (t & 3) * 16;         // 16 consecutive cols
    const size_t tb = (size_t)(by * 32 + bx) * 4096;
    const size_t ss = (size_t)1024 * 4096;
    if (t < 64) { rsum[t] = 0.f; csum[t] = 0.f; }

    int v[16];
#pragma unroll
    for (int q = 0; q < 16; q++) v[q] = 0;
    for (int s = 0; s < 4; s++) {
        bf16x8 p0 = *(const bf16x8*)&Cp[tb + s * ss + i * 64 + c0];
        bf16x8 p1 = *(const bf16x8*)&Cp[tb + s * ss + i * 64 + c0 + 8];
#pragma unroll
        for (int q = 0; q < 8; q++) { v[q] += (int)p0[q]; v[8 + q] += (int)p1[q]; }
    }
    const int gi = by * 64 + i;
    float rp = 0.f;
    s16x4 pk[4];
#pragma unroll
    for (int q = 0; q < 16; q++) {
        const int gj = bx * 64 + c0 + q;
        float val = (gi == gj) ? 0.f : (float)v[q];
        tile[i][c0 + q] = val;
        rp += val;
        pk[q >> 2][q & 3] = f2bf(val);
    }
#pragma unroll
    for (int q = 0; q < 4; q++)
        *(s16x4*)&Ahs[(size_t)gi * kk + bx * 64 + c0 + q * 4] = pk[q];
    __syncthreads();
    atomicAdd(&rsum[i], rp);
    if (bx != by) {
        float cpv = 0.f;
#pragma unroll
        for (int q = 0; q < 16; q++) {
            float val = tile[c0 + q][i];
            cpv += val;
            pk[q >> 2][q & 3] = f2bf(val);
        }
#pragma unroll
        for (int q = 0; q < 4; q++)
            *(s16x4*)&Ahs[(size_t)(bx * 64 + i) * kk + by * 64 + c0 + q * 4] = pk[q];
        atomicAdd(&csum[i], cpv);
    }
    __syncthreads();
    if (t < 64) {
        atomicAdd(&rs[by * 64 + t], rsum[t]);
        if (bx != by) atomicAdd(&rs[bx * 64 + t], csum[t]);
    }
}

// reduce transposed xw partial slices -> Z^T hi/lo  (x4 vectorized)
__global__ void z_reduce(const float* __restrict__ Cp, int S,
                         const float* __restrict__ rs,
                         short* __restrict__ Zh, short* __restrict__ Zl,
                         int n, int C)
{
    int t4 = (blockIdx.x * 256 + threadIdx.x) * 4;   // t = c*n + r layout
    int r = t4 % n;
    size_t stride = (size_t)n * C;
    f32x4 v = {0.f, 0.f, 0.f, 0.f};
    for (int s = 0; s < S; s++) v += *(const f32x4*)&Cp[t4 + s * stride];
    f32x4 rsv = *(const f32x4*)&rs[r];
    s16x4 zh, zl;
#pragma unroll
    for (int q = 0; q < 4; q++) {
        float z = v[q] / sqrtf(rsv[q] + 2.f);
        short h = f2bf(z);
        zh[q] = h; zl[q] = f2bf(z - bf2f(h));
    }
    *(s16x4*)&Zh[t4] = zh;
    *(s16x4*)&Zl[t4] = zl;
}

// reduce row-major xw partial slices -> Zf fp32 [r][C]  (x4 vectorized)
__global__ void zf_reduce(const float* __restrict__ Cp, int S,
                          const float* __restrict__ rs,
                          float* __restrict__ Zf, int n, int C)
{
    int t4 = (blockIdx.x * 256 + threadIdx.x) * 4;   // t = r*C + c
    int r = t4 / C;
    size_t stride = (size_t)n * C;
    f32x4 v = {0.f, 0.f, 0.f, 0.f};
    for (int s = 0; s < S; s++) v += *(const f32x4*)&Cp[t4 + s * stride];
    float d = 1.f / sqrtf(rs[r] + 2.f);
    v *= d;
    *(f32x4*)&Zf[t4] = v;
}

// CSR SpMM + fused GCN epilogue (+ optional fused pool score: SC=1)
template<int CN, int RELU, int SC>
__global__ __launch_bounds__(256)
void spmm_gcn(const int* __restrict__ csr, const float* __restrict__ rs,
              const float* __restrict__ Zf, const float* __restrict__ b,
              float* __restrict__ out,
              const float* __restrict__ pvec, float* __restrict__ score)
{
    const int lane = threadIdx.x & 63;
    const int row  = blockIdx.x * 4 + (threadIdx.x >> 6);
    const int dg   = (int)rs[row];
    const int* nb  = csr + (size_t)row * 128;
    if (CN == 256) {
        const int c = lane * 4;
        float4 acc = {0.f, 0.f, 0.f, 0.f};
        int q = 0;
        for (; q + 4 <= dg; q += 4) {
            int j0 = nb[q], j1 = nb[q+1], j2 = nb[q+2], j3 = nb[q+3];
            float4 z0 = *(const float4*)&Zf[(size_t)j0 * CN + c];
            float4 z1 = *(const float4*)&Zf[(size_t)j1 * CN + c];
            float4 z2 = *(const float4*)&Zf[(size_t)j2 * CN + c];
            float4 z3 = *(const float4*)&Zf[(size_t)j3 * CN + c];
            acc.x += z0.x; acc.y += z0.y; acc.z += z0.z; acc.w += z0.w;
            acc.x += z1.x; acc.y += z1.y; acc.z += z1.z; acc.w += z1.w;
            acc.x += z2.x; acc.y += z2.y; acc.z += z2.z; acc.w += z2.w;
            acc.x += z3.x; acc.y += z3.y; acc.z += z3.z; acc.w += z3.w;
        }
        for (; q < dg; q++) {
            float4 z = *(const float4*)&Zf[(size_t)nb[q] * CN + c];
            acc.x += z.x; acc.y += z.y; acc.z += z.z; acc.w += z.w;
        }
        float d = 1.f / sqrtf(rs[row] + 2.f);
        float4 zi = *(const float4*)&Zf[(size_t)row * CN + c];
        float4 bb = *(const float4*)&b[c];
        float4 g;
        g.x = d * acc.x + 2.f * d * zi.x + bb.x;
        g.y = d * acc.y + 2.f * d * zi.y + bb.y;
        g.z = d * acc.z + 2.f * d * zi.z + bb.z;
        g.w = d * acc.w + 2.f * d * zi.w + bb.w;
        if (RELU) {
            g.x = fmaxf(g.x, 0.f); g.y = fmaxf(g.y, 0.f);
            g.z = fmaxf(g.z, 0.f); g.w = fmaxf(g.w, 0.f);
        }
        *(float4*)&out[(size_t)row * CN + c] = g;
        if (SC) {
            float4 pv = ((const float4*)pvec)[lane];
            double nn  = (double)pv.x * pv.x + (double)pv.y * pv.y +
                         (double)pv.z * pv.z + (double)pv.w * pv.w;
            double acd = (double)g.x * pv.x + (double)g.y * pv.y +
                         (double)g.z * pv.z + (double)g.w * pv.w;
            for (int off = 32; off; off >>= 1) {
                acd += __shfl_down(acd, off);
                nn  += __shfl_down(nn, off);
            }
            if (lane == 0) score[row] = tanhf((float)(acd / sqrt(nn)));
        }
    } else {
        const int c = lane * 2;
        float2 acc = {0.f, 0.f};
        int q = 0;
        for (; q + 4 <= dg; q += 4) {
            int j0 = nb[q], j1 = nb[q+1], j2 = nb[q+2], j3 = nb[q+3];
            float2 z0 = *(const float2*)&Zf[(size_t)j0 * CN + c];
            float2 z1 = *(const float2*)&Zf[(size_t)j1 * CN + c];
            float2 z2 = *(const float2*)&Zf[(size_t)j2 * CN + c];
            float2 z3 = *(const float2*)&Zf[(size_t)j3 * CN + c];
            acc.x += z0.x; acc.y += z0.y;
            acc.x += z1.x; acc.y += z1.y;
            acc.x += z2.x; acc.y += z2.y;
            acc.x += z3.x; acc.y += z3.y;
        }
        for (; q < dg; q++) {
            float2 z = *(const float2*)&Zf[(size_t)nb[q] * CN + c];
            acc.x += z.x; acc.y += z.y;
        }
        float d = 1.f / sqrtf(rs[row] + 2.f);
        float2 zi = *(const float2*)&Zf[(size_t)row * CN + c];
        float2 g;
        g.x = d * acc.x + 2.f * d * zi.x + b[c];
        g.y = d * acc.y + 2.f * d * zi.y + b[c + 1];
        if (RELU) { g.x = fmaxf(g.x, 0.f); g.y = fmaxf(g.y, 0.f); }
        *(float2*)&out[(size_t)row * CN + c] = g;
    }
}

// fused: reduce AZ slices + GCN epilogue (+inv scatter) (+compile-time score)
template<int SC>
__global__ void gcn_final(const float* __restrict__ Cp, int S,
                          const short* __restrict__ Zh, const short* __restrict__ Zl,
                          const float* __restrict__ rs, const float* __restrict__ b,
                          float* __restrict__ out, short* __restrict__ oh,
                          short* __restrict__ ol, int k, int C, int relu,
                          const int* __restrict__ inv, const float* __restrict__ res,
                          const float* __restrict__ pvec, float* __restrict__ score)
{
    int t4 = (blockIdx.x * 256 + threadIdx.x) * 4;
    int j = t4 / C, c = t4 - j * C;
    int r = inv ? inv[j] : j;
    f32x4 v = res ? *(const f32x4*)&res[t4] : (f32x4){0.f, 0.f, 0.f, 0.f};
    if (r >= 0) {
        size_t base = (size_t)r * C + c;
        size_t stride = (size_t)k * C;
        f32x4 az = {0.f, 0.f, 0.f, 0.f};
        for (int s = 0; s < S; s++) az += *(const f32x4*)&Cp[base + s * stride];
        float d = 1.f / sqrtf(rs[r] + 2.f);
        f32x4 bb = *(const f32x4*)&b[c];
#pragma unroll
        for (int q = 0; q < 4; q++) {
            size_t zi = (size_t)(c + q) * k + r;
            float zz = bf2f(Zh[zi]) + bf2f(Zl[zi]);      // zz ~= d * xw
            float g = d * az[q] + 2.f * d * zz + bb[q];
            if (relu && g < 0.f) g = 0.f;
            v[q] += g;
        }
    }
    *(f32x4*)&out[t4] = v;
    if (oh) {
        s16x4 hh, ll;
#pragma unroll
        for (int q = 0; q < 4; q++) {
            short h = f2bf(v[q]);
            hh[q] = h; ll[q] = f2bf(v[q] - bf2f(h));
        }
        *(s16x4*)&oh[t4] = hh;
        *(s16x4*)&ol[t4] = ll;
    }
    if (SC) {
        // C==256: one wave per row (64 lanes x 4 cols) -> free score reduce,
        // math identical to the old score_kernel (double dot / double norm).
        const int lane = threadIdx.x & 63;
        float4 pv = *(const float4*)&pvec[c];
        double nn  = (double)pv.x * pv.x + (double)pv.y * pv.y +
                     (double)pv.z * pv.z + (double)pv.w * pv.w;
        double acd = (double)v[0] * pv.x + (double)v[1] * pv.y +
                     (double)v[2] * pv.z + (double)v[3] * pv.w;
        for (int off = 32; off; off >>= 1) {
            acd += __shfl_down(acd, off);
            nn  += __shfl_down(nn, off);
        }
        if (lane == 0) score[j] = tanhf((float)(acd / sqrt(nn)));
    }
}

__device__ __forceinline__ unsigned long long packkey(float s, int i) {
    unsigned u = __builtin_bit_cast(unsigned, s);
    u = (u & 0x80000000u) ? ~u : (u | 0x80000000u);
    return ((unsigned long long)u << 32) | (unsigned)(0xFFFFFFFFu - (unsigned)i);
}

// fused rank + select + gather: block owns 32 rows (16 j-slices x 32 lanes);
// scans all n keys from 512-key LDS chunks; then scatter-writes perm/inv and
// the gathered+scaled hi/lo x rows (wave per selected row, C=256).
// Grid n/32 (128/64/32 blocks) — 2x wider than the old 64-row version.
__global__ __launch_bounds__(512)
void rank_pool(const float* __restrict__ score, int n, int k,
               const float* __restrict__ xold,
               int* __restrict__ perm, int* __restrict__ inv,
               short* __restrict__ Xh, short* __restrict__ Xl)
{
    __shared__ unsigned long long sk[512];
    __shared__ int rk[32];
    __shared__ int selrow[32];
    __shared__ int selrank[32];
    __shared__ float selval[32];
    __shared__ int cnt;
    const int t  = threadIdx.x;
    const int il = t & 31;            // local row
    const int js = t >> 5;            // j-slice (16 slices of 32)
    const int i  = blockIdx.x * 32 + il;
    if (t < 32) rk[t] = 0;
    if (t == 0) cnt = 0;
    const unsigned long long mykey = packkey(score[i], i);
    int r = 0;
    for (int jb = 0; jb < n; jb += 512) {
        __syncthreads();
        if (jb + t < n) sk[t] = packkey(score[jb + t], jb + t);
        __syncthreads();
        const unsigned long long* p = &sk[js * 32];
#pragma unroll 16
        for (int q = 0; q < 32; q++) r += (p[q] > mykey) ? 1 : 0;
    }
    atomicAdd(&rk[il], r);
    __syncthreads();
    if (t < 32) {
        int rank = rk[t];
        int ii = blockIdx.x * 32 + t;
        inv[ii] = (rank < k) ? rank : -1;
        if (rank < k) {
            perm[rank] = ii;
            int s = atomicAdd(&cnt, 1);
            selrow[s]  = ii;
            selrank[s] = rank;
            selval[s]  = score[ii];
        }
    }
    __syncthreads();
    const int wave = t >> 6, lane = t & 63;
    for (int s = wave; s < cnt; s += 8) {
        const int   row = selrow[s];
        const float vv  = selval[s];
        f32x4 x = *(const f32x4*)&xold[(size_t)row * 256 + lane * 4];
        s16x4 hh, ll;
#pragma unroll
        for (int q = 0; q < 4; q++) {
            float v = x[q] * vv;
            short h = f2bf(v);
            hh[q] = h; ll[q] = f2bf(v - bf2f(h));
        }
        size_t o = (size_t)selrank[s] * 256 + lane * 4;
        *(s16x4*)&Xh[o] = hh;
        *(s16x4*)&Xl[o] = ll;
    }
}

// fp32 mirrored slices -> A hi(/lo), rowsums  (x4 vectorized)
template<bool LO>
__global__ void aug_finish_f(const float* __restrict__ Cp, int S, int kk,
                             short* __restrict__ Ahs, short* __restrict__ Als,
                             float* __restrict__ rs)
{
    int t4 = (blockIdx.x * 256 + threadIdx.x) * 4;
    int r = t4 / kk, c0 = t4 - r * kk;
    size_t stride = (size_t)kk * kk;
    f32x4 v = {0.f, 0.f, 0.f, 0.f};
    for (int s = 0; s < S; s++) v += *(const f32x4*)&Cp[t4 + s * stride];
    if (r >= c0 && r < c0 + 4) v[r - c0] = 0.f;
    s16x4 hh, ll;
    float ws = 0.f;
#pragma unroll
    for (int q = 0; q < 4; q++) {
        short h = f2bf(v[q]);
        hh[q] = h;
        if (LO) ll[q] = f2bf(v[q] - bf2f(h));
        ws += v[q];
    }
    *(s16x4*)&Ahs[t4] = hh;
    if (LO) *(s16x4*)&Als[t4] = ll;
    for (int off = 32; off; off >>= 1) ws += __shfl_down(ws, off);
    if ((threadIdx.x & 63) == 0) atomicAdd(&rs[r], ws);
}

// ---------------------------------------------------------------------------
// Host orchestration
// ---------------------------------------------------------------------------

extern "C" void kernel_launch(void* const* d_in, const int* in_sizes, int n_in,
                              void* d_out, int out_size, void* d_ws, size_t ws_size,
                              hipStream_t stream)
{
    const float* x0  = (const float*)d_in[0];
    const int*   ei  = (const int*)d_in[1];
    const float* Wd0 = (const float*)d_in[2];  const float* bd0 = (const float*)d_in[3];
    const float* Wd1 = (const float*)d_in[4];  const float* bd1 = (const float*)d_in[5];
    const float* Wd2 = (const float*)d_in[6];  const float* bd2 = (const float*)d_in[7];
    const float* Wd3 = (const float*)d_in[8];  const float* bd3 = (const float*)d_in[9];
    const float* p1  = (const float*)d_in[10];
    const float* p2  = (const float*)d_in[11];
    const float* p3  = (const float*)d_in[12];
    const float* Wu0 = (const float*)d_in[13]; const float* bu0 = (const float*)d_in[14];
    const float* Wu1 = (const float*)d_in[15]; const float* bu1 = (const float*)d_in[16];
    const float* Wu2 = (const float*)d_in[17]; const float* bu2 = (const float*)d_in[18];

    const int E = in_sizes[1] / 2;

    char* ws = (char*)d_ws;
    size_t off = 0;
    auto alloc = [&](size_t bytes) -> void* {
        void* p = ws + off;
        off += (bytes + 255) & ~(size_t)255;
        return p;
    };
    unsigned long long* M0 = (unsigned long long*)alloc((size_t)4096 * 64 * 8);
    short* A1h  = (short*)alloc((size_t)2048 * 2048 * 2);
    short* A2h  = (short*)alloc((size_t)1024 * 1024 * 2);
    short* A2l  = (short*)alloc((size_t)1024 * 1024 * 2);
    short* A3h  = (short*)alloc((size_t)512 * 512 * 2);
    short* A3l  = (short*)alloc((size_t)512 * 512 * 2);
    short* Gh   = (short*)alloc((size_t)1024 * 2048 * 2);
    short* Gl   = (short*)alloc((size_t)512 * 1024 * 2);
    int*   csr  = (int*)alloc((size_t)4096 * 128 * 4);
    unsigned long long* maskb = (unsigned long long*)alloc((size_t)2048 * 64 * 8);
    float* Zf   = (float*)alloc((size_t)4096 * 256 * 4);
    float* Cp   = (float*)alloc((size_t)64 * 1024 * 1024);   // partial arena
    float* xs0  = (float*)alloc((size_t)4096 * 256 * 4);
    float* xs1  = (float*)alloc((size_t)2048 * 256 * 4);
    float* xs2  = (float*)alloc((size_t)1024 * 256 * 4);
    float* xu0  = (float*)alloc((size_t)4096 * 256 * 4);
    float* xu1  = (float*)alloc((size_t)2048 * 256 * 4);
    float* xu2  = (float*)alloc((size_t)1024 * 256 * 4);
    short* xu0h = (short*)alloc((size_t)4096 * 256 * 2);
    short* xu0l = (short*)alloc((size_t)4096 * 256 * 2);
    short* xu1h = (short*)alloc((size_t)2048 * 256 * 2);
    short* xu1l = (short*)alloc((size_t)2048 * 256 * 2);
    short* xu2h = (short*)alloc((size_t)1024 * 256 * 2);
    short* xu2l = (short*)alloc((size_t)1024 * 256 * 2);
    short* X0h  = (short*)alloc((size_t)4096 * 128 * 2);
    short* X0l  = (short*)alloc((size_t)4096 * 128 * 2);
    short* xah  = (short*)alloc((size_t)2048 * 256 * 2);
    short* xal  = (short*)alloc((size_t)2048 * 256 * 2);
    short* Wth  = (short*)alloc((size_t)393216 * 2);
    short* Wtl  = (short*)alloc((size_t)393216 * 2);
    short* Zh   = (short*)alloc((size_t)256 * 4096 * 2);
    short* Zl   = (short*)alloc((size_t)256 * 4096 * 2);
    float* rs0  = (float*)alloc(4096 * 4);
    float* rs1  = (float*)alloc(2048 * 4);
    float* rs2  = (float*)alloc(1024 * 4);
    float* rs3  = (float*)alloc(512 * 4);
    float* scoreb = (float*)alloc(4096 * 4);
    int*   perm1  = (int*)alloc(2048 * 4);
    int*   perm2  = (int*)alloc(1024 * 4);
    int*   perm3  = (int*)alloc(512 * 4);
    int*   inv1   = (int*)alloc(4096 * 4);
    int*   inv2   = (int*)alloc(2048 * 4);
    int*   inv3   = (int*)alloc(1024 * 4);

    float* Cp2 = Cp + (size_t)8 * 1024 * 1024;   // +32 MiB: xw slice region

    // post-xw stages of a dense-A GCN layer: z_reduce -> AZ -> gcn_final
    auto gcn_rest = [&](int n, int Cout, const short* pAh, const short* pAl,
                        const float* rsA, const float* b, float* out,
                        short* oh, short* ol, int relu, int modeA, int Saz,
                        const int* inv, const float* res, int nout,
                        const float* pvec, const float* CpXw, int Sxw) {
        z_reduce<<<(n * Cout) / 1024, 256, 0, stream>>>(CpXw, Sxw, rsA, Zh, Zl, n, Cout);
        dim3 g(Cout / 128, n / 128, Saz);
        if (modeA == 1)
            gemm_bt<1, 0><<<g, 256, 0, stream>>>(pAh, nullptr, Zh, Zl, Cp, n, Cout, n, n / Saz);
        else
            gemm_bt<2, 0><<<g, 256, 0, stream>>>(pAh, pAl, Zh, Zl, Cp, n, Cout, n, n / Saz);
        if (pvec)
            gcn_final<1><<<(nout * Cout) / 1024, 256, 0, stream>>>(
                Cp, Saz, Zh, Zl, rsA, b, out, oh, ol, n, Cout, relu, inv, res,
                pvec, scoreb);
        else
            gcn_final<0><<<(nout * Cout) / 1024, 256, 0, stream>>>(
                Cp, Saz, Zh, Zl, rsA, b, out, oh, ol, n, Cout, relu, inv, res,
                nullptr, nullptr);
    };

    // full dense layer (up path, no overlap partner): xw at Cp base
    auto gcn_dense = [&](const short* Xh, const short* Xl, int n, int Kc, int Cout,
                         const short* pAh, const short* pAl, const float* rsA,
                         int wtoff, const float* b,
                         float* out, short* oh, short* ol, int relu, int modeA,
                         int Saz, const int* inv, const float* res, int nout,
                         const float* pvec, int Sxw) {
        gemm_bt<2, 3><<<dim3(Cout / 128, n / 128, Sxw), 256, 0, stream>>>(
            Xh, Xl, Wth + wtoff, Wtl + wtoff, Cp, n, Cout, Kc, Kc / Sxw);
        gcn_rest(n, Cout, pAh, pAl, rsA, b, out, oh, ol, relu, modeA, Saz,
                 inv, res, nout, pvec, Cp, Sxw);
    };

    auto pool = [&](const float* xlev, int n, int* perm, int* inv) {
        int k = n / 2;
        rank_pool<<<n / 32, 512, 0, stream>>>(scoreb, n, k, xlev, perm, inv, xah, xal);
    };

    // ---- prep (weights + x0 split + M0 zero) + bitmask adjacency ----
    prep<<<4608, 256, 0, stream>>>(Wd0, Wd1, Wd2, Wd3, Wu0, Wu1, Wu2, x0,
                                   Wth, Wtl, X0h, X0l, M0);
    build_bits<<<(E + 255) / 256, 256, 0, stream>>>(ei, E, M0);

    // ---- down 0: FAT{x@W (256 blk) || row_compact CSR (1024 blk)} ----
    xw_fat<3, 0><<<256 + 1024, 256, 0, stream>>>(
        X0h, X0l, Wth, Wtl, Cp, 4096, 256, 128, 32,
        2, 32, 256,
        nullptr, nullptr, 0, nullptr, nullptr, nullptr, 0, rs0, M0, nullptr, csr);
    zf_reduce<<<1024, 256, 0, stream>>>(Cp, 4, rs0, Zf, 4096, 256);
    spmm_gcn<256, 1, 1><<<1024, 256, 0, stream>>>(csr, rs0, Zf, bd0, xs0, p1, scoreb);

    // ---- level 0 -> 1: pool, FAT{xw(L1)->Cp2 || mask_gather}, popc, merge ----
    pool(xs0, 4096, perm1, inv1);
    xw_fat<2, 3><<<128 + 512, 256, 0, stream>>>(
        xah, xal, Wth + 32768, Wtl + 32768, Cp2, 2048, 256, 256, 64,
        2, 16, 128,
        nullptr, nullptr, 0, perm1, nullptr, nullptr, 2048, rs1, M0, maskb, nullptr);
    popc_aug_p<<<dim3(32, 32, 4), 256, 0, stream>>>(maskb, (short*)Cp);
    aug_merge<<<dim3(32, 32), 256, 0, stream>>>((const short*)Cp, 2048, A1h, rs1);
    gcn_rest(2048, 256, A1h, nullptr, rs1, bd1, xs1, nullptr, nullptr, 1, 1, 8,
             nullptr, nullptr, 2048, p2, Cp2, 4);

    // ---- level 1 -> 2: pool, FAT{xw(L2,Sxw=8)->Cp2 || gatherG_h}, TRI, finish ----
    pool(xs1, 2048, perm2, inv2);
    xw_fat<0, 3><<<128 + 1024, 256, 0, stream>>>(
        xah, xal, Wth + 98304, Wtl + 98304, Cp2, 1024, 256, 256, 32,
        2, 8, 128,
        A1h, nullptr, 2048, perm2, Gh, nullptr, 1024, rs2, nullptr, nullptr, nullptr);
    gemm_bt<0, 1><<<dim3(8, 8, 8), 256, 0, stream>>>(Gh, nullptr, Gh, nullptr, Cp, 1024, 1024, 2048, 256);
    aug_finish_f<true><<<(1024 * 1024 / 4) / 256, 256, 0, stream>>>(Cp, 8, 1024, A2h, A2l, rs2);
    gcn_rest(1024, 256, A2h, A2l, rs2, bd2, xs2, nullptr, nullptr, 1, 2, 8,
             nullptr, nullptr, 1024, p3, Cp2, 8);

    // ---- level 2 -> 3: pool, FAT{xw(down3,Sxw=8)->Cp2 || gatherG_hl}, TRI, finish ----
    pool(xs2, 1024, perm3, inv3);
    xw_fat<1, 3><<<64 + 256, 256, 0, stream>>>(
        xah, xal, Wth + 163840, Wtl + 163840, Cp2, 512, 256, 256, 32,
        2, 4, 64,
        A2h, A2l, 1024, perm3, Gh, Gl, 512, rs3, nullptr, nullptr, nullptr);
    gemm_bt<2, 1><<<dim3(4, 4, 8), 256, 0, stream>>>(Gh, Gl, Gh, Gl, Cp, 512, 512, 1024, 128);
    aug_finish_f<true><<<(512 * 512 / 4) / 256, 256, 0, stream>>>(Cp, 8, 512, A3h, A3l, rs3);

    // ---- down 3: out scattered into xu2 = xs2 + u (inv3) ----
    gcn_rest(512, 256, A3h, A3l, rs3, bd3, xu2, xu2h, xu2l, 1, 2, 8,
             inv3, xs2, 1024, nullptr, Cp2, 8);

    // ---- up 0: out scattered into xu1 = xs1 + u (inv2), Sxw=8 ----
    gcn_dense(xu2h, xu2l, 1024, 256, 256, A2h, A2l, rs2, 229376, bu0,
              xu1, xu1h, xu1l, 1, 2, 8, inv2, xs1, 2048, nullptr, 8);

    // ---- up 1: out scattered into xu0 = xs0 + u (inv1), Sxw=4 ----
    gcn_dense(xu1h, xu1l, 2048, 256, 256, A1h, nullptr, rs1, 294912, bu1,
              xu0, xu0h, xu0l, 1, 1, 8, inv1, xs0, 4096, nullptr, 4);

    // ---- up 2 (A0 sparse, Cout=128, no relu) -> d_out ----
    gemm_bt<2, 0><<<dim3(1, 32, 8), 256, 0, stream>>>(
        xu0h, xu0l, Wth + 360448, Wtl + 360448, Cp, 4096, 128, 256, 32);
    zf_reduce<<<512, 256, 0, stream>>>(Cp, 8, rs0, Zf, 4096, 128);
    spmm_gcn<128, 0, 0><<<1024, 256, 0, stream>>>(csr, rs0, Zf, bu2, (float*)d_out,
                                                  nullptr, nullptr);
}